// Round 7
// baseline (1040.219 us; speedup 1.0000x reference)
//
#include <hip/hip_runtime.h>
#include <hip/hip_bf16.h>
#include <hip/hip_fp16.h>

typedef __hip_bfloat16 bf16;
typedef __attribute__((ext_vector_type(8))) short short8;
typedef __attribute__((ext_vector_type(8))) _Float16 half8;
typedef __attribute__((ext_vector_type(2))) _Float16 half2v;
typedef __attribute__((ext_vector_type(4))) float f32x4;

#define N_NODES 50000
#define N_EDGES 1600000
#define FIN 8
#define HD 64
#define NH (N_NODES * HD)
#define HHALF (N_NODES * 32)
#define NLAYERS 3

// CSR build geometry
#define RSLC 256                 // row slices, E/RSLC = 6250
#define EPR (N_EDGES / RSLC)
#define NWORDS 12500             // 50000 nodes as packed u8 in u32

__device__ __forceinline__ float b2f(bf16 v) { return __bfloat162float(v); }
__device__ __forceinline__ float bu2f(unsigned int u) { return __uint_as_float(u << 16); }
__device__ __forceinline__ unsigned short f2bu(float f) {
    unsigned int x = __float_as_uint(f);
    unsigned int r = x + 0x7FFFu + ((x >> 16) & 1u);
    return (unsigned short)(r >> 16);
}
__device__ __forceinline__ unsigned short f2h(float f) {
    _Float16 h = (_Float16)f;
    return *(unsigned short*)&h;
}
// low 16 bits as fp16 -> float (single v_cvt_f32_f16)
union H16 { unsigned short b; _Float16 h; };
__device__ __forceinline__ float h16f(unsigned u) {
    H16 x; x.b = (unsigned short)u;
    return (float)x.h;
}

// ---------------- dtype detection ----------------
__global__ void k_detect(const void* __restrict__ ew, int* __restrict__ flag) {
    int ok = 1;
    for (int i = threadIdx.x; i < 512; i += 64) {
        float v = b2f(((const bf16*)ew)[i]);
        if (!(v >= 0.f && v <= 1.f)) ok = 0;
    }
    unsigned long long m = __ballot(ok);
    if (threadIdx.x == 0) *flag = (m == 0xFFFFFFFFFFFFFFFFull) ? 0 : 1;
}

struct ConvArgs {
    const void* src[14];
    float* dst[14];
    int cum[15];
};

__global__ void k_conv_small(ConvArgs a, const int* __restrict__ flag) {
    int q = blockIdx.x * 256 + threadIdx.x;
    if (q >= a.cum[14]) return;
    int s = 0;
    while (q >= a.cum[s + 1]) ++s;
    int off = q - a.cum[s];
    if (*flag) a.dst[s][off] = ((const float*)a.src[s])[off];
    else       a.dst[s][off] = bu2f(((const unsigned short*)a.src[s])[off]);
}

// ---------------- degree: coalesced read + global f32 atomics (col-indexed) ----------------
// NOTE (measured r6): ~100 us, WRITE_SIZE ~49.8 MB = 1.6M atomics x 32 B write-through at
// the coherence point (per-XCD L2s non-coherent). Atomic-backend-throughput-bound; known cost.
__global__ void k_deg(const int* __restrict__ ei, const void* __restrict__ ewr,
                      const int* __restrict__ flag, float* __restrict__ deg) {
    int e = blockIdx.x * 256 + threadIdx.x;
    if (e >= N_EDGES) return;
    int c = ei[N_EDGES + e];
    float w = (*flag) ? ((const float*)ewr)[e] : bu2f(((const unsigned short*)ewr)[e]);
    atomicAdd(&deg[c], w);
}

// ---------------- CSR build: byte-packed LDS histograms, no global atomics ----------------

__global__ void __launch_bounds__(256) k_hist_row(const int* __restrict__ ei,
                                                  unsigned int* __restrict__ pcnt_u32) {
    __shared__ unsigned int sm[NWORDS];
    int b = blockIdx.x, t = threadIdx.x;
    for (int i = t; i < NWORDS; i += 256) sm[i] = 0;
    __syncthreads();
    int ebase = b * EPR;
    for (int el = t; el < EPR; el += 256) {
        int r = ei[ebase + el];
        atomicAdd(&sm[r >> 2], 1u << ((r & 3) * 8));
    }
    __syncthreads();
    unsigned int* dst = pcnt_u32 + (size_t)b * NWORDS;
    for (int i = t; i < NWORDS; i += 256) dst[i] = sm[i];
}

// per-node: 256-slice u8 prefix -> pref16, total -> cnt; dis/dis2 from deg
__global__ void k_merge(const unsigned char* __restrict__ pcnt8,
                        const float* __restrict__ deg,
                        int* __restrict__ cnt, float* __restrict__ dis,
                        float* __restrict__ dis2,
                        unsigned short* __restrict__ pref16, int* __restrict__ bsum) {
    __shared__ int red[256];
    int t = threadIdx.x;
    int n = blockIdx.x * 256 + t;
    int run = 0;
    if (n < N_NODES) {
#pragma unroll 8
        for (int s = 0; s < RSLC; ++s) {
            pref16[(size_t)s * N_NODES + n] = (unsigned short)run;
            run += pcnt8[(size_t)s * N_NODES + n];
        }
        cnt[n] = run;
        float di = fminf(rsqrtf(deg[n]), 1e6f);  // rsqrt(0)=inf -> 1e6, matches ref clamp
        dis[n] = di;
        dis2[n] = di * di;
    }
    red[t] = run;
    __syncthreads();
    for (int off = 128; off; off >>= 1) {
        if (t < off) red[t] += red[t + off];
        __syncthreads();
    }
    if (t == 0) bsum[blockIdx.x] = red[0];
}

__global__ void k_scan_top(const int* __restrict__ bsum, int* __restrict__ bpre,
                           int* __restrict__ row_ptr) {
    __shared__ int sm[256];
    int t = threadIdx.x;
    int v = (t < 196) ? bsum[t] : 0;
    sm[t] = v;
    __syncthreads();
    int val = v;
    for (int off = 1; off < 256; off <<= 1) {
        int other = (t >= off) ? sm[t - off] : 0;
        __syncthreads();
        val += other;
        sm[t] = val;
        __syncthreads();
    }
    bpre[t] = val - v;
    if (t == 0) row_ptr[N_NODES] = N_EDGES;
}

__global__ void k_scan_fin(const int* __restrict__ cnt, const int* __restrict__ bpre,
                           int* __restrict__ row_ptr) {
    __shared__ int sm[256];
    int t = threadIdx.x;
    int n = blockIdx.x * 256 + t;
    int v = (n < N_NODES) ? cnt[n] : 0;
    sm[t] = v;
    __syncthreads();
    int val = v;
    for (int off = 1; off < 256; off <<= 1) {
        int other = (t >= off) ? sm[t - off] : 0;
        __syncthreads();
        val += other;
        sm[t] = val;
        __syncthreads();
    }
    if (n < N_NODES) row_ptr[n] = bpre[blockIdx.x] + val - v;
}

// placement: per-slice u8 ordinal in LDS; writes pairs4[pos]=(c<<16|w_fp16) scattered (4 B)
// + iperm[e]=pos coalesced. ei/ew reads coalesced.
__global__ void __launch_bounds__(256) k_placeA(const int* __restrict__ ei,
                                                const void* __restrict__ ewr,
                                                const int* __restrict__ flag,
                                                const int* __restrict__ row_ptr,
                                                const unsigned short* __restrict__ pref16,
                                                unsigned int* __restrict__ pairs4,
                                                int* __restrict__ iperm) {
    __shared__ unsigned int sm[NWORDS];
    int b = blockIdx.x, t = threadIdx.x;
    for (int i = t; i < NWORDS; i += 256) sm[i] = 0;
    __syncthreads();
    int f32 = *flag;
    int ebase = b * EPR;
    const unsigned short* pr = pref16 + (size_t)b * N_NODES;
    for (int el = t; el < EPR; el += 256) {
        int e = ebase + el;
        int r = ei[e];
        int c = ei[N_EDGES + e];
        float w = f32 ? ((const float*)ewr)[e] : bu2f(((const unsigned short*)ewr)[e]);
        int sh = (r & 3) * 8;
        unsigned old = atomicAdd(&sm[r >> 2], 1u << sh);
        int ord = (old >> sh) & 0xFF;
        int pos = row_ptr[r] + pr[r] + ord;
        pairs4[pos] = ((unsigned)c << 16) | (unsigned)f2h(w);  // scattered 4 B
        iperm[e] = pos;                                        // coalesced
    }
}

// rc rebuild: wave per node, coalesced read of pairs4 + coalesced write of rc
__global__ void __launch_bounds__(256) k_rc(const int* __restrict__ row_ptr,
                                            const unsigned int* __restrict__ pairs4,
                                            unsigned int* __restrict__ rc) {
    int lane = threadIdx.x & 63;
    int wv = __builtin_amdgcn_readfirstlane((int)(blockIdx.x * 4 + (threadIdx.x >> 6)));
    int s = __builtin_amdgcn_readfirstlane(row_ptr[wv]);
    int e = __builtin_amdgcn_readfirstlane(row_ptr[wv + 1]);
    unsigned rhi = ((unsigned)wv) << 16;
    for (int pos = s + lane; pos < e; pos += 64)
        rc[pos] = (pairs4[pos] >> 16) | rhi;
}

// ---------------- input projection: h (f32 [N][64]) + hbf split [2][N][32] scaled state ---

__global__ void k_inproj(const void* __restrict__ xr_, const float* __restrict__ W,
                         const float* __restrict__ b, const float* __restrict__ dis,
                         float* __restrict__ h,
                         unsigned short* __restrict__ h_bf, const int* __restrict__ flag) {
    __shared__ float Wt[FIN * HD];
    __shared__ float bs[HD];
    int t = threadIdx.x;
    int f32 = *flag;
    for (int idx = t; idx < FIN * HD; idx += 256) {
        int f = idx >> 3, j = idx & 7;
        Wt[j * 64 + f] = W[idx];
    }
    if (t < 64) bs[t] = b[t];
    __syncthreads();
    int gid = blockIdx.x * 256 + t;
    if (gid < NH) {
        int i = gid >> 6, f = gid & 63;
        const float* xf = (const float*)xr_ + i * FIN;
        const unsigned short* xb = (const unsigned short*)xr_ + i * FIN;
        float acc = bs[f];
#pragma unroll
        for (int j = 0; j < FIN; ++j) {
            float xv = f32 ? xf[j] : bu2f(xb[j]);
            acc += xv * Wt[j * 64 + f];
        }
        h[gid] = acc;
        h_bf[(size_t)(f >> 5) * HHALF + i * 32 + (f & 31)] = f2bu(acc * dis[i]);
    }
}

// ---------------- stats + coefficient MLP ----------------

__global__ void k_stats(const float* __restrict__ h, float* __restrict__ stats) {
    __shared__ float ssum[256], ssq[256];
    int t = threadIdx.x;
    float ls = 0.f, lq = 0.f;
    for (int idx = blockIdx.x * 256 + t; idx < NH; idx += 102400) {
        float v = h[idx];
        ls += v; lq += v * v;
    }
    ssum[t] = ls; ssq[t] = lq;
    __syncthreads();
    if (t < 64) {
        float a = ssum[t] + ssum[t + 64] + ssum[t + 128] + ssum[t + 192];
        atomicAdd(&stats[t], a);
        float q = ssq[t] + ssq[t + 64] + ssq[t + 128] + ssq[t + 192];
        for (int off = 32; off; off >>= 1) q += __shfl_down(q, off, 64);
        if (t == 0) atomicAdd(&stats[64], q);
    }
}

__global__ void k_coeffs(const float* __restrict__ stats,
                         const float* __restrict__ W1, const float* __restrict__ b1,
                         const float* __restrict__ W2, const float* __restrict__ b2,
                         int layer, float* __restrict__ coeffs) {
    __shared__ float ci[68];
    __shared__ float hid[32];
    __shared__ float lg[6];
    int t = threadIdx.x;
    float sf = stats[t];
    float tot = sf;
    for (int off = 1; off < 64; off <<= 1) tot += __shfl_xor(tot, off, 64);
    ci[t] = sf / (float)N_NODES;
    if (t == 0) {
        float sumsq = stats[64];
        float mean = tot / (float)NH;
        float var = (sumsq - (float)NH * mean * mean) / (float)(NH - 1);
        ci[64] = mean;
        ci[65] = sqrtf(fmaxf(var, 0.f));
        ci[66] = (float)N_NODES;
        ci[67] = (float)N_EDGES;
    }
    __syncthreads();
    if (t < 32) {
        float a = b1[layer * 32 + t];
        const float* wr = W1 + (layer * 32 + t) * 68;
        for (int j = 0; j < 68; ++j) a += ci[j] * wr[j];
        hid[t] = fmaxf(a, 0.f);
    }
    __syncthreads();
    if (t < 6) {
        float a = b2[layer * 6 + t];
        const float* wr = W2 + (layer * 6 + t) * 32;
        for (int g = 0; g < 32; ++g) a += hid[g] * wr[g];
        lg[t] = a;
    }
    __syncthreads();
    if (t == 0) {
        float mx = lg[0];
        for (int p = 1; p < 6; ++p) mx = fmaxf(mx, lg[p]);
        float s = 0.f, e[6];
        for (int p = 0; p < 6; ++p) { e[p] = expf(lg[p] - mx); s += e[p]; }
        for (int p = 0; p < 6; ++p) coeffs[p] = e[p] / s;
    }
}

// ---------------- SpMM hop, XCD-split: wave = (node, feature-half), 2 edges per VMEM ------
// src half = 3.2 MB < 4 MB XCD L2; blockIdx&1 parity pins each XCD (round-robin %8) to ONE
// half. Pair words stay WAVE-UNIFORM SCALAR loads (contiguous j..j+15 -> s_load_dwordx16);
// lanes 0-31 take even CSR slots, lanes 32-63 odd slots (one v_cndmask per 2 edges).
// Gather: one VMEM instr covers 2 edges (2 x 64 B segments). s_{k+1}=dis2[r]*sum w*s_k[col].

__device__ __forceinline__ float acc_range_h(const unsigned short* __restrict__ src,
                                             const unsigned int* __restrict__ pairs4,
                                             int j0, int j1, int odd, int f, float acc) {
    int j = j0;
    for (; j + 15 < j1; j += 16) {
        unsigned p0 = pairs4[j],      p1 = pairs4[j + 1],  p2 = pairs4[j + 2],  p3 = pairs4[j + 3];
        unsigned p4 = pairs4[j + 4],  p5 = pairs4[j + 5],  p6 = pairs4[j + 6],  p7 = pairs4[j + 7];
        unsigned p8 = pairs4[j + 8],  p9 = pairs4[j + 9],  pa = pairs4[j + 10], pb = pairs4[j + 11];
        unsigned pc = pairs4[j + 12], pd = pairs4[j + 13], pe = pairs4[j + 14], pf = pairs4[j + 15];
        unsigned q0 = odd ? p1 : p0;
        unsigned q1 = odd ? p3 : p2;
        unsigned q2 = odd ? p5 : p4;
        unsigned q3 = odd ? p7 : p6;
        unsigned q4 = odd ? p9 : p8;
        unsigned q5 = odd ? pb : pa;
        unsigned q6 = odd ? pd : pc;
        unsigned q7 = odd ? pf : pe;
        float g0 = bu2f(src[(q0 >> 16) * 32 + f]);
        float g1 = bu2f(src[(q1 >> 16) * 32 + f]);
        float g2 = bu2f(src[(q2 >> 16) * 32 + f]);
        float g3 = bu2f(src[(q3 >> 16) * 32 + f]);
        float g4 = bu2f(src[(q4 >> 16) * 32 + f]);
        float g5 = bu2f(src[(q5 >> 16) * 32 + f]);
        float g6 = bu2f(src[(q6 >> 16) * 32 + f]);
        float g7 = bu2f(src[(q7 >> 16) * 32 + f]);
        acc += h16f(q0) * g0 + h16f(q1) * g1 + h16f(q2) * g2 + h16f(q3) * g3;
        acc += h16f(q4) * g4 + h16f(q5) * g5 + h16f(q6) * g6 + h16f(q7) * g7;
    }
    for (; j + 7 < j1; j += 8) {
        unsigned p0 = pairs4[j],     p1 = pairs4[j + 1], p2 = pairs4[j + 2], p3 = pairs4[j + 3];
        unsigned p4 = pairs4[j + 4], p5 = pairs4[j + 5], p6 = pairs4[j + 6], p7 = pairs4[j + 7];
        unsigned q0 = odd ? p1 : p0;
        unsigned q1 = odd ? p3 : p2;
        unsigned q2 = odd ? p5 : p4;
        unsigned q3 = odd ? p7 : p6;
        float g0 = bu2f(src[(q0 >> 16) * 32 + f]);
        float g1 = bu2f(src[(q1 >> 16) * 32 + f]);
        float g2 = bu2f(src[(q2 >> 16) * 32 + f]);
        float g3 = bu2f(src[(q3 >> 16) * 32 + f]);
        acc += h16f(q0) * g0 + h16f(q1) * g1 + h16f(q2) * g2 + h16f(q3) * g3;
    }
    for (; j + 1 < j1; j += 2) {
        unsigned p0 = pairs4[j], p1 = pairs4[j + 1];
        unsigned q = odd ? p1 : p0;
        acc += h16f(q) * bu2f(src[(q >> 16) * 32 + f]);
    }
    if (j < j1) {   // odd row length: lanes 32-63 get q=0 -> w=0 contribution
        unsigned p0 = pairs4[j];
        unsigned q = odd ? 0u : p0;
        acc += h16f(q) * bu2f(src[(q >> 16) * 32 + f]);
    }
    return acc;
}

__global__ void __launch_bounds__(256) k_spmm(
    const unsigned short* __restrict__ txo, unsigned short* __restrict__ txn,
    const int* __restrict__ row_ptr, const unsigned int* __restrict__ pairs4,
    const float* __restrict__ dis2, int full_out) {
    int t = threadIdx.x;
    int lane = t & 63;
    int f = lane & 31, odd = lane >> 5;
    int hsel = blockIdx.x & 1;
    int wv = __builtin_amdgcn_readfirstlane((int)((blockIdx.x >> 1) * 4 + (t >> 6)));
    const unsigned short* src = txo + (size_t)hsel * HHALF;
    int s = __builtin_amdgcn_readfirstlane(row_ptr[wv]);
    int e = __builtin_amdgcn_readfirstlane(row_ptr[wv + 1]);
    float acc = acc_range_h(src, pairs4, s, e, odd, f, 0.f);
    acc += __shfl_xor(acc, 32, 64);   // even-slot + odd-slot partials, same feature
    if (odd == 0) {
        unsigned short v = f2bu(acc * dis2[wv]);
        if (full_out) txn[wv * 64 + hsel * 32 + f] = v;                   // [N][64] for hop5 gather
        else          txn[(size_t)hsel * HHALF + wv * 32 + f] = v;        // [2][N][32] for next hop
    }
}

// ---------------- fused last hop + polynomial combine + layernorm (full-layout gather) ----
// t1..t3 split [2][N][32]; t4 (=txo) full [N][64]. tx_k = s_k/dis; hop5 tx5 = dis*acc.

__device__ __forceinline__ float acc_range(const unsigned short* __restrict__ txo,
                                           const unsigned int* __restrict__ pairs4,
                                           int j0, int j1, int lane, float acc) {
    int j = j0;
    for (; j + 15 < j1; j += 16) {
        unsigned p0 = pairs4[j],      p1 = pairs4[j + 1],  p2 = pairs4[j + 2],  p3 = pairs4[j + 3];
        unsigned p4 = pairs4[j + 4],  p5 = pairs4[j + 5],  p6 = pairs4[j + 6],  p7 = pairs4[j + 7];
        unsigned p8 = pairs4[j + 8],  p9 = pairs4[j + 9],  pa = pairs4[j + 10], pb = pairs4[j + 11];
        unsigned pc = pairs4[j + 12], pd = pairs4[j + 13], pe = pairs4[j + 14], pf = pairs4[j + 15];
        float g0 = bu2f(txo[(p0 >> 16) * 64 + lane]);
        float g1 = bu2f(txo[(p1 >> 16) * 64 + lane]);
        float g2 = bu2f(txo[(p2 >> 16) * 64 + lane]);
        float g3 = bu2f(txo[(p3 >> 16) * 64 + lane]);
        float g4 = bu2f(txo[(p4 >> 16) * 64 + lane]);
        float g5 = bu2f(txo[(p5 >> 16) * 64 + lane]);
        float g6 = bu2f(txo[(p6 >> 16) * 64 + lane]);
        float g7 = bu2f(txo[(p7 >> 16) * 64 + lane]);
        float g8 = bu2f(txo[(p8 >> 16) * 64 + lane]);
        float g9 = bu2f(txo[(p9 >> 16) * 64 + lane]);
        float ga = bu2f(txo[(pa >> 16) * 64 + lane]);
        float gb = bu2f(txo[(pb >> 16) * 64 + lane]);
        float gc = bu2f(txo[(pc >> 16) * 64 + lane]);
        float gd = bu2f(txo[(pd >> 16) * 64 + lane]);
        float ge = bu2f(txo[(pe >> 16) * 64 + lane]);
        float gf = bu2f(txo[(pf >> 16) * 64 + lane]);
        acc += h16f(p0) * g0 + h16f(p1) * g1 + h16f(p2) * g2 + h16f(p3) * g3;
        acc += h16f(p4) * g4 + h16f(p5) * g5 + h16f(p6) * g6 + h16f(p7) * g7;
        acc += h16f(p8) * g8 + h16f(p9) * g9 + h16f(pa) * ga + h16f(pb) * gb;
        acc += h16f(pc) * gc + h16f(pd) * gd + h16f(pe) * ge + h16f(pf) * gf;
    }
    for (; j + 7 < j1; j += 8) {
        unsigned p0 = pairs4[j],     p1 = pairs4[j + 1], p2 = pairs4[j + 2], p3 = pairs4[j + 3];
        unsigned p4 = pairs4[j + 4], p5 = pairs4[j + 5], p6 = pairs4[j + 6], p7 = pairs4[j + 7];
        float g0 = bu2f(txo[(p0 >> 16) * 64 + lane]);
        float g1 = bu2f(txo[(p1 >> 16) * 64 + lane]);
        float g2 = bu2f(txo[(p2 >> 16) * 64 + lane]);
        float g3 = bu2f(txo[(p3 >> 16) * 64 + lane]);
        float g4 = bu2f(txo[(p4 >> 16) * 64 + lane]);
        float g5 = bu2f(txo[(p5 >> 16) * 64 + lane]);
        float g6 = bu2f(txo[(p6 >> 16) * 64 + lane]);
        float g7 = bu2f(txo[(p7 >> 16) * 64 + lane]);
        acc += h16f(p0) * g0 + h16f(p1) * g1 + h16f(p2) * g2 + h16f(p3) * g3;
        acc += h16f(p4) * g4 + h16f(p5) * g5 + h16f(p6) * g6 + h16f(p7) * g7;
    }
    for (; j < j1; ++j) {
        unsigned p = pairs4[j];
        acc += h16f(p) * bu2f(txo[(p >> 16) * 64 + lane]);
    }
    return acc;
}

__global__ void __launch_bounds__(256) k_spmm_ln(
    const unsigned short* __restrict__ txo,
    const int* __restrict__ row_ptr, const unsigned int* __restrict__ pairs4,
    float* __restrict__ h, unsigned short* __restrict__ h_bf,
    const unsigned short* __restrict__ t1, const unsigned short* __restrict__ t2,
    const unsigned short* __restrict__ t3, const unsigned short* __restrict__ t4,
    const float* __restrict__ coeffs, const float* __restrict__ dis,
    const float* __restrict__ sc, const float* __restrict__ bi,
    int layer, int last, void* __restrict__ outv, const int* __restrict__ flag) {
    int lane = threadIdx.x & 63;
    int wv = __builtin_amdgcn_readfirstlane((int)(blockIdx.x * 4 + (threadIdx.x >> 6)));
    int s = __builtin_amdgcn_readfirstlane(row_ptr[wv]);
    int e = __builtin_amdgcn_readfirstlane(row_ptr[wv + 1]);
    float acc = acc_range(txo, pairs4, s, e, lane, 0.f);
    int o = wv * 64 + lane;
    size_t so = (size_t)(lane >> 5) * HHALF + wv * 32 + (lane & 31);   // split-layout stream
    float ds = dis[wv];
    float invd = 1.f / ds;
    float c0 = coeffs[0], c1 = coeffs[1], c2 = coeffs[2],
          c3 = coeffs[3], c4 = coeffs[4], c5 = coeffs[5];
    float v = (1.f + c0) * h[o] +
              invd * (c1 * bu2f(t1[so]) + c2 * bu2f(t2[so]) +
                      c3 * bu2f(t3[so]) + c4 * bu2f(t4[o])) +
              c5 * ds * acc;
    float m = v;
    for (int off = 1; off < 64; off <<= 1) m += __shfl_xor(m, off, 64);
    m *= (1.f / 64.f);
    float d = v - m;
    float q = d * d;
    for (int off = 1; off < 64; off <<= 1) q += __shfl_xor(q, off, 64);
    float var = q * (1.f / 64.f);
    float y = d / sqrtf(var + 1e-5f) * sc[layer * 64 + lane] + bi[layer * 64 + lane];
    h[o] = y;
    h_bf[so] = f2bu(y * ds);   // next layer's scaled state s0, split layout
    if (last) {
        if (*flag) ((float*)outv)[N_EDGES + o] = y;
        else       ((unsigned short*)outv)[N_EDGES + o] = f2bu(y);
    }
}

// ---------------- edge predictor (fp16) ----------------

__global__ void __launch_bounds__(256) k_uv(const float* __restrict__ h,
                                            const float* __restrict__ W1,
                                            unsigned short* __restrict__ ub,
                                            unsigned short* __restrict__ vb) {
    __shared__ float Wt[128 * 65];
    __shared__ float hs[4 * 64];
    int t = threadIdx.x;
    for (int idx = t; idx < 8192; idx += 256) {
        int f = idx >> 7, j = idx & 127;
        Wt[j * 65 + f] = W1[idx];
    }
    int node0 = blockIdx.x * 4;
    hs[t] = h[node0 * 64 + t];
    __syncthreads();
    int ni = t >> 6, f = t & 63;
    const float* hr = hs + ni * 64;
    float au = 0.f, av = 0.f;
#pragma unroll 8
    for (int j = 0; j < 64; ++j) {
        float xv = hr[j];
        au += Wt[j * 65 + f] * xv;
        av += Wt[(j + 64) * 65 + f] * xv;
    }
    int i = node0 + ni;
    ub[i * 64 + f] = f2h(au);   // fp16 bits
    vb[i * 64 + f] = f2h(av);
}

// packed fp16 relu(u + v + b) via native _Float16 vectors (avoids __hmax2 overload clash)
__device__ __forceinline__ unsigned h2rel(unsigned uu, unsigned vv, half2v b) {
    half2v a = *(half2v*)&uu + *(half2v*)&vv + b;
    a[0] = a[0] > (_Float16)0 ? a[0] : (_Float16)0;
    a[1] = a[1] > (_Float16)0 ? a[1] : (_Float16)0;
    return *(unsigned*)&a;
}

union U4H8 { uint4 u; half8 h; };

// MFMA f16 edge predictor: 16 CSR-ordered edges per wave-iteration; coalesced tmp output
__global__ void __launch_bounds__(256) k_edgepred(
    const unsigned short* __restrict__ ub, const unsigned short* __restrict__ vb,
    const unsigned int* __restrict__ rc,
    const float* __restrict__ eb1, const float* __restrict__ eW2,
    const float* __restrict__ eb2, const float* __restrict__ eW3,
    const float* __restrict__ eb3, float* __restrict__ tmpP) {
    int t = threadIdx.x;
    int lane = t & 63;
    int m = lane & 15, q = lane >> 4;

    half8 B00, B01, B10, B11;
#pragma unroll
    for (int j = 0; j < 8; ++j) {
        B00[j] = (_Float16)eW2[(m) * 64      + q * 8 + j];
        B01[j] = (_Float16)eW2[(m) * 64 + 32 + q * 8 + j];
        B10[j] = (_Float16)eW2[(m + 16) * 64      + q * 8 + j];
        B11[j] = (_Float16)eW2[(m + 16) * 64 + 32 + q * 8 + j];
    }
    half2v b1p0[4], b1p1[4];
#pragma unroll
    for (int wq = 0; wq < 4; ++wq) {
        b1p0[wq][0] = (_Float16)eb1[q * 8 + 2 * wq];
        b1p0[wq][1] = (_Float16)eb1[q * 8 + 2 * wq + 1];
        b1p1[wq][0] = (_Float16)eb1[32 + q * 8 + 2 * wq];
        b1p1[wq][1] = (_Float16)eb1[32 + q * 8 + 2 * wq + 1];
    }
    float w3a = eW3[m], w3b = eW3[16 + m];
    float b2a = eb2[m], b2b = eb2[16 + m];
    float b3v = eb3[0];

    int gw = blockIdx.x * 4 + (t >> 6);
    const int NW = 1563 * 4;
    for (int tile = gw; tile < N_EDGES / 16; tile += NW) {
        int base = tile << 4;
        unsigned rcv = rc[base + m];
        int col = rcv & 0xFFFF;
        int row = rcv >> 16;
        const unsigned short* up = ub + row * 64;
        const unsigned short* vp = vb + col * 64;
        uint4 U0 = *(const uint4*)(up + q * 8);
        uint4 U1 = *(const uint4*)(up + 32 + q * 8);
        uint4 V0 = *(const uint4*)(vp + q * 8);
        uint4 V1 = *(const uint4*)(vp + 32 + q * 8);
        U4H8 a0, a1;
        a0.u.x = h2rel(U0.x, V0.x, b1p0[0]);
        a0.u.y = h2rel(U0.y, V0.y, b1p0[1]);
        a0.u.z = h2rel(U0.z, V0.z, b1p0[2]);
        a0.u.w = h2rel(U0.w, V0.w, b1p0[3]);
        a1.u.x = h2rel(U1.x, V1.x, b1p1[0]);
        a1.u.y = h2rel(U1.y, V1.y, b1p1[1]);
        a1.u.z = h2rel(U1.z, V1.z, b1p1[2]);
        a1.u.w = h2rel(U1.w, V1.w, b1p1[3]);
        f32x4 acc0 = {0.f, 0.f, 0.f, 0.f};
        f32x4 acc1 = {0.f, 0.f, 0.f, 0.f};
        acc0 = __builtin_amdgcn_mfma_f32_16x16x32_f16(a0.h, B00, acc0, 0, 0, 0);
        acc0 = __builtin_amdgcn_mfma_f32_16x16x32_f16(a1.h, B01, acc0, 0, 0, 0);
        acc1 = __builtin_amdgcn_mfma_f32_16x16x32_f16(a0.h, B10, acc1, 0, 0, 0);
        acc1 = __builtin_amdgcn_mfma_f32_16x16x32_f16(a1.h, B11, acc1, 0, 0, 0);
        float z[4];
#pragma unroll
        for (int rr = 0; rr < 4; ++rr) {
            z[rr] = w3a * fmaxf(acc0[rr] + b2a, 0.f) + w3b * fmaxf(acc1[rr] + b2b, 0.f);
            z[rr] += __shfl_xor(z[rr], 1, 64);
            z[rr] += __shfl_xor(z[rr], 2, 64);
            z[rr] += __shfl_xor(z[rr], 4, 64);
            z[rr] += __shfl_xor(z[rr], 8, 64);
        }
        if (m == 0) {
#pragma unroll
            for (int rr = 0; rr < 4; ++rr) {
                float p = 1.f / (1.f + __expf(-(z[rr] + b3v)));
                tmpP[base + (q << 2) + rr] = p;   // coalesced (16 B per lane)
            }
        }
    }
}

// final: out[e] = tmpP[iperm[e]] (coalesced read+write; tmpP gather is L2-resident)
__global__ void k_out(const int* __restrict__ iperm, const float* __restrict__ tmpP,
                      void* __restrict__ outv, const int* __restrict__ flag) {
    int e = blockIdx.x * 256 + threadIdx.x;
    if (e >= N_EDGES) return;
    float p = tmpP[iperm[e]];
    if (*flag) ((float*)outv)[e] = p;
    else       ((unsigned short*)outv)[e] = f2bu(p);
}

// ---------------- launch ----------------

extern "C" void kernel_launch(void* const* d_in, const int* in_sizes, int n_in,
                              void* d_out, int out_size, void* d_ws, size_t ws_size,
                              hipStream_t stream) {
    (void)in_sizes; (void)n_in; (void)out_size; (void)ws_size;
    const void* x_r   = d_in[0];
    const int*  ei    = (const int*)d_in[1];
    const void* ew_r  = d_in[2];

    char* w = (char*)d_ws;
    float* h            = (float*)w;          w += (size_t)NH * 4;       // 12.8 MB
    unsigned short* hbf = (unsigned short*)w; w += (size_t)NH * 2;       // 6.4 (split [2][N][32])
    char* txr           = w;                  w += (size_t)NH * 8;       // 25.6 (4 bufs)
    unsigned int* pairs4 = (unsigned int*)w;  w += (size_t)N_EDGES * 4;  // 6.4
    unsigned int* rc    = (unsigned int*)w;   w += (size_t)N_EDGES * 4;  // 6.4 (adjacent!)
    int* iperm          = (int*)w;            w += (size_t)N_EDGES * 4;  // 6.4
    int* row_ptr        = (int*)w;            w += 200192;
    int* cnt            = (int*)w;            w += 200192;
    float* dis          = (float*)w;          w += 200192;
    float* dis2         = (float*)w;          w += 200192;
    float* cWin = (float*)w; w += 2048;
    float* cbin = (float*)w; w += 256;
    float* ccW1 = (float*)w; w += 26112;
    float* ccb1 = (float*)w; w += 384;
    float* ccW2 = (float*)w; w += 2304;
    float* ccb2 = (float*)w; w += 128;
    float* clns = (float*)w; w += 768;
    float* clnb = (float*)w; w += 768;
    float* ceW1 = (float*)w; w += 32768;
    float* ceb1 = (float*)w; w += 256;
    float* ceW2 = (float*)w; w += 8192;
    float* ceb2 = (float*)w; w += 128;
    float* ceW3 = (float*)w; w += 128;
    float* ceb3 = (float*)w; w += 128;
    int* bsum = (int*)w; w += 1024;
    int* bpre = (int*)w; w += 1024;
    char* zero_base = w;
    float* stats = (float*)w; w += 1024;
    float* deg   = (float*)w; w += 200192;     // zeroed every launch
    size_t zero_bytes = (size_t)(w - zero_base);
    float* coeffs = (float*)w; w += 128;
    int*   flag   = (int*)w;   w += 128;

    // setup-phase overlays (lifetimes disjoint with hosts):
    //  pcnt8  (12.8 MB) -> [pairs4|rc] contiguous region  [hist_row -> merge; dead before placeA writes pairs4]
    //  pref16 (25.6 MB) -> txr                             [merge -> placeA]
    //  tmpP   (6.4 MB)  -> pairs4 region                   [edgepred -> k_out; pairs4 dead]
    unsigned int* pcnt_u32 = (unsigned int*)pairs4;
    unsigned char* pcnt8   = (unsigned char*)pairs4;
    unsigned short* pref16 = (unsigned short*)txr;
    float* tmpP            = (float*)pairs4;

    unsigned short* tx[4];
    for (int k = 0; k < 4; ++k) tx[k] = (unsigned short*)txr + (size_t)k * NH;
    unsigned short* ub = tx[0];   // k_uv runs after last spmm_ln: tx dead
    unsigned short* vb = tx[1];

    (void)hipMemsetAsync(zero_base, 0, zero_bytes, stream);

    k_detect<<<1, 64, 0, stream>>>(ew_r, flag);

    ConvArgs ca;
    const void* srcs[14] = {d_in[3], d_in[4], d_in[5], d_in[6], d_in[7], d_in[8], d_in[9],
                            d_in[10], d_in[11], d_in[12], d_in[13], d_in[14], d_in[15], d_in[16]};
    float* dsts[14] = {cWin, cbin, ccW1, ccb1, ccW2, ccb2, clns,
                       clnb, ceW1, ceb1, ceW2, ceb2, ceW3, ceb3};
    int sizes[14] = {512, 64, 6528, 96, 576, 18, 192, 192, 8192, 64, 2048, 32, 32, 1};
    int c = 0;
    for (int i = 0; i < 14; ++i) { ca.src[i] = srcs[i]; ca.dst[i] = dsts[i]; ca.cum[i] = c; c += sizes[i]; }
    ca.cum[14] = c;
    k_conv_small<<<(c + 255) / 256, 256, 0, stream>>>(ca, flag);

    k_deg<<<6250, 256, 0, stream>>>(ei, ew_r, flag, deg);
    k_hist_row<<<RSLC, 256, 0, stream>>>(ei, pcnt_u32);
    k_merge<<<196, 256, 0, stream>>>(pcnt8, deg, cnt, dis, dis2, pref16, bsum);
    k_scan_top<<<1, 256, 0, stream>>>(bsum, bpre, row_ptr);
    k_scan_fin<<<196, 256, 0, stream>>>(cnt, bpre, row_ptr);
    k_placeA<<<RSLC, 256, 0, stream>>>(ei, ew_r, flag, row_ptr, pref16, pairs4, iperm);
    k_rc<<<12500, 256, 0, stream>>>(row_ptr, pairs4, rc);
    k_inproj<<<12500, 256, 0, stream>>>(x_r, cWin, cbin, dis, h, hbf, flag);

    for (int l = 0; l < NLAYERS; ++l) {
        k_stats<<<400, 256, 0, stream>>>(h, stats + l * 80);
        k_coeffs<<<1, 64, 0, stream>>>(stats + l * 80, ccW1, ccb1, ccW2, ccb2, l,
                                       coeffs + l * 8);
        // hops 1-4: XCD-split kernels; hop4 writes full layout for spmm_ln's gather
        k_spmm<<<25000, 256, 0, stream>>>(hbf,   tx[0], row_ptr, pairs4, dis2, 0);
        k_spmm<<<25000, 256, 0, stream>>>(tx[0], tx[1], row_ptr, pairs4, dis2, 0);
        k_spmm<<<25000, 256, 0, stream>>>(tx[1], tx[2], row_ptr, pairs4, dis2, 0);
        k_spmm<<<25000, 256, 0, stream>>>(tx[2], tx[3], row_ptr, pairs4, dis2, 1);
        k_spmm_ln<<<12500, 256, 0, stream>>>(tx[3], row_ptr, pairs4, h, hbf,
                                             tx[0], tx[1], tx[2], tx[3],
                                             coeffs + l * 8, dis, clns, clnb, l,
                                             (l == NLAYERS - 1) ? 1 : 0, d_out, flag);
    }

    k_uv<<<12500, 256, 0, stream>>>(h, ceW1, ub, vb);
    k_edgepred<<<1563, 256, 0, stream>>>(ub, vb, rc, ceb1, ceW2, ceb2, ceW3, ceb3, tmpP);
    k_out<<<6250, 256, 0, stream>>>(iperm, tmpP, d_out, flag);
}

// Round 8
// 869.621 us; speedup vs baseline: 1.1962x; 1.1962x over previous
//
#include <hip/hip_runtime.h>
#include <hip/hip_bf16.h>
#include <hip/hip_fp16.h>

typedef __hip_bfloat16 bf16;
typedef __attribute__((ext_vector_type(8))) short short8;
typedef __attribute__((ext_vector_type(8))) _Float16 half8;
typedef __attribute__((ext_vector_type(2))) _Float16 half2v;
typedef __attribute__((ext_vector_type(4))) float f32x4;

#define N_NODES 50000
#define N_EDGES 1600000
#define FIN 8
#define HD 64
#define NH (N_NODES * HD)
#define NLAYERS 3

// CSR build geometry
#define RSLC 256                 // row slices, E/RSLC = 6250
#define EPR (N_EDGES / RSLC)
#define NWORDS 12500             // 50000 nodes as packed u8 in u32
#define DEGSTR 50048             // deg replica stride (64-aligned)
#define NDEGR 4                  // deg replicas (sector-contention spread)

__device__ __forceinline__ float b2f(bf16 v) { return __bfloat162float(v); }
__device__ __forceinline__ float bu2f(unsigned int u) { return __uint_as_float(u << 16); }
__device__ __forceinline__ unsigned short f2bu(float f) {
    unsigned int x = __float_as_uint(f);
    unsigned int r = x + 0x7FFFu + ((x >> 16) & 1u);
    return (unsigned short)(r >> 16);
}
__device__ __forceinline__ unsigned short f2h(float f) {
    _Float16 h = (_Float16)f;
    return *(unsigned short*)&h;
}
// low 16 bits as fp16 -> float (single v_cvt_f32_f16)
union H16 { unsigned short b; _Float16 h; };
__device__ __forceinline__ float h16f(unsigned u) {
    H16 x; x.b = (unsigned short)u;
    return (float)x.h;
}

// ---------------- dtype detection ----------------
__global__ void k_detect(const void* __restrict__ ew, int* __restrict__ flag) {
    int ok = 1;
    for (int i = threadIdx.x; i < 512; i += 64) {
        float v = b2f(((const bf16*)ew)[i]);
        if (!(v >= 0.f && v <= 1.f)) ok = 0;
    }
    unsigned long long m = __ballot(ok);
    if (threadIdx.x == 0) *flag = (m == 0xFFFFFFFFFFFFFFFFull) ? 0 : 1;
}

struct ConvArgs {
    const void* src[14];
    float* dst[14];
    int cum[15];
};

__global__ void k_conv_small(ConvArgs a, const int* __restrict__ flag) {
    int q = blockIdx.x * 256 + threadIdx.x;
    if (q >= a.cum[14]) return;
    int s = 0;
    while (q >= a.cum[s + 1]) ++s;
    int off = q - a.cum[s];
    if (*flag) a.dst[s][off] = ((const float*)a.src[s])[off];
    else       a.dst[s][off] = bu2f(((const unsigned short*)a.src[s])[off]);
}

// ---------------- CSR build: byte-packed LDS histograms, no global atomics ----------------

__global__ void __launch_bounds__(256) k_hist_row(const int* __restrict__ ei,
                                                  unsigned int* __restrict__ pcnt_u32) {
    __shared__ unsigned int sm[NWORDS];
    int b = blockIdx.x, t = threadIdx.x;
    for (int i = t; i < NWORDS; i += 256) sm[i] = 0;
    __syncthreads();
    int ebase = b * EPR;
    for (int el = t; el < EPR; el += 256) {
        int r = ei[ebase + el];
        atomicAdd(&sm[r >> 2], 1u << ((r & 3) * 8));
    }
    __syncthreads();
    unsigned int* dst = pcnt_u32 + (size_t)b * NWORDS;
    for (int i = t; i < NWORDS; i += 256) dst[i] = sm[i];
}

// per-node: 256-slice u8 prefix -> pref16, total -> cnt, block sums (CSR only; deg moved out)
__global__ void k_merge(const unsigned char* __restrict__ pcnt8,
                        int* __restrict__ cnt,
                        unsigned short* __restrict__ pref16, int* __restrict__ bsum) {
    __shared__ int red[256];
    int t = threadIdx.x;
    int n = blockIdx.x * 256 + t;
    int run = 0;
    if (n < N_NODES) {
#pragma unroll 8
        for (int s = 0; s < RSLC; ++s) {
            pref16[(size_t)s * N_NODES + n] = (unsigned short)run;
            run += pcnt8[(size_t)s * N_NODES + n];
        }
        cnt[n] = run;
    }
    red[t] = run;
    __syncthreads();
    for (int off = 128; off; off >>= 1) {
        if (t < off) red[t] += red[t + off];
        __syncthreads();
    }
    if (t == 0) bsum[blockIdx.x] = red[0];
}

__global__ void k_scan_top(const int* __restrict__ bsum, int* __restrict__ bpre,
                           int* __restrict__ row_ptr) {
    __shared__ int sm[256];
    int t = threadIdx.x;
    int v = (t < 196) ? bsum[t] : 0;
    sm[t] = v;
    __syncthreads();
    int val = v;
    for (int off = 1; off < 256; off <<= 1) {
        int other = (t >= off) ? sm[t - off] : 0;
        __syncthreads();
        val += other;
        sm[t] = val;
        __syncthreads();
    }
    bpre[t] = val - v;
    if (t == 0) row_ptr[N_NODES] = N_EDGES;
}

__global__ void k_scan_fin(const int* __restrict__ cnt, const int* __restrict__ bpre,
                           int* __restrict__ row_ptr) {
    __shared__ int sm[256];
    int t = threadIdx.x;
    int n = blockIdx.x * 256 + t;
    int v = (n < N_NODES) ? cnt[n] : 0;
    sm[t] = v;
    __syncthreads();
    int val = v;
    for (int off = 1; off < 256; off <<= 1) {
        int other = (t >= off) ? sm[t - off] : 0;
        __syncthreads();
        val += other;
        sm[t] = val;
        __syncthreads();
    }
    if (n < N_NODES) row_ptr[n] = bpre[blockIdx.x] + val - v;
}

// placement + FUSED degree: per-slice u8 ordinal in LDS; writes pairs4[pos]=(c<<16|w_fp16)
// scattered (4 B) + iperm[e]=pos coalesced + deg atomicAdd (4 replicas, sector-spread).
// The no-return atomics issue async and their ~100 us backend drain overlaps placeA's own
// LDS/scatter work instead of costing a standalone kernel (r6: k_deg was 100 us, 0.3% VALU).
__global__ void __launch_bounds__(256) k_placeA(const int* __restrict__ ei,
                                                const void* __restrict__ ewr,
                                                const int* __restrict__ flag,
                                                const int* __restrict__ row_ptr,
                                                const unsigned short* __restrict__ pref16,
                                                unsigned int* __restrict__ pairs4,
                                                int* __restrict__ iperm,
                                                float* __restrict__ deg4) {
    __shared__ unsigned int sm[NWORDS];
    int b = blockIdx.x, t = threadIdx.x;
    for (int i = t; i < NWORDS; i += 256) sm[i] = 0;
    __syncthreads();
    int f32 = *flag;
    int ebase = b * EPR;
    const unsigned short* pr = pref16 + (size_t)b * N_NODES;
    for (int el = t; el < EPR; el += 256) {
        int e = ebase + el;
        int r = ei[e];
        int c = ei[N_EDGES + e];
        float w = f32 ? ((const float*)ewr)[e] : bu2f(((const unsigned short*)ewr)[e]);
        atomicAdd(&deg4[(size_t)(e & (NDEGR - 1)) * DEGSTR + c], w);
        int sh = (r & 3) * 8;
        unsigned old = atomicAdd(&sm[r >> 2], 1u << sh);
        int ord = (old >> sh) & 0xFF;
        int pos = row_ptr[r] + pr[r] + ord;
        pairs4[pos] = ((unsigned)c << 16) | (unsigned)f2h(w);  // scattered 4 B
        iperm[e] = pos;                                        // coalesced
    }
}

// rc rebuild: wave per node, coalesced read of pairs4 + coalesced write of rc
__global__ void __launch_bounds__(256) k_rc(const int* __restrict__ row_ptr,
                                            const unsigned int* __restrict__ pairs4,
                                            unsigned int* __restrict__ rc) {
    int lane = threadIdx.x & 63;
    int wv = __builtin_amdgcn_readfirstlane((int)(blockIdx.x * 4 + (threadIdx.x >> 6)));
    int s = __builtin_amdgcn_readfirstlane(row_ptr[wv]);
    int e = __builtin_amdgcn_readfirstlane(row_ptr[wv + 1]);
    unsigned rhi = ((unsigned)wv) << 16;
    for (int pos = s + lane; pos < e; pos += 64)
        rc[pos] = (pairs4[pos] >> 16) | rhi;
}

// dis/dis2 from the 4 deg replicas (streaming, trivial)
__global__ void k_dis(const float* __restrict__ deg4,
                      float* __restrict__ dis, float* __restrict__ dis2) {
    int n = blockIdx.x * 256 + threadIdx.x;
    if (n >= N_NODES) return;
    float d = deg4[n] + deg4[DEGSTR + n] + deg4[2 * DEGSTR + n] + deg4[3 * DEGSTR + n];
    float di = fminf(rsqrtf(d), 1e6f);   // rsqrt(0)=inf -> 1e6, matches ref clamp
    dis[n] = di;
    dis2[n] = di * di;
}

// ---------------- input projection: h (f32, unscaled) + hbf = bf16(dis*h) scaled state ----

__global__ void k_inproj(const void* __restrict__ xr_, const float* __restrict__ W,
                         const float* __restrict__ b, const float* __restrict__ dis,
                         float* __restrict__ h,
                         unsigned short* __restrict__ h_bf, const int* __restrict__ flag) {
    __shared__ float Wt[FIN * HD];
    __shared__ float bs[HD];
    int t = threadIdx.x;
    int f32 = *flag;
    for (int idx = t; idx < FIN * HD; idx += 256) {
        int f = idx >> 3, j = idx & 7;
        Wt[j * 64 + f] = W[idx];
    }
    if (t < 64) bs[t] = b[t];
    __syncthreads();
    int gid = blockIdx.x * 256 + t;
    if (gid < NH) {
        int i = gid >> 6, f = gid & 63;
        const float* xf = (const float*)xr_ + i * FIN;
        const unsigned short* xb = (const unsigned short*)xr_ + i * FIN;
        float acc = bs[f];
#pragma unroll
        for (int j = 0; j < FIN; ++j) {
            float xv = f32 ? xf[j] : bu2f(xb[j]);
            acc += xv * Wt[j * 64 + f];
        }
        h[gid] = acc;
        h_bf[gid] = f2bu(acc * dis[i]);   // scaled state s0 = dis .* h
    }
}

// ---------------- stats + coefficient MLP ----------------

__global__ void k_stats(const float* __restrict__ h, float* __restrict__ stats) {
    __shared__ float ssum[256], ssq[256];
    int t = threadIdx.x;
    float ls = 0.f, lq = 0.f;
    for (int idx = blockIdx.x * 256 + t; idx < NH; idx += 102400) {
        float v = h[idx];
        ls += v; lq += v * v;
    }
    ssum[t] = ls; ssq[t] = lq;
    __syncthreads();
    if (t < 64) {
        float a = ssum[t] + ssum[t + 64] + ssum[t + 128] + ssum[t + 192];
        atomicAdd(&stats[t], a);
        float q = ssq[t] + ssq[t + 64] + ssq[t + 128] + ssq[t + 192];
        for (int off = 32; off; off >>= 1) q += __shfl_down(q, off, 64);
        if (t == 0) atomicAdd(&stats[64], q);
    }
}

__global__ void k_coeffs(const float* __restrict__ stats,
                         const float* __restrict__ W1, const float* __restrict__ b1,
                         const float* __restrict__ W2, const float* __restrict__ b2,
                         int layer, float* __restrict__ coeffs) {
    __shared__ float ci[68];
    __shared__ float hid[32];
    __shared__ float lg[6];
    int t = threadIdx.x;
    float sf = stats[t];
    float tot = sf;
    for (int off = 1; off < 64; off <<= 1) tot += __shfl_xor(tot, off, 64);
    ci[t] = sf / (float)N_NODES;
    if (t == 0) {
        float sumsq = stats[64];
        float mean = tot / (float)NH;
        float var = (sumsq - (float)NH * mean * mean) / (float)(NH - 1);
        ci[64] = mean;
        ci[65] = sqrtf(fmaxf(var, 0.f));
        ci[66] = (float)N_NODES;
        ci[67] = (float)N_EDGES;
    }
    __syncthreads();
    if (t < 32) {
        float a = b1[layer * 32 + t];
        const float* wr = W1 + (layer * 32 + t) * 68;
        for (int j = 0; j < 68; ++j) a += ci[j] * wr[j];
        hid[t] = fmaxf(a, 0.f);
    }
    __syncthreads();
    if (t < 6) {
        float a = b2[layer * 6 + t];
        const float* wr = W2 + (layer * 6 + t) * 32;
        for (int g = 0; g < 32; ++g) a += hid[g] * wr[g];
        lg[t] = a;
    }
    __syncthreads();
    if (t == 0) {
        float mx = lg[0];
        for (int p = 1; p < 6; ++p) mx = fmaxf(mx, lg[p]);
        float s = 0.f, e[6];
        for (int p = 0; p < 6; ++p) { e[p] = expf(lg[p] - mx); s += e[p]; }
        for (int p = 0; p < 6; ++p) coeffs[p] = e[p] / s;
    }
}

// ---------------- SpMM hop: wave per node, scalar pair loads, 16-deep gather unroll -------
// scaled-state algebra: s_{k+1}[r] = dis2[r] * sum_e w_e * s_k[col]
// (measured-good structure, r6 = 922 us; two XCD-split variants both regressed — keep this.)

__device__ __forceinline__ float acc_range(const unsigned short* __restrict__ txo,
                                           const unsigned int* __restrict__ pairs4,
                                           int j0, int j1, int lane, float acc) {
    int j = j0;
    for (; j + 15 < j1; j += 16) {
        unsigned p0 = pairs4[j],      p1 = pairs4[j + 1],  p2 = pairs4[j + 2],  p3 = pairs4[j + 3];
        unsigned p4 = pairs4[j + 4],  p5 = pairs4[j + 5],  p6 = pairs4[j + 6],  p7 = pairs4[j + 7];
        unsigned p8 = pairs4[j + 8],  p9 = pairs4[j + 9],  pa = pairs4[j + 10], pb = pairs4[j + 11];
        unsigned pc = pairs4[j + 12], pd = pairs4[j + 13], pe = pairs4[j + 14], pf = pairs4[j + 15];
        float g0 = bu2f(txo[(p0 >> 16) * 64 + lane]);
        float g1 = bu2f(txo[(p1 >> 16) * 64 + lane]);
        float g2 = bu2f(txo[(p2 >> 16) * 64 + lane]);
        float g3 = bu2f(txo[(p3 >> 16) * 64 + lane]);
        float g4 = bu2f(txo[(p4 >> 16) * 64 + lane]);
        float g5 = bu2f(txo[(p5 >> 16) * 64 + lane]);
        float g6 = bu2f(txo[(p6 >> 16) * 64 + lane]);
        float g7 = bu2f(txo[(p7 >> 16) * 64 + lane]);
        float g8 = bu2f(txo[(p8 >> 16) * 64 + lane]);
        float g9 = bu2f(txo[(p9 >> 16) * 64 + lane]);
        float ga = bu2f(txo[(pa >> 16) * 64 + lane]);
        float gb = bu2f(txo[(pb >> 16) * 64 + lane]);
        float gc = bu2f(txo[(pc >> 16) * 64 + lane]);
        float gd = bu2f(txo[(pd >> 16) * 64 + lane]);
        float ge = bu2f(txo[(pe >> 16) * 64 + lane]);
        float gf = bu2f(txo[(pf >> 16) * 64 + lane]);
        acc += h16f(p0) * g0 + h16f(p1) * g1 + h16f(p2) * g2 + h16f(p3) * g3;
        acc += h16f(p4) * g4 + h16f(p5) * g5 + h16f(p6) * g6 + h16f(p7) * g7;
        acc += h16f(p8) * g8 + h16f(p9) * g9 + h16f(pa) * ga + h16f(pb) * gb;
        acc += h16f(pc) * gc + h16f(pd) * gd + h16f(pe) * ge + h16f(pf) * gf;
    }
    for (; j + 7 < j1; j += 8) {
        unsigned p0 = pairs4[j],     p1 = pairs4[j + 1], p2 = pairs4[j + 2], p3 = pairs4[j + 3];
        unsigned p4 = pairs4[j + 4], p5 = pairs4[j + 5], p6 = pairs4[j + 6], p7 = pairs4[j + 7];
        float g0 = bu2f(txo[(p0 >> 16) * 64 + lane]);
        float g1 = bu2f(txo[(p1 >> 16) * 64 + lane]);
        float g2 = bu2f(txo[(p2 >> 16) * 64 + lane]);
        float g3 = bu2f(txo[(p3 >> 16) * 64 + lane]);
        float g4 = bu2f(txo[(p4 >> 16) * 64 + lane]);
        float g5 = bu2f(txo[(p5 >> 16) * 64 + lane]);
        float g6 = bu2f(txo[(p6 >> 16) * 64 + lane]);
        float g7 = bu2f(txo[(p7 >> 16) * 64 + lane]);
        acc += h16f(p0) * g0 + h16f(p1) * g1 + h16f(p2) * g2 + h16f(p3) * g3;
        acc += h16f(p4) * g4 + h16f(p5) * g5 + h16f(p6) * g6 + h16f(p7) * g7;
    }
    for (; j < j1; ++j) {
        unsigned p = pairs4[j];
        acc += h16f(p) * bu2f(txo[(p >> 16) * 64 + lane]);
    }
    return acc;
}

__global__ void __launch_bounds__(256) k_spmm(
    const unsigned short* __restrict__ txo, unsigned short* __restrict__ txn,
    const int* __restrict__ row_ptr, const unsigned int* __restrict__ pairs4,
    const float* __restrict__ dis2) {
    int lane = threadIdx.x & 63;
    int wv = __builtin_amdgcn_readfirstlane((int)(blockIdx.x * 4 + (threadIdx.x >> 6)));
    int s = __builtin_amdgcn_readfirstlane(row_ptr[wv]);
    int e = __builtin_amdgcn_readfirstlane(row_ptr[wv + 1]);
    float acc = acc_range(txo, pairs4, s, e, lane, 0.f);
    float d2 = dis2[wv];
    txn[wv * 64 + lane] = f2bu(acc * d2);
}

// ---------------- fused last hop + polynomial combine + layernorm ----------------
// t1..t4 hold scaled s_k; tx_k = s_k / dis[r]; hop5: tx5 = dis[r] * acc

__global__ void __launch_bounds__(256) k_spmm_ln(
    const unsigned short* __restrict__ txo,
    const int* __restrict__ row_ptr, const unsigned int* __restrict__ pairs4,
    float* __restrict__ h, unsigned short* __restrict__ h_bf,
    const unsigned short* __restrict__ t1, const unsigned short* __restrict__ t2,
    const unsigned short* __restrict__ t3, const unsigned short* __restrict__ t4,
    const float* __restrict__ coeffs, const float* __restrict__ dis,
    const float* __restrict__ sc, const float* __restrict__ bi,
    int layer, int last, void* __restrict__ outv, const int* __restrict__ flag) {
    int lane = threadIdx.x & 63;
    int wv = __builtin_amdgcn_readfirstlane((int)(blockIdx.x * 4 + (threadIdx.x >> 6)));
    int s = __builtin_amdgcn_readfirstlane(row_ptr[wv]);
    int e = __builtin_amdgcn_readfirstlane(row_ptr[wv + 1]);
    float acc = acc_range(txo, pairs4, s, e, lane, 0.f);
    int o = wv * 64 + lane;
    float ds = dis[wv];
    float invd = 1.f / ds;
    float c0 = coeffs[0], c1 = coeffs[1], c2 = coeffs[2],
          c3 = coeffs[3], c4 = coeffs[4], c5 = coeffs[5];
    float v = (1.f + c0) * h[o] +
              invd * (c1 * bu2f(t1[o]) + c2 * bu2f(t2[o]) +
                      c3 * bu2f(t3[o]) + c4 * bu2f(t4[o])) +
              c5 * ds * acc;
    float m = v;
    for (int off = 1; off < 64; off <<= 1) m += __shfl_xor(m, off, 64);
    m *= (1.f / 64.f);
    float d = v - m;
    float q = d * d;
    for (int off = 1; off < 64; off <<= 1) q += __shfl_xor(q, off, 64);
    float var = q * (1.f / 64.f);
    float y = d / sqrtf(var + 1e-5f) * sc[layer * 64 + lane] + bi[layer * 64 + lane];
    h[o] = y;
    h_bf[o] = f2bu(y * ds);   // next layer's scaled state s0
    if (last) {
        if (*flag) ((float*)outv)[N_EDGES + o] = y;
        else       ((unsigned short*)outv)[N_EDGES + o] = f2bu(y);
    }
}

// ---------------- edge predictor (fp16) ----------------

__global__ void __launch_bounds__(256) k_uv(const float* __restrict__ h,
                                            const float* __restrict__ W1,
                                            unsigned short* __restrict__ ub,
                                            unsigned short* __restrict__ vb) {
    __shared__ float Wt[128 * 65];
    __shared__ float hs[4 * 64];
    int t = threadIdx.x;
    for (int idx = t; idx < 8192; idx += 256) {
        int f = idx >> 7, j = idx & 127;
        Wt[j * 65 + f] = W1[idx];
    }
    int node0 = blockIdx.x * 4;
    hs[t] = h[node0 * 64 + t];
    __syncthreads();
    int ni = t >> 6, f = t & 63;
    const float* hr = hs + ni * 64;
    float au = 0.f, av = 0.f;
#pragma unroll 8
    for (int j = 0; j < 64; ++j) {
        float xv = hr[j];
        au += Wt[j * 65 + f] * xv;
        av += Wt[(j + 64) * 65 + f] * xv;
    }
    int i = node0 + ni;
    ub[i * 64 + f] = f2h(au);   // fp16 bits
    vb[i * 64 + f] = f2h(av);
}

// packed fp16 relu(u + v + b) via native _Float16 vectors (avoids __hmax2 overload clash)
__device__ __forceinline__ unsigned h2rel(unsigned uu, unsigned vv, half2v b) {
    half2v a = *(half2v*)&uu + *(half2v*)&vv + b;
    a[0] = a[0] > (_Float16)0 ? a[0] : (_Float16)0;
    a[1] = a[1] > (_Float16)0 ? a[1] : (_Float16)0;
    return *(unsigned*)&a;
}

union U4H8 { uint4 u; half8 h; };

// MFMA f16 edge predictor: 16 CSR-ordered edges per wave-iteration; coalesced tmp output
__global__ void __launch_bounds__(256) k_edgepred(
    const unsigned short* __restrict__ ub, const unsigned short* __restrict__ vb,
    const unsigned int* __restrict__ rc,
    const float* __restrict__ eb1, const float* __restrict__ eW2,
    const float* __restrict__ eb2, const float* __restrict__ eW3,
    const float* __restrict__ eb3, float* __restrict__ tmpP) {
    int t = threadIdx.x;
    int lane = t & 63;
    int m = lane & 15, q = lane >> 4;

    half8 B00, B01, B10, B11;
#pragma unroll
    for (int j = 0; j < 8; ++j) {
        B00[j] = (_Float16)eW2[(m) * 64      + q * 8 + j];
        B01[j] = (_Float16)eW2[(m) * 64 + 32 + q * 8 + j];
        B10[j] = (_Float16)eW2[(m + 16) * 64      + q * 8 + j];
        B11[j] = (_Float16)eW2[(m + 16) * 64 + 32 + q * 8 + j];
    }
    half2v b1p0[4], b1p1[4];
#pragma unroll
    for (int wq = 0; wq < 4; ++wq) {
        b1p0[wq][0] = (_Float16)eb1[q * 8 + 2 * wq];
        b1p0[wq][1] = (_Float16)eb1[q * 8 + 2 * wq + 1];
        b1p1[wq][0] = (_Float16)eb1[32 + q * 8 + 2 * wq];
        b1p1[wq][1] = (_Float16)eb1[32 + q * 8 + 2 * wq + 1];
    }
    float w3a = eW3[m], w3b = eW3[16 + m];
    float b2a = eb2[m], b2b = eb2[16 + m];
    float b3v = eb3[0];

    int gw = blockIdx.x * 4 + (t >> 6);
    const int NW = 1563 * 4;
    for (int tile = gw; tile < N_EDGES / 16; tile += NW) {
        int base = tile << 4;
        unsigned rcv = rc[base + m];
        int col = rcv & 0xFFFF;
        int row = rcv >> 16;
        const unsigned short* up = ub + row * 64;
        const unsigned short* vp = vb + col * 64;
        uint4 U0 = *(const uint4*)(up + q * 8);
        uint4 U1 = *(const uint4*)(up + 32 + q * 8);
        uint4 V0 = *(const uint4*)(vp + q * 8);
        uint4 V1 = *(const uint4*)(vp + 32 + q * 8);
        U4H8 a0, a1;
        a0.u.x = h2rel(U0.x, V0.x, b1p0[0]);
        a0.u.y = h2rel(U0.y, V0.y, b1p0[1]);
        a0.u.z = h2rel(U0.z, V0.z, b1p0[2]);
        a0.u.w = h2rel(U0.w, V0.w, b1p0[3]);
        a1.u.x = h2rel(U1.x, V1.x, b1p1[0]);
        a1.u.y = h2rel(U1.y, V1.y, b1p1[1]);
        a1.u.z = h2rel(U1.z, V1.z, b1p1[2]);
        a1.u.w = h2rel(U1.w, V1.w, b1p1[3]);
        f32x4 acc0 = {0.f, 0.f, 0.f, 0.f};
        f32x4 acc1 = {0.f, 0.f, 0.f, 0.f};
        acc0 = __builtin_amdgcn_mfma_f32_16x16x32_f16(a0.h, B00, acc0, 0, 0, 0);
        acc0 = __builtin_amdgcn_mfma_f32_16x16x32_f16(a1.h, B01, acc0, 0, 0, 0);
        acc1 = __builtin_amdgcn_mfma_f32_16x16x32_f16(a0.h, B10, acc1, 0, 0, 0);
        acc1 = __builtin_amdgcn_mfma_f32_16x16x32_f16(a1.h, B11, acc1, 0, 0, 0);
        float z[4];
#pragma unroll
        for (int rr = 0; rr < 4; ++rr) {
            z[rr] = w3a * fmaxf(acc0[rr] + b2a, 0.f) + w3b * fmaxf(acc1[rr] + b2b, 0.f);
            z[rr] += __shfl_xor(z[rr], 1, 64);
            z[rr] += __shfl_xor(z[rr], 2, 64);
            z[rr] += __shfl_xor(z[rr], 4, 64);
            z[rr] += __shfl_xor(z[rr], 8, 64);
        }
        if (m == 0) {
#pragma unroll
            for (int rr = 0; rr < 4; ++rr) {
                float p = 1.f / (1.f + __expf(-(z[rr] + b3v)));
                tmpP[base + (q << 2) + rr] = p;   // coalesced (16 B per lane)
            }
        }
    }
}

// final: out[e] = tmpP[iperm[e]] (coalesced read+write; tmpP gather is L2-resident)
__global__ void k_out(const int* __restrict__ iperm, const float* __restrict__ tmpP,
                      void* __restrict__ outv, const int* __restrict__ flag) {
    int e = blockIdx.x * 256 + threadIdx.x;
    if (e >= N_EDGES) return;
    float p = tmpP[iperm[e]];
    if (*flag) ((float*)outv)[e] = p;
    else       ((unsigned short*)outv)[e] = f2bu(p);
}

// ---------------- launch ----------------

extern "C" void kernel_launch(void* const* d_in, const int* in_sizes, int n_in,
                              void* d_out, int out_size, void* d_ws, size_t ws_size,
                              hipStream_t stream) {
    (void)in_sizes; (void)n_in; (void)out_size; (void)ws_size;
    const void* x_r   = d_in[0];
    const int*  ei    = (const int*)d_in[1];
    const void* ew_r  = d_in[2];

    char* w = (char*)d_ws;
    float* h            = (float*)w;          w += (size_t)NH * 4;       // 12.8 MB
    unsigned short* hbf = (unsigned short*)w; w += (size_t)NH * 2;       // 6.4
    char* txr           = w;                  w += (size_t)NH * 8;       // 25.6 (4 bufs)
    unsigned int* pairs4 = (unsigned int*)w;  w += (size_t)N_EDGES * 4;  // 6.4
    unsigned int* rc    = (unsigned int*)w;   w += (size_t)N_EDGES * 4;  // 6.4 (adjacent!)
    int* iperm          = (int*)w;            w += (size_t)N_EDGES * 4;  // 6.4
    int* row_ptr        = (int*)w;            w += 200192;
    int* cnt            = (int*)w;            w += 200192;
    float* dis          = (float*)w;          w += 200192;
    float* dis2         = (float*)w;          w += 200192;
    float* cWin = (float*)w; w += 2048;
    float* cbin = (float*)w; w += 256;
    float* ccW1 = (float*)w; w += 26112;
    float* ccb1 = (float*)w; w += 384;
    float* ccW2 = (float*)w; w += 2304;
    float* ccb2 = (float*)w; w += 128;
    float* clns = (float*)w; w += 768;
    float* clnb = (float*)w; w += 768;
    float* ceW1 = (float*)w; w += 32768;
    float* ceb1 = (float*)w; w += 256;
    float* ceW2 = (float*)w; w += 8192;
    float* ceb2 = (float*)w; w += 128;
    float* ceW3 = (float*)w; w += 128;
    float* ceb3 = (float*)w; w += 128;
    int* bsum = (int*)w; w += 1024;
    int* bpre = (int*)w; w += 1024;
    char* zero_base = w;
    float* stats = (float*)w; w += 1024;
    float* deg4  = (float*)w; w += (size_t)NDEGR * DEGSTR * 4;   // 800 KB, zeroed every launch
    size_t zero_bytes = (size_t)(w - zero_base);
    float* coeffs = (float*)w; w += 128;
    int*   flag   = (int*)w;   w += 128;

    // setup-phase overlays (lifetimes disjoint with hosts):
    //  pcnt8  (12.8 MB) -> [pairs4|rc] contiguous region  [hist_row -> merge; dead before placeA writes pairs4]
    //  pref16 (25.6 MB) -> txr                             [merge -> placeA]
    //  tmpP   (6.4 MB)  -> pairs4 region                   [edgepred -> k_out; pairs4 dead]
    unsigned int* pcnt_u32 = (unsigned int*)pairs4;
    unsigned char* pcnt8   = (unsigned char*)pairs4;
    unsigned short* pref16 = (unsigned short*)txr;
    float* tmpP            = (float*)pairs4;

    unsigned short* tx[4];
    for (int k = 0; k < 4; ++k) tx[k] = (unsigned short*)txr + (size_t)k * NH;
    unsigned short* ub = tx[0];   // k_uv runs after last spmm_ln: tx dead
    unsigned short* vb = tx[1];

    (void)hipMemsetAsync(zero_base, 0, zero_bytes, stream);

    k_detect<<<1, 64, 0, stream>>>(ew_r, flag);

    ConvArgs ca;
    const void* srcs[14] = {d_in[3], d_in[4], d_in[5], d_in[6], d_in[7], d_in[8], d_in[9],
                            d_in[10], d_in[11], d_in[12], d_in[13], d_in[14], d_in[15], d_in[16]};
    float* dsts[14] = {cWin, cbin, ccW1, ccb1, ccW2, ccb2, clns,
                       clnb, ceW1, ceb1, ceW2, ceb2, ceW3, ceb3};
    int sizes[14] = {512, 64, 6528, 96, 576, 18, 192, 192, 8192, 64, 2048, 32, 32, 1};
    int c = 0;
    for (int i = 0; i < 14; ++i) { ca.src[i] = srcs[i]; ca.dst[i] = dsts[i]; ca.cum[i] = c; c += sizes[i]; }
    ca.cum[14] = c;
    k_conv_small<<<(c + 255) / 256, 256, 0, stream>>>(ca, flag);

    k_hist_row<<<RSLC, 256, 0, stream>>>(ei, pcnt_u32);
    k_merge<<<196, 256, 0, stream>>>(pcnt8, cnt, pref16, bsum);
    k_scan_top<<<1, 256, 0, stream>>>(bsum, bpre, row_ptr);
    k_scan_fin<<<196, 256, 0, stream>>>(cnt, bpre, row_ptr);
    k_placeA<<<RSLC, 256, 0, stream>>>(ei, ew_r, flag, row_ptr, pref16, pairs4, iperm, deg4);
    k_rc<<<12500, 256, 0, stream>>>(row_ptr, pairs4, rc);
    k_dis<<<196, 256, 0, stream>>>(deg4, dis, dis2);
    k_inproj<<<12500, 256, 0, stream>>>(x_r, cWin, cbin, dis, h, hbf, flag);

    for (int l = 0; l < NLAYERS; ++l) {
        k_stats<<<400, 256, 0, stream>>>(h, stats + l * 80);
        k_coeffs<<<1, 64, 0, stream>>>(stats + l * 80, ccW1, ccb1, ccW2, ccb2, l,
                                       coeffs + l * 8);
        const unsigned short* src = hbf;
        for (int k = 0; k < 4; ++k) {
            k_spmm<<<12500, 256, 0, stream>>>(src, tx[k], row_ptr, pairs4, dis2);
            src = tx[k];
        }
        k_spmm_ln<<<12500, 256, 0, stream>>>(tx[3], row_ptr, pairs4, h, hbf,
                                             tx[0], tx[1], tx[2], tx[3],
                                             coeffs + l * 8, dis, clns, clnb, l,
                                             (l == NLAYERS - 1) ? 1 : 0, d_out, flag);
    }

    k_uv<<<12500, 256, 0, stream>>>(h, ceW1, ub, vb);
    k_edgepred<<<1563, 256, 0, stream>>>(ub, vb, rc, ceb1, ceW2, ceb2, ceW3, ceb3, tmpP);
    k_out<<<6250, 256, 0, stream>>>(iperm, tmpP, d_out, flag);
}

// Round 9
// 837.249 us; speedup vs baseline: 1.2424x; 1.0387x over previous
//
#include <hip/hip_runtime.h>
#include <hip/hip_bf16.h>
#include <hip/hip_fp16.h>

typedef __hip_bfloat16 bf16;
typedef __attribute__((ext_vector_type(8))) short short8;
typedef __attribute__((ext_vector_type(8))) _Float16 half8;
typedef __attribute__((ext_vector_type(2))) _Float16 half2v;
typedef __attribute__((ext_vector_type(4))) float f32x4;

#define N_NODES 50000
#define N_EDGES 1600000
#define FIN 8
#define HD 64
#define NH (N_NODES * HD)
#define NLAYERS 3

// CSR build geometry
#define RSLC 256                 // row slices, E/RSLC = 6250
#define EPR (N_EDGES / RSLC)
#define NWORDS 12500             // 50000 nodes as packed u8 in u32
// degree build: 128 slices, full-node u16 fixed-point LDS histogram (no global atomics)
#define DSLC2 128
#define EPD2 (N_EDGES / DSLC2)   // 12500
#define DWORDS 25000             // 50000 nodes as packed u16 in u32 (100 KB LDS)
#define DEGSCALE 512.0f

__device__ __forceinline__ float b2f(bf16 v) { return __bfloat162float(v); }
__device__ __forceinline__ float bu2f(unsigned int u) { return __uint_as_float(u << 16); }
__device__ __forceinline__ unsigned short f2bu(float f) {
    unsigned int x = __float_as_uint(f);
    unsigned int r = x + 0x7FFFu + ((x >> 16) & 1u);
    return (unsigned short)(r >> 16);
}
__device__ __forceinline__ unsigned short f2h(float f) {
    _Float16 h = (_Float16)f;
    return *(unsigned short*)&h;
}
// low 16 bits as fp16 -> float (single v_cvt_f32_f16)
union H16 { unsigned short b; _Float16 h; };
__device__ __forceinline__ float h16f(unsigned u) {
    H16 x; x.b = (unsigned short)u;
    return (float)x.h;
}

// ---------------- dtype detection ----------------
__global__ void k_detect(const void* __restrict__ ew, int* __restrict__ flag) {
    int ok = 1;
    for (int i = threadIdx.x; i < 512; i += 64) {
        float v = b2f(((const bf16*)ew)[i]);
        if (!(v >= 0.f && v <= 1.f)) ok = 0;
    }
    unsigned long long m = __ballot(ok);
    if (threadIdx.x == 0) *flag = (m == 0xFFFFFFFFFFFFFFFFull) ? 0 : 1;
}

struct ConvArgs {
    const void* src[14];
    float* dst[14];
    int cum[15];
};

__global__ void k_conv_small(ConvArgs a, const int* __restrict__ flag) {
    int q = blockIdx.x * 256 + threadIdx.x;
    if (q >= a.cum[14]) return;
    int s = 0;
    while (q >= a.cum[s + 1]) ++s;
    int off = q - a.cum[s];
    if (*flag) a.dst[s][off] = ((const float*)a.src[s])[off];
    else       a.dst[s][off] = bu2f(((const unsigned short*)a.src[s])[off]);
}

// ---------------- degree: LDS u16 fixed-point histogram, NO global atomics ----------------
// r8 measured: 1.6M scattered f32 global atomics = fixed ~100 us wall, occupancy-independent.
// Here: 128 blocks x 12500 edges; full 50000-node LDS table (u16 fp, scale 512, 2/u32, 100KB).
// Carry between packed halves needs >=128 edges on one node in one slice: P~0 (Poisson 0.25).
// Partials dumped (full, no pre-zero needed); k_dis sums 128 u16 slices EXACTLY in integer.
__global__ void __launch_bounds__(1024) k_deg2(const int* __restrict__ ei,
                                               const void* __restrict__ ewr,
                                               const int* __restrict__ flag,
                                               unsigned short* __restrict__ pdeg16) {
    __shared__ unsigned int sm[DWORDS];
    int b = blockIdx.x, t = threadIdx.x;
    for (int i = t; i < DWORDS; i += 1024) sm[i] = 0;
    __syncthreads();
    int f32 = *flag;
    int ebase = b * EPD2;
    for (int el = t; el < EPD2; el += 1024) {
        int e = ebase + el;
        int c = ei[N_EDGES + e];
        float w = f32 ? ((const float*)ewr)[e] : bu2f(((const unsigned short*)ewr)[e]);
        unsigned fx = (unsigned)__float2int_rn(w * DEGSCALE);
        atomicAdd(&sm[c >> 1], fx << ((c & 1) * 16));
    }
    __syncthreads();
    unsigned int* dst = (unsigned int*)(pdeg16 + (size_t)b * N_NODES);
    for (int i = t; i < DWORDS; i += 1024) dst[i] = sm[i];
}

// dis/dis2 from the 128 u16 partial slices (integer-exact sum)
__global__ void k_dis(const unsigned short* __restrict__ pdeg16,
                      float* __restrict__ dis, float* __restrict__ dis2) {
    int n = blockIdx.x * 256 + threadIdx.x;
    if (n >= N_NODES) return;
    unsigned s = 0;
#pragma unroll 8
    for (int k = 0; k < DSLC2; ++k) s += pdeg16[(size_t)k * N_NODES + n];
    float d = (float)s * (1.f / DEGSCALE);
    float di = fminf(rsqrtf(d), 1e6f);   // rsqrt(0)=inf -> 1e6, matches ref clamp
    dis[n] = di;
    dis2[n] = di * di;
}

// ---------------- CSR build: byte-packed LDS histograms, no global atomics ----------------
// 1024 threads: grid=256 is 1 block/CU (50KB LDS); 16 waves/CU vs 4 -> 4x latency hiding.

__global__ void __launch_bounds__(1024) k_hist_row(const int* __restrict__ ei,
                                                   unsigned int* __restrict__ pcnt_u32) {
    __shared__ unsigned int sm[NWORDS];
    int b = blockIdx.x, t = threadIdx.x;
    for (int i = t; i < NWORDS; i += 1024) sm[i] = 0;
    __syncthreads();
    int ebase = b * EPR;
    for (int el = t; el < EPR; el += 1024) {
        int r = ei[ebase + el];
        atomicAdd(&sm[r >> 2], 1u << ((r & 3) * 8));
    }
    __syncthreads();
    unsigned int* dst = pcnt_u32 + (size_t)b * NWORDS;
    for (int i = t; i < NWORDS; i += 1024) dst[i] = sm[i];
}

// per-node: 256-slice u8 prefix -> pref16, total -> cnt, block sums
__global__ void k_merge(const unsigned char* __restrict__ pcnt8,
                        int* __restrict__ cnt,
                        unsigned short* __restrict__ pref16, int* __restrict__ bsum) {
    __shared__ int red[256];
    int t = threadIdx.x;
    int n = blockIdx.x * 256 + t;
    int run = 0;
    if (n < N_NODES) {
#pragma unroll 8
        for (int s = 0; s < RSLC; ++s) {
            pref16[(size_t)s * N_NODES + n] = (unsigned short)run;
            run += pcnt8[(size_t)s * N_NODES + n];
        }
        cnt[n] = run;
    }
    red[t] = run;
    __syncthreads();
    for (int off = 128; off; off >>= 1) {
        if (t < off) red[t] += red[t + off];
        __syncthreads();
    }
    if (t == 0) bsum[blockIdx.x] = red[0];
}

__global__ void k_scan_top(const int* __restrict__ bsum, int* __restrict__ bpre,
                           int* __restrict__ row_ptr) {
    __shared__ int sm[256];
    int t = threadIdx.x;
    int v = (t < 196) ? bsum[t] : 0;
    sm[t] = v;
    __syncthreads();
    int val = v;
    for (int off = 1; off < 256; off <<= 1) {
        int other = (t >= off) ? sm[t - off] : 0;
        __syncthreads();
        val += other;
        sm[t] = val;
        __syncthreads();
    }
    bpre[t] = val - v;
    if (t == 0) row_ptr[N_NODES] = N_EDGES;
}

__global__ void k_scan_fin(const int* __restrict__ cnt, const int* __restrict__ bpre,
                           int* __restrict__ row_ptr) {
    __shared__ int sm[256];
    int t = threadIdx.x;
    int n = blockIdx.x * 256 + t;
    int v = (n < N_NODES) ? cnt[n] : 0;
    sm[t] = v;
    __syncthreads();
    int val = v;
    for (int off = 1; off < 256; off <<= 1) {
        int other = (t >= off) ? sm[t - off] : 0;
        __syncthreads();
        val += other;
        sm[t] = val;
        __syncthreads();
    }
    if (n < N_NODES) row_ptr[n] = bpre[blockIdx.x] + val - v;
}

// placement: per-slice u8 ordinal in LDS; writes pairs4[pos]=(c<<16|w_fp16) scattered (4 B)
// + iperm[e]=pos coalesced. ei/ew reads coalesced. 1024 threads (see k_hist_row note).
__global__ void __launch_bounds__(1024) k_placeA(const int* __restrict__ ei,
                                                 const void* __restrict__ ewr,
                                                 const int* __restrict__ flag,
                                                 const int* __restrict__ row_ptr,
                                                 const unsigned short* __restrict__ pref16,
                                                 unsigned int* __restrict__ pairs4,
                                                 int* __restrict__ iperm) {
    __shared__ unsigned int sm[NWORDS];
    int b = blockIdx.x, t = threadIdx.x;
    for (int i = t; i < NWORDS; i += 1024) sm[i] = 0;
    __syncthreads();
    int f32 = *flag;
    int ebase = b * EPR;
    const unsigned short* pr = pref16 + (size_t)b * N_NODES;
    for (int el = t; el < EPR; el += 1024) {
        int e = ebase + el;
        int r = ei[e];
        int c = ei[N_EDGES + e];
        float w = f32 ? ((const float*)ewr)[e] : bu2f(((const unsigned short*)ewr)[e]);
        int sh = (r & 3) * 8;
        unsigned old = atomicAdd(&sm[r >> 2], 1u << sh);
        int ord = (old >> sh) & 0xFF;
        int pos = row_ptr[r] + pr[r] + ord;
        pairs4[pos] = ((unsigned)c << 16) | (unsigned)f2h(w);  // scattered 4 B
        iperm[e] = pos;                                        // coalesced
    }
}

// rc rebuild: wave per node, coalesced read of pairs4 + coalesced write of rc
__global__ void __launch_bounds__(256) k_rc(const int* __restrict__ row_ptr,
                                            const unsigned int* __restrict__ pairs4,
                                            unsigned int* __restrict__ rc) {
    int lane = threadIdx.x & 63;
    int wv = __builtin_amdgcn_readfirstlane((int)(blockIdx.x * 4 + (threadIdx.x >> 6)));
    int s = __builtin_amdgcn_readfirstlane(row_ptr[wv]);
    int e = __builtin_amdgcn_readfirstlane(row_ptr[wv + 1]);
    unsigned rhi = ((unsigned)wv) << 16;
    for (int pos = s + lane; pos < e; pos += 64)
        rc[pos] = (pairs4[pos] >> 16) | rhi;
}

// ---------------- input projection: h (f32, unscaled) + hbf = bf16(dis*h) scaled state ----

__global__ void k_inproj(const void* __restrict__ xr_, const float* __restrict__ W,
                         const float* __restrict__ b, const float* __restrict__ dis,
                         float* __restrict__ h,
                         unsigned short* __restrict__ h_bf, const int* __restrict__ flag) {
    __shared__ float Wt[FIN * HD];
    __shared__ float bs[HD];
    int t = threadIdx.x;
    int f32 = *flag;
    for (int idx = t; idx < FIN * HD; idx += 256) {
        int f = idx >> 3, j = idx & 7;
        Wt[j * 64 + f] = W[idx];
    }
    if (t < 64) bs[t] = b[t];
    __syncthreads();
    int gid = blockIdx.x * 256 + t;
    if (gid < NH) {
        int i = gid >> 6, f = gid & 63;
        const float* xf = (const float*)xr_ + i * FIN;
        const unsigned short* xb = (const unsigned short*)xr_ + i * FIN;
        float acc = bs[f];
#pragma unroll
        for (int j = 0; j < FIN; ++j) {
            float xv = f32 ? xf[j] : bu2f(xb[j]);
            acc += xv * Wt[j * 64 + f];
        }
        h[gid] = acc;
        h_bf[gid] = f2bu(acc * dis[i]);   // scaled state s0 = dis .* h
    }
}

// ---------------- stats + coefficient MLP ----------------

__global__ void k_stats(const float* __restrict__ h, float* __restrict__ stats) {
    __shared__ float ssum[256], ssq[256];
    int t = threadIdx.x;
    float ls = 0.f, lq = 0.f;
    for (int idx = blockIdx.x * 256 + t; idx < NH; idx += 102400) {
        float v = h[idx];
        ls += v; lq += v * v;
    }
    ssum[t] = ls; ssq[t] = lq;
    __syncthreads();
    if (t < 64) {
        float a = ssum[t] + ssum[t + 64] + ssum[t + 128] + ssum[t + 192];
        atomicAdd(&stats[t], a);
        float q = ssq[t] + ssq[t + 64] + ssq[t + 128] + ssq[t + 192];
        for (int off = 32; off; off >>= 1) q += __shfl_down(q, off, 64);
        if (t == 0) atomicAdd(&stats[64], q);
    }
}

__global__ void k_coeffs(const float* __restrict__ stats,
                         const float* __restrict__ W1, const float* __restrict__ b1,
                         const float* __restrict__ W2, const float* __restrict__ b2,
                         int layer, float* __restrict__ coeffs) {
    __shared__ float ci[68];
    __shared__ float hid[32];
    __shared__ float lg[6];
    int t = threadIdx.x;
    float sf = stats[t];
    float tot = sf;
    for (int off = 1; off < 64; off <<= 1) tot += __shfl_xor(tot, off, 64);
    ci[t] = sf / (float)N_NODES;
    if (t == 0) {
        float sumsq = stats[64];
        float mean = tot / (float)NH;
        float var = (sumsq - (float)NH * mean * mean) / (float)(NH - 1);
        ci[64] = mean;
        ci[65] = sqrtf(fmaxf(var, 0.f));
        ci[66] = (float)N_NODES;
        ci[67] = (float)N_EDGES;
    }
    __syncthreads();
    if (t < 32) {
        float a = b1[layer * 32 + t];
        const float* wr = W1 + (layer * 32 + t) * 68;
        for (int j = 0; j < 68; ++j) a += ci[j] * wr[j];
        hid[t] = fmaxf(a, 0.f);
    }
    __syncthreads();
    if (t < 6) {
        float a = b2[layer * 6 + t];
        const float* wr = W2 + (layer * 6 + t) * 32;
        for (int g = 0; g < 32; ++g) a += hid[g] * wr[g];
        lg[t] = a;
    }
    __syncthreads();
    if (t == 0) {
        float mx = lg[0];
        for (int p = 1; p < 6; ++p) mx = fmaxf(mx, lg[p]);
        float s = 0.f, e[6];
        for (int p = 0; p < 6; ++p) { e[p] = expf(lg[p] - mx); s += e[p]; }
        for (int p = 0; p < 6; ++p) coeffs[p] = e[p] / s;
    }
}

// ---------------- SpMM hop: wave per node, scalar pair loads, 16-deep gather unroll -------
// scaled-state algebra: s_{k+1}[r] = dis2[r] * sum_e w_e * s_k[col]
// (measured-good structure; two XCD-split variants both regressed — keep this.)

__device__ __forceinline__ float acc_range(const unsigned short* __restrict__ txo,
                                           const unsigned int* __restrict__ pairs4,
                                           int j0, int j1, int lane, float acc) {
    int j = j0;
    for (; j + 15 < j1; j += 16) {
        unsigned p0 = pairs4[j],      p1 = pairs4[j + 1],  p2 = pairs4[j + 2],  p3 = pairs4[j + 3];
        unsigned p4 = pairs4[j + 4],  p5 = pairs4[j + 5],  p6 = pairs4[j + 6],  p7 = pairs4[j + 7];
        unsigned p8 = pairs4[j + 8],  p9 = pairs4[j + 9],  pa = pairs4[j + 10], pb = pairs4[j + 11];
        unsigned pc = pairs4[j + 12], pd = pairs4[j + 13], pe = pairs4[j + 14], pf = pairs4[j + 15];
        float g0 = bu2f(txo[(p0 >> 16) * 64 + lane]);
        float g1 = bu2f(txo[(p1 >> 16) * 64 + lane]);
        float g2 = bu2f(txo[(p2 >> 16) * 64 + lane]);
        float g3 = bu2f(txo[(p3 >> 16) * 64 + lane]);
        float g4 = bu2f(txo[(p4 >> 16) * 64 + lane]);
        float g5 = bu2f(txo[(p5 >> 16) * 64 + lane]);
        float g6 = bu2f(txo[(p6 >> 16) * 64 + lane]);
        float g7 = bu2f(txo[(p7 >> 16) * 64 + lane]);
        float g8 = bu2f(txo[(p8 >> 16) * 64 + lane]);
        float g9 = bu2f(txo[(p9 >> 16) * 64 + lane]);
        float ga = bu2f(txo[(pa >> 16) * 64 + lane]);
        float gb = bu2f(txo[(pb >> 16) * 64 + lane]);
        float gc = bu2f(txo[(pc >> 16) * 64 + lane]);
        float gd = bu2f(txo[(pd >> 16) * 64 + lane]);
        float ge = bu2f(txo[(pe >> 16) * 64 + lane]);
        float gf = bu2f(txo[(pf >> 16) * 64 + lane]);
        acc += h16f(p0) * g0 + h16f(p1) * g1 + h16f(p2) * g2 + h16f(p3) * g3;
        acc += h16f(p4) * g4 + h16f(p5) * g5 + h16f(p6) * g6 + h16f(p7) * g7;
        acc += h16f(p8) * g8 + h16f(p9) * g9 + h16f(pa) * ga + h16f(pb) * gb;
        acc += h16f(pc) * gc + h16f(pd) * gd + h16f(pe) * ge + h16f(pf) * gf;
    }
    for (; j + 7 < j1; j += 8) {
        unsigned p0 = pairs4[j],     p1 = pairs4[j + 1], p2 = pairs4[j + 2], p3 = pairs4[j + 3];
        unsigned p4 = pairs4[j + 4], p5 = pairs4[j + 5], p6 = pairs4[j + 6], p7 = pairs4[j + 7];
        float g0 = bu2f(txo[(p0 >> 16) * 64 + lane]);
        float g1 = bu2f(txo[(p1 >> 16) * 64 + lane]);
        float g2 = bu2f(txo[(p2 >> 16) * 64 + lane]);
        float g3 = bu2f(txo[(p3 >> 16) * 64 + lane]);
        float g4 = bu2f(txo[(p4 >> 16) * 64 + lane]);
        float g5 = bu2f(txo[(p5 >> 16) * 64 + lane]);
        float g6 = bu2f(txo[(p6 >> 16) * 64 + lane]);
        float g7 = bu2f(txo[(p7 >> 16) * 64 + lane]);
        acc += h16f(p0) * g0 + h16f(p1) * g1 + h16f(p2) * g2 + h16f(p3) * g3;
        acc += h16f(p4) * g4 + h16f(p5) * g5 + h16f(p6) * g6 + h16f(p7) * g7;
    }
    for (; j < j1; ++j) {
        unsigned p = pairs4[j];
        acc += h16f(p) * bu2f(txo[(p >> 16) * 64 + lane]);
    }
    return acc;
}

__global__ void __launch_bounds__(256) k_spmm(
    const unsigned short* __restrict__ txo, unsigned short* __restrict__ txn,
    const int* __restrict__ row_ptr, const unsigned int* __restrict__ pairs4,
    const float* __restrict__ dis2) {
    int lane = threadIdx.x & 63;
    int wv = __builtin_amdgcn_readfirstlane((int)(blockIdx.x * 4 + (threadIdx.x >> 6)));
    int s = __builtin_amdgcn_readfirstlane(row_ptr[wv]);
    int e = __builtin_amdgcn_readfirstlane(row_ptr[wv + 1]);
    float acc = acc_range(txo, pairs4, s, e, lane, 0.f);
    float d2 = dis2[wv];
    txn[wv * 64 + lane] = f2bu(acc * d2);
}

// ---------------- fused last hop + polynomial combine + layernorm ----------------
// t1..t4 hold scaled s_k; tx_k = s_k / dis[r]; hop5: tx5 = dis[r] * acc

__global__ void __launch_bounds__(256) k_spmm_ln(
    const unsigned short* __restrict__ txo,
    const int* __restrict__ row_ptr, const unsigned int* __restrict__ pairs4,
    float* __restrict__ h, unsigned short* __restrict__ h_bf,
    const unsigned short* __restrict__ t1, const unsigned short* __restrict__ t2,
    const unsigned short* __restrict__ t3, const unsigned short* __restrict__ t4,
    const float* __restrict__ coeffs, const float* __restrict__ dis,
    const float* __restrict__ sc, const float* __restrict__ bi,
    int layer, int last, void* __restrict__ outv, const int* __restrict__ flag) {
    int lane = threadIdx.x & 63;
    int wv = __builtin_amdgcn_readfirstlane((int)(blockIdx.x * 4 + (threadIdx.x >> 6)));
    int s = __builtin_amdgcn_readfirstlane(row_ptr[wv]);
    int e = __builtin_amdgcn_readfirstlane(row_ptr[wv + 1]);
    float acc = acc_range(txo, pairs4, s, e, lane, 0.f);
    int o = wv * 64 + lane;
    float ds = dis[wv];
    float invd = 1.f / ds;
    float c0 = coeffs[0], c1 = coeffs[1], c2 = coeffs[2],
          c3 = coeffs[3], c4 = coeffs[4], c5 = coeffs[5];
    float v = (1.f + c0) * h[o] +
              invd * (c1 * bu2f(t1[o]) + c2 * bu2f(t2[o]) +
                      c3 * bu2f(t3[o]) + c4 * bu2f(t4[o])) +
              c5 * ds * acc;
    float m = v;
    for (int off = 1; off < 64; off <<= 1) m += __shfl_xor(m, off, 64);
    m *= (1.f / 64.f);
    float d = v - m;
    float q = d * d;
    for (int off = 1; off < 64; off <<= 1) q += __shfl_xor(q, off, 64);
    float var = q * (1.f / 64.f);
    float y = d / sqrtf(var + 1e-5f) * sc[layer * 64 + lane] + bi[layer * 64 + lane];
    h[o] = y;
    h_bf[o] = f2bu(y * ds);   // next layer's scaled state s0
    if (last) {
        if (*flag) ((float*)outv)[N_EDGES + o] = y;
        else       ((unsigned short*)outv)[N_EDGES + o] = f2bu(y);
    }
}

// ---------------- edge predictor (fp16) ----------------

__global__ void __launch_bounds__(256) k_uv(const float* __restrict__ h,
                                            const float* __restrict__ W1,
                                            unsigned short* __restrict__ ub,
                                            unsigned short* __restrict__ vb) {
    __shared__ float Wt[128 * 65];
    __shared__ float hs[4 * 64];
    int t = threadIdx.x;
    for (int idx = t; idx < 8192; idx += 256) {
        int f = idx >> 7, j = idx & 127;
        Wt[j * 65 + f] = W1[idx];
    }
    int node0 = blockIdx.x * 4;
    hs[t] = h[node0 * 64 + t];
    __syncthreads();
    int ni = t >> 6, f = t & 63;
    const float* hr = hs + ni * 64;
    float au = 0.f, av = 0.f;
#pragma unroll 8
    for (int j = 0; j < 64; ++j) {
        float xv = hr[j];
        au += Wt[j * 65 + f] * xv;
        av += Wt[(j + 64) * 65 + f] * xv;
    }
    int i = node0 + ni;
    ub[i * 64 + f] = f2h(au);   // fp16 bits
    vb[i * 64 + f] = f2h(av);
}

// packed fp16 relu(u + v + b) via native _Float16 vectors (avoids __hmax2 overload clash)
__device__ __forceinline__ unsigned h2rel(unsigned uu, unsigned vv, half2v b) {
    half2v a = *(half2v*)&uu + *(half2v*)&vv + b;
    a[0] = a[0] > (_Float16)0 ? a[0] : (_Float16)0;
    a[1] = a[1] > (_Float16)0 ? a[1] : (_Float16)0;
    return *(unsigned*)&a;
}

union U4H8 { uint4 u; half8 h; };

// MFMA f16 edge predictor: 16 CSR-ordered edges per wave-iteration; coalesced tmp output
__global__ void __launch_bounds__(256) k_edgepred(
    const unsigned short* __restrict__ ub, const unsigned short* __restrict__ vb,
    const unsigned int* __restrict__ rc,
    const float* __restrict__ eb1, const float* __restrict__ eW2,
    const float* __restrict__ eb2, const float* __restrict__ eW3,
    const float* __restrict__ eb3, float* __restrict__ tmpP) {
    int t = threadIdx.x;
    int lane = t & 63;
    int m = lane & 15, q = lane >> 4;

    half8 B00, B01, B10, B11;
#pragma unroll
    for (int j = 0; j < 8; ++j) {
        B00[j] = (_Float16)eW2[(m) * 64      + q * 8 + j];
        B01[j] = (_Float16)eW2[(m) * 64 + 32 + q * 8 + j];
        B10[j] = (_Float16)eW2[(m + 16) * 64      + q * 8 + j];
        B11[j] = (_Float16)eW2[(m + 16) * 64 + 32 + q * 8 + j];
    }
    half2v b1p0[4], b1p1[4];
#pragma unroll
    for (int wq = 0; wq < 4; ++wq) {
        b1p0[wq][0] = (_Float16)eb1[q * 8 + 2 * wq];
        b1p0[wq][1] = (_Float16)eb1[q * 8 + 2 * wq + 1];
        b1p1[wq][0] = (_Float16)eb1[32 + q * 8 + 2 * wq];
        b1p1[wq][1] = (_Float16)eb1[32 + q * 8 + 2 * wq + 1];
    }
    float w3a = eW3[m], w3b = eW3[16 + m];
    float b2a = eb2[m], b2b = eb2[16 + m];
    float b3v = eb3[0];

    int gw = blockIdx.x * 4 + (t >> 6);
    const int NW = 1563 * 4;
    for (int tile = gw; tile < N_EDGES / 16; tile += NW) {
        int base = tile << 4;
        unsigned rcv = rc[base + m];
        int col = rcv & 0xFFFF;
        int row = rcv >> 16;
        const unsigned short* up = ub + row * 64;
        const unsigned short* vp = vb + col * 64;
        uint4 U0 = *(const uint4*)(up + q * 8);
        uint4 U1 = *(const uint4*)(up + 32 + q * 8);
        uint4 V0 = *(const uint4*)(vp + q * 8);
        uint4 V1 = *(const uint4*)(vp + 32 + q * 8);
        U4H8 a0, a1;
        a0.u.x = h2rel(U0.x, V0.x, b1p0[0]);
        a0.u.y = h2rel(U0.y, V0.y, b1p0[1]);
        a0.u.z = h2rel(U0.z, V0.z, b1p0[2]);
        a0.u.w = h2rel(U0.w, V0.w, b1p0[3]);
        a1.u.x = h2rel(U1.x, V1.x, b1p1[0]);
        a1.u.y = h2rel(U1.y, V1.y, b1p1[1]);
        a1.u.z = h2rel(U1.z, V1.z, b1p1[2]);
        a1.u.w = h2rel(U1.w, V1.w, b1p1[3]);
        f32x4 acc0 = {0.f, 0.f, 0.f, 0.f};
        f32x4 acc1 = {0.f, 0.f, 0.f, 0.f};
        acc0 = __builtin_amdgcn_mfma_f32_16x16x32_f16(a0.h, B00, acc0, 0, 0, 0);
        acc0 = __builtin_amdgcn_mfma_f32_16x16x32_f16(a1.h, B01, acc0, 0, 0, 0);
        acc1 = __builtin_amdgcn_mfma_f32_16x16x32_f16(a0.h, B10, acc1, 0, 0, 0);
        acc1 = __builtin_amdgcn_mfma_f32_16x16x32_f16(a1.h, B11, acc1, 0, 0, 0);
        float z[4];
#pragma unroll
        for (int rr = 0; rr < 4; ++rr) {
            z[rr] = w3a * fmaxf(acc0[rr] + b2a, 0.f) + w3b * fmaxf(acc1[rr] + b2b, 0.f);
            z[rr] += __shfl_xor(z[rr], 1, 64);
            z[rr] += __shfl_xor(z[rr], 2, 64);
            z[rr] += __shfl_xor(z[rr], 4, 64);
            z[rr] += __shfl_xor(z[rr], 8, 64);
        }
        if (m == 0) {
#pragma unroll
            for (int rr = 0; rr < 4; ++rr) {
                float p = 1.f / (1.f + __expf(-(z[rr] + b3v)));
                tmpP[base + (q << 2) + rr] = p;   // coalesced (16 B per lane)
            }
        }
    }
}

// final: out[e] = tmpP[iperm[e]] (coalesced read+write; tmpP gather is L2-resident)
__global__ void k_out(const int* __restrict__ iperm, const float* __restrict__ tmpP,
                      void* __restrict__ outv, const int* __restrict__ flag) {
    int e = blockIdx.x * 256 + threadIdx.x;
    if (e >= N_EDGES) return;
    float p = tmpP[iperm[e]];
    if (*flag) ((float*)outv)[e] = p;
    else       ((unsigned short*)outv)[e] = f2bu(p);
}

// ---------------- launch ----------------

extern "C" void kernel_launch(void* const* d_in, const int* in_sizes, int n_in,
                              void* d_out, int out_size, void* d_ws, size_t ws_size,
                              hipStream_t stream) {
    (void)in_sizes; (void)n_in; (void)out_size; (void)ws_size;
    const void* x_r   = d_in[0];
    const int*  ei    = (const int*)d_in[1];
    const void* ew_r  = d_in[2];

    char* w = (char*)d_ws;
    float* h            = (float*)w;          w += (size_t)NH * 4;       // 12.8 MB
    unsigned short* hbf = (unsigned short*)w; w += (size_t)NH * 2;       // 6.4
    char* txr           = w;                  w += (size_t)NH * 8;       // 25.6 (4 bufs)
    unsigned int* pairs4 = (unsigned int*)w;  w += (size_t)N_EDGES * 4;  // 6.4
    unsigned int* rc    = (unsigned int*)w;   w += (size_t)N_EDGES * 4;  // 6.4 (adjacent!)
    int* iperm          = (int*)w;            w += (size_t)N_EDGES * 4;  // 6.4
    int* row_ptr        = (int*)w;            w += 200192;
    int* cnt            = (int*)w;            w += 200192;
    float* dis          = (float*)w;          w += 200192;
    float* dis2         = (float*)w;          w += 200192;
    float* cWin = (float*)w; w += 2048;
    float* cbin = (float*)w; w += 256;
    float* ccW1 = (float*)w; w += 26112;
    float* ccb1 = (float*)w; w += 384;
    float* ccW2 = (float*)w; w += 2304;
    float* ccb2 = (float*)w; w += 128;
    float* clns = (float*)w; w += 768;
    float* clnb = (float*)w; w += 768;
    float* ceW1 = (float*)w; w += 32768;
    float* ceb1 = (float*)w; w += 256;
    float* ceW2 = (float*)w; w += 8192;
    float* ceb2 = (float*)w; w += 128;
    float* ceW3 = (float*)w; w += 128;
    float* ceb3 = (float*)w; w += 128;
    int* bsum = (int*)w; w += 1024;
    int* bpre = (int*)w; w += 1024;
    char* zero_base = w;
    float* stats = (float*)w; w += 1024;
    size_t zero_bytes = (size_t)(w - zero_base);
    float* coeffs = (float*)w; w += 128;
    int*   flag   = (int*)w;   w += 128;

    // setup-phase overlays (lifetimes disjoint with hosts):
    //  pcnt8  (12.8 MB) -> [pairs4|rc] contiguous region  [hist_row -> merge; dead before placeA writes pairs4]
    //  pref16 (25.6 MB) -> txr                             [merge -> placeA]
    //  pdeg16 (12.8 MB) -> h region                        [deg2 -> k_dis; h first written by inproj]
    //  tmpP   (6.4 MB)  -> pairs4 region                   [edgepred -> k_out; pairs4 dead]
    unsigned int* pcnt_u32 = (unsigned int*)pairs4;
    unsigned char* pcnt8   = (unsigned char*)pairs4;
    unsigned short* pref16 = (unsigned short*)txr;
    unsigned short* pdeg16 = (unsigned short*)h;
    float* tmpP            = (float*)pairs4;

    unsigned short* tx[4];
    for (int k = 0; k < 4; ++k) tx[k] = (unsigned short*)txr + (size_t)k * NH;
    unsigned short* ub = tx[0];   // k_uv runs after last spmm_ln: tx dead
    unsigned short* vb = tx[1];

    (void)hipMemsetAsync(zero_base, 0, zero_bytes, stream);

    k_detect<<<1, 64, 0, stream>>>(ew_r, flag);

    ConvArgs ca;
    const void* srcs[14] = {d_in[3], d_in[4], d_in[5], d_in[6], d_in[7], d_in[8], d_in[9],
                            d_in[10], d_in[11], d_in[12], d_in[13], d_in[14], d_in[15], d_in[16]};
    float* dsts[14] = {cWin, cbin, ccW1, ccb1, ccW2, ccb2, clns,
                       clnb, ceW1, ceb1, ceW2, ceb2, ceW3, ceb3};
    int sizes[14] = {512, 64, 6528, 96, 576, 18, 192, 192, 8192, 64, 2048, 32, 32, 1};
    int c = 0;
    for (int i = 0; i < 14; ++i) { ca.src[i] = srcs[i]; ca.dst[i] = dsts[i]; ca.cum[i] = c; c += sizes[i]; }
    ca.cum[14] = c;
    k_conv_small<<<(c + 255) / 256, 256, 0, stream>>>(ca, flag);

    k_deg2<<<DSLC2, 1024, 0, stream>>>(ei, ew_r, flag, pdeg16);
    k_hist_row<<<RSLC, 1024, 0, stream>>>(ei, pcnt_u32);
    k_merge<<<196, 256, 0, stream>>>(pcnt8, cnt, pref16, bsum);
    k_scan_top<<<1, 256, 0, stream>>>(bsum, bpre, row_ptr);
    k_scan_fin<<<196, 256, 0, stream>>>(cnt, bpre, row_ptr);
    k_placeA<<<RSLC, 1024, 0, stream>>>(ei, ew_r, flag, row_ptr, pref16, pairs4, iperm);
    k_rc<<<12500, 256, 0, stream>>>(row_ptr, pairs4, rc);
    k_dis<<<196, 256, 0, stream>>>(pdeg16, dis, dis2);
    k_inproj<<<12500, 256, 0, stream>>>(x_r, cWin, cbin, dis, h, hbf, flag);

    for (int l = 0; l < NLAYERS; ++l) {
        k_stats<<<400, 256, 0, stream>>>(h, stats + l * 80);
        k_coeffs<<<1, 64, 0, stream>>>(stats + l * 80, ccW1, ccb1, ccW2, ccb2, l,
                                       coeffs + l * 8);
        const unsigned short* src = hbf;
        for (int k = 0; k < 4; ++k) {
            k_spmm<<<12500, 256, 0, stream>>>(src, tx[k], row_ptr, pairs4, dis2);
            src = tx[k];
        }
        k_spmm_ln<<<12500, 256, 0, stream>>>(tx[3], row_ptr, pairs4, h, hbf,
                                             tx[0], tx[1], tx[2], tx[3],
                                             coeffs + l * 8, dis, clns, clnb, l,
                                             (l == NLAYERS - 1) ? 1 : 0, d_out, flag);
    }

    k_uv<<<12500, 256, 0, stream>>>(h, ceW1, ub, vb);
    k_edgepred<<<1563, 256, 0, stream>>>(ub, vb, rc, ceb1, ceW2, ceb2, ceW3, ceb3, tmpP);
    k_out<<<6250, 256, 0, stream>>>(iperm, tmpP, d_out, flag);
}

// Round 11
// 827.743 us; speedup vs baseline: 1.2567x; 1.0115x over previous
//
#include <hip/hip_runtime.h>
#include <hip/hip_bf16.h>
#include <hip/hip_fp16.h>

typedef __hip_bfloat16 bf16;
typedef __attribute__((ext_vector_type(8))) short short8;
typedef __attribute__((ext_vector_type(8))) _Float16 half8;
typedef __attribute__((ext_vector_type(2))) _Float16 half2v;
typedef __attribute__((ext_vector_type(4))) float f32x4;

#define N_NODES 50000
#define N_EDGES 1600000
#define FIN 8
#define HD 64
#define NH (N_NODES * HD)
#define NLAYERS 3

// CSR build geometry
#define RSLC 256                 // row slices, E/RSLC = 6250
#define EPR (N_EDGES / RSLC)
#define NWORDS 12500             // 50000 nodes as packed u8 in u32
// degree build: 128 slices, full-node u16 fixed-point LDS histogram (no global atomics)
// NOTE r10 lesson: blocks partition EDGES; every block must count ALL its edges' cols
// (full-node table). A half-range table drops the complementary cols entirely.
#define DSLC2 128
#define EPD2 (N_EDGES / DSLC2)   // 12500
#define DWORDS 25000             // 50000 nodes as packed u16 in u32 (100 KB LDS)
#define DEGSCALE 512.0f

__device__ __forceinline__ float b2f(bf16 v) { return __bfloat162float(v); }
__device__ __forceinline__ float bu2f(unsigned int u) { return __uint_as_float(u << 16); }
__device__ __forceinline__ unsigned short f2bu(float f) {
    unsigned int x = __float_as_uint(f);
    unsigned int r = x + 0x7FFFu + ((x >> 16) & 1u);
    return (unsigned short)(r >> 16);
}
__device__ __forceinline__ unsigned short f2h(float f) {
    _Float16 h = (_Float16)f;
    return *(unsigned short*)&h;
}
// low 16 bits as fp16 -> float (single v_cvt_f32_f16)
union H16 { unsigned short b; _Float16 h; };
__device__ __forceinline__ float h16f(unsigned u) {
    H16 x; x.b = (unsigned short)u;
    return (float)x.h;
}

// ---------------- dtype detection ----------------
__global__ void k_detect(const void* __restrict__ ew, int* __restrict__ flag) {
    int ok = 1;
    for (int i = threadIdx.x; i < 512; i += 64) {
        float v = b2f(((const bf16*)ew)[i]);
        if (!(v >= 0.f && v <= 1.f)) ok = 0;
    }
    unsigned long long m = __ballot(ok);
    if (threadIdx.x == 0) *flag = (m == 0xFFFFFFFFFFFFFFFFull) ? 0 : 1;
}

struct ConvArgs {
    const void* src[14];
    float* dst[14];
    int cum[15];
};

__global__ void k_conv_small(ConvArgs a, const int* __restrict__ flag) {
    int q = blockIdx.x * 256 + threadIdx.x;
    if (q >= a.cum[14]) return;
    int s = 0;
    while (q >= a.cum[s + 1]) ++s;
    int off = q - a.cum[s];
    if (*flag) a.dst[s][off] = ((const float*)a.src[s])[off];
    else       a.dst[s][off] = bu2f(((const unsigned short*)a.src[s])[off]);
}

// ---------------- degree: LDS u16 fixed-point histogram, NO global atomics ----------------
// 128 blocks x 12500 edges; full 50000-node LDS table (u16 fp, scale 512, 2/u32, 100KB).
// Carry between packed halves needs >=128 edges on one node in one slice: P~0.
// Partials dumped (full, no pre-zero needed); k_dis sums 128 u16 slices EXACTLY in integer.
__global__ void __launch_bounds__(1024) k_deg2(const int* __restrict__ ei,
                                               const void* __restrict__ ewr,
                                               const int* __restrict__ flag,
                                               unsigned short* __restrict__ pdeg16) {
    __shared__ unsigned int sm[DWORDS];
    int b = blockIdx.x, t = threadIdx.x;
    for (int i = t; i < DWORDS; i += 1024) sm[i] = 0;
    __syncthreads();
    int f32 = *flag;
    int ebase = b * EPD2;
    for (int el = t; el < EPD2; el += 1024) {
        int e = ebase + el;
        int c = ei[N_EDGES + e];
        float w = f32 ? ((const float*)ewr)[e] : bu2f(((const unsigned short*)ewr)[e]);
        unsigned fx = (unsigned)__float2int_rn(w * DEGSCALE);
        atomicAdd(&sm[c >> 1], fx << ((c & 1) * 16));
    }
    __syncthreads();
    unsigned int* dst = (unsigned int*)(pdeg16 + (size_t)b * N_NODES);
    for (int i = t; i < DWORDS; i += 1024) dst[i] = sm[i];
}

// dis/dis2 from the 128 u16 partial slices (integer-exact sum)
__global__ void k_dis(const unsigned short* __restrict__ pdeg16,
                      float* __restrict__ dis, float* __restrict__ dis2) {
    int n = blockIdx.x * 256 + threadIdx.x;
    if (n >= N_NODES) return;
    unsigned s = 0;
#pragma unroll 8
    for (int k = 0; k < DSLC2; ++k) s += pdeg16[(size_t)k * N_NODES + n];
    float d = (float)s * (1.f / DEGSCALE);
    float di = fminf(rsqrtf(d), 1e6f);   // rsqrt(0)=inf -> 1e6, matches ref clamp
    dis[n] = di;
    dis2[n] = di * di;
}

// ---------------- CSR build: byte-packed LDS histograms, no global atomics ----------------
// 1024 threads: grid=256 is 1 block/CU (50KB LDS); 16 waves/CU vs 4 -> 4x latency hiding.

__global__ void __launch_bounds__(1024) k_hist_row(const int* __restrict__ ei,
                                                   unsigned int* __restrict__ pcnt_u32) {
    __shared__ unsigned int sm[NWORDS];
    int b = blockIdx.x, t = threadIdx.x;
    for (int i = t; i < NWORDS; i += 1024) sm[i] = 0;
    __syncthreads();
    int ebase = b * EPR;
    for (int el = t; el < EPR; el += 1024) {
        int r = ei[ebase + el];
        atomicAdd(&sm[r >> 2], 1u << ((r & 3) * 8));
    }
    __syncthreads();
    unsigned int* dst = pcnt_u32 + (size_t)b * NWORDS;
    for (int i = t; i < NWORDS; i += 1024) dst[i] = sm[i];
}

// per-node: 256-slice u8 prefix -> pref16, total -> cnt, block sums
__global__ void k_merge(const unsigned char* __restrict__ pcnt8,
                        int* __restrict__ cnt,
                        unsigned short* __restrict__ pref16, int* __restrict__ bsum) {
    __shared__ int red[256];
    int t = threadIdx.x;
    int n = blockIdx.x * 256 + t;
    int run = 0;
    if (n < N_NODES) {
#pragma unroll 8
        for (int s = 0; s < RSLC; ++s) {
            pref16[(size_t)s * N_NODES + n] = (unsigned short)run;
            run += pcnt8[(size_t)s * N_NODES + n];
        }
        cnt[n] = run;
    }
    red[t] = run;
    __syncthreads();
    for (int off = 128; off; off >>= 1) {
        if (t < off) red[t] += red[t + off];
        __syncthreads();
    }
    if (t == 0) bsum[blockIdx.x] = red[0];
}

__global__ void k_scan_top(const int* __restrict__ bsum, int* __restrict__ bpre,
                           int* __restrict__ row_ptr) {
    __shared__ int sm[256];
    int t = threadIdx.x;
    int v = (t < 196) ? bsum[t] : 0;
    sm[t] = v;
    __syncthreads();
    int val = v;
    for (int off = 1; off < 256; off <<= 1) {
        int other = (t >= off) ? sm[t - off] : 0;
        __syncthreads();
        val += other;
        sm[t] = val;
        __syncthreads();
    }
    bpre[t] = val - v;
    if (t == 0) row_ptr[N_NODES] = N_EDGES;
}

__global__ void k_scan_fin(const int* __restrict__ cnt, const int* __restrict__ bpre,
                           int* __restrict__ row_ptr) {
    __shared__ int sm[256];
    int t = threadIdx.x;
    int n = blockIdx.x * 256 + t;
    int v = (n < N_NODES) ? cnt[n] : 0;
    sm[t] = v;
    __syncthreads();
    int val = v;
    for (int off = 1; off < 256; off <<= 1) {
        int other = (t >= off) ? sm[t - off] : 0;
        __syncthreads();
        val += other;
        sm[t] = val;
        __syncthreads();
    }
    if (n < N_NODES) row_ptr[n] = bpre[blockIdx.x] + val - v;
}

// placement: per-slice u8 ordinal in LDS; writes pairs4[pos]=(c<<16|w_fp16) scattered (4 B)
// + iperm[e]=pos coalesced. ei/ew reads coalesced. 1024 threads (16 waves/CU at 1 blk/CU).
__global__ void __launch_bounds__(1024) k_placeA(const int* __restrict__ ei,
                                                 const void* __restrict__ ewr,
                                                 const int* __restrict__ flag,
                                                 const int* __restrict__ row_ptr,
                                                 const unsigned short* __restrict__ pref16,
                                                 unsigned int* __restrict__ pairs4,
                                                 int* __restrict__ iperm) {
    __shared__ unsigned int sm[NWORDS];
    int b = blockIdx.x, t = threadIdx.x;
    for (int i = t; i < NWORDS; i += 1024) sm[i] = 0;
    __syncthreads();
    int f32 = *flag;
    int ebase = b * EPR;
    const unsigned short* pr = pref16 + (size_t)b * N_NODES;
    for (int el = t; el < EPR; el += 1024) {
        int e = ebase + el;
        int r = ei[e];
        int c = ei[N_EDGES + e];
        float w = f32 ? ((const float*)ewr)[e] : bu2f(((const unsigned short*)ewr)[e]);
        int sh = (r & 3) * 8;
        unsigned old = atomicAdd(&sm[r >> 2], 1u << sh);
        int ord = (old >> sh) & 0xFF;
        int pos = row_ptr[r] + pr[r] + ord;
        pairs4[pos] = ((unsigned)c << 16) | (unsigned)f2h(w);  // scattered 4 B
        iperm[e] = pos;                                        // coalesced
    }
}

// rc rebuild: wave per node, coalesced read of pairs4 + coalesced write of rc
__global__ void __launch_bounds__(256) k_rc(const int* __restrict__ row_ptr,
                                            const unsigned int* __restrict__ pairs4,
                                            unsigned int* __restrict__ rc) {
    int lane = threadIdx.x & 63;
    int wv = __builtin_amdgcn_readfirstlane((int)(blockIdx.x * 4 + (threadIdx.x >> 6)));
    int s = __builtin_amdgcn_readfirstlane(row_ptr[wv]);
    int e = __builtin_amdgcn_readfirstlane(row_ptr[wv + 1]);
    unsigned rhi = ((unsigned)wv) << 16;
    for (int pos = s + lane; pos < e; pos += 64)
        rc[pos] = (pairs4[pos] >> 16) | rhi;
}

// ---------------- input projection: h (f32, unscaled) + hbf = bf16(dis*h) scaled state ----

__global__ void k_inproj(const void* __restrict__ xr_, const float* __restrict__ W,
                         const float* __restrict__ b, const float* __restrict__ dis,
                         float* __restrict__ h,
                         unsigned short* __restrict__ h_bf, const int* __restrict__ flag) {
    __shared__ float Wt[FIN * HD];
    __shared__ float bs[HD];
    int t = threadIdx.x;
    int f32 = *flag;
    for (int idx = t; idx < FIN * HD; idx += 256) {
        int f = idx >> 3, j = idx & 7;
        Wt[j * 64 + f] = W[idx];
    }
    if (t < 64) bs[t] = b[t];
    __syncthreads();
    int gid = blockIdx.x * 256 + t;
    if (gid < NH) {
        int i = gid >> 6, f = gid & 63;
        const float* xf = (const float*)xr_ + i * FIN;
        const unsigned short* xb = (const unsigned short*)xr_ + i * FIN;
        float acc = bs[f];
#pragma unroll
        for (int j = 0; j < FIN; ++j) {
            float xv = f32 ? xf[j] : bu2f(xb[j]);
            acc += xv * Wt[j * 64 + f];
        }
        h[gid] = acc;
        h_bf[gid] = f2bu(acc * dis[i]);   // scaled state s0 = dis .* h
    }
}

// ---------------- stats + coefficient MLP ----------------

__global__ void k_stats(const float* __restrict__ h, float* __restrict__ stats) {
    __shared__ float ssum[256], ssq[256];
    int t = threadIdx.x;
    float ls = 0.f, lq = 0.f;
    for (int idx = blockIdx.x * 256 + t; idx < NH; idx += 102400) {
        float v = h[idx];
        ls += v; lq += v * v;
    }
    ssum[t] = ls; ssq[t] = lq;
    __syncthreads();
    if (t < 64) {
        float a = ssum[t] + ssum[t + 64] + ssum[t + 128] + ssum[t + 192];
        atomicAdd(&stats[t], a);
        float q = ssq[t] + ssq[t + 64] + ssq[t + 128] + ssq[t + 192];
        for (int off = 32; off; off >>= 1) q += __shfl_down(q, off, 64);
        if (t == 0) atomicAdd(&stats[64], q);
    }
}

__global__ void k_coeffs(const float* __restrict__ stats,
                         const float* __restrict__ W1, const float* __restrict__ b1,
                         const float* __restrict__ W2, const float* __restrict__ b2,
                         int layer, float* __restrict__ coeffs) {
    __shared__ float ci[68];
    __shared__ float hid[32];
    __shared__ float lg[6];
    int t = threadIdx.x;
    float sf = stats[t];
    float tot = sf;
    for (int off = 1; off < 64; off <<= 1) tot += __shfl_xor(tot, off, 64);
    ci[t] = sf / (float)N_NODES;
    if (t == 0) {
        float sumsq = stats[64];
        float mean = tot / (float)NH;
        float var = (sumsq - (float)NH * mean * mean) / (float)(NH - 1);
        ci[64] = mean;
        ci[65] = sqrtf(fmaxf(var, 0.f));
        ci[66] = (float)N_NODES;
        ci[67] = (float)N_EDGES;
    }
    __syncthreads();
    if (t < 32) {
        float a = b1[layer * 32 + t];
        const float* wr = W1 + (layer * 32 + t) * 68;
        for (int j = 0; j < 68; ++j) a += ci[j] * wr[j];
        hid[t] = fmaxf(a, 0.f);
    }
    __syncthreads();
    if (t < 6) {
        float a = b2[layer * 6 + t];
        const float* wr = W2 + (layer * 6 + t) * 32;
        for (int g = 0; g < 32; ++g) a += hid[g] * wr[g];
        lg[t] = a;
    }
    __syncthreads();
    if (t == 0) {
        float mx = lg[0];
        for (int p = 1; p < 6; ++p) mx = fmaxf(mx, lg[p]);
        float s = 0.f, e[6];
        for (int p = 0; p < 6; ++p) { e[p] = expf(lg[p] - mx); s += e[p]; }
        for (int p = 0; p < 6; ++p) coeffs[p] = e[p] / s;
    }
}

// ---------------- SpMM hop: wave per node, scalar pair loads, 16-deep gather unroll -------
// scaled-state algebra: s_{k+1}[r] = dis2[r] * sum_e w_e * s_k[col]
// (measured-good structure; two XCD-split variants both regressed — keep this.)

__device__ __forceinline__ float acc_range(const unsigned short* __restrict__ txo,
                                           const unsigned int* __restrict__ pairs4,
                                           int j0, int j1, int lane, float acc) {
    int j = j0;
    for (; j + 15 < j1; j += 16) {
        unsigned p0 = pairs4[j],      p1 = pairs4[j + 1],  p2 = pairs4[j + 2],  p3 = pairs4[j + 3];
        unsigned p4 = pairs4[j + 4],  p5 = pairs4[j + 5],  p6 = pairs4[j + 6],  p7 = pairs4[j + 7];
        unsigned p8 = pairs4[j + 8],  p9 = pairs4[j + 9],  pa = pairs4[j + 10], pb = pairs4[j + 11];
        unsigned pc = pairs4[j + 12], pd = pairs4[j + 13], pe = pairs4[j + 14], pf = pairs4[j + 15];
        float g0 = bu2f(txo[(p0 >> 16) * 64 + lane]);
        float g1 = bu2f(txo[(p1 >> 16) * 64 + lane]);
        float g2 = bu2f(txo[(p2 >> 16) * 64 + lane]);
        float g3 = bu2f(txo[(p3 >> 16) * 64 + lane]);
        float g4 = bu2f(txo[(p4 >> 16) * 64 + lane]);
        float g5 = bu2f(txo[(p5 >> 16) * 64 + lane]);
        float g6 = bu2f(txo[(p6 >> 16) * 64 + lane]);
        float g7 = bu2f(txo[(p7 >> 16) * 64 + lane]);
        float g8 = bu2f(txo[(p8 >> 16) * 64 + lane]);
        float g9 = bu2f(txo[(p9 >> 16) * 64 + lane]);
        float ga = bu2f(txo[(pa >> 16) * 64 + lane]);
        float gb = bu2f(txo[(pb >> 16) * 64 + lane]);
        float gc = bu2f(txo[(pc >> 16) * 64 + lane]);
        float gd = bu2f(txo[(pd >> 16) * 64 + lane]);
        float ge = bu2f(txo[(pe >> 16) * 64 + lane]);
        float gf = bu2f(txo[(pf >> 16) * 64 + lane]);
        acc += h16f(p0) * g0 + h16f(p1) * g1 + h16f(p2) * g2 + h16f(p3) * g3;
        acc += h16f(p4) * g4 + h16f(p5) * g5 + h16f(p6) * g6 + h16f(p7) * g7;
        acc += h16f(p8) * g8 + h16f(p9) * g9 + h16f(pa) * ga + h16f(pb) * gb;
        acc += h16f(pc) * gc + h16f(pd) * gd + h16f(pe) * ge + h16f(pf) * gf;
    }
    for (; j + 7 < j1; j += 8) {
        unsigned p0 = pairs4[j],     p1 = pairs4[j + 1], p2 = pairs4[j + 2], p3 = pairs4[j + 3];
        unsigned p4 = pairs4[j + 4], p5 = pairs4[j + 5], p6 = pairs4[j + 6], p7 = pairs4[j + 7];
        float g0 = bu2f(txo[(p0 >> 16) * 64 + lane]);
        float g1 = bu2f(txo[(p1 >> 16) * 64 + lane]);
        float g2 = bu2f(txo[(p2 >> 16) * 64 + lane]);
        float g3 = bu2f(txo[(p3 >> 16) * 64 + lane]);
        float g4 = bu2f(txo[(p4 >> 16) * 64 + lane]);
        float g5 = bu2f(txo[(p5 >> 16) * 64 + lane]);
        float g6 = bu2f(txo[(p6 >> 16) * 64 + lane]);
        float g7 = bu2f(txo[(p7 >> 16) * 64 + lane]);
        acc += h16f(p0) * g0 + h16f(p1) * g1 + h16f(p2) * g2 + h16f(p3) * g3;
        acc += h16f(p4) * g4 + h16f(p5) * g5 + h16f(p6) * g6 + h16f(p7) * g7;
    }
    for (; j < j1; ++j) {
        unsigned p = pairs4[j];
        acc += h16f(p) * bu2f(txo[(p >> 16) * 64 + lane]);
    }
    return acc;
}

__global__ void __launch_bounds__(256) k_spmm(
    const unsigned short* __restrict__ txo, unsigned short* __restrict__ txn,
    const int* __restrict__ row_ptr, const unsigned int* __restrict__ pairs4,
    const float* __restrict__ dis2) {
    int lane = threadIdx.x & 63;
    int wv = __builtin_amdgcn_readfirstlane((int)(blockIdx.x * 4 + (threadIdx.x >> 6)));
    int s = __builtin_amdgcn_readfirstlane(row_ptr[wv]);
    int e = __builtin_amdgcn_readfirstlane(row_ptr[wv + 1]);
    float acc = acc_range(txo, pairs4, s, e, lane, 0.f);
    float d2 = dis2[wv];
    txn[wv * 64 + lane] = f2bu(acc * d2);
}

// ---------------- fused last hop + polynomial combine + layernorm ----------------
// t1..t4 hold scaled s_k; tx_k = s_k / dis[r]; hop5: tx5 = dis[r] * acc

__global__ void __launch_bounds__(256) k_spmm_ln(
    const unsigned short* __restrict__ txo,
    const int* __restrict__ row_ptr, const unsigned int* __restrict__ pairs4,
    float* __restrict__ h, unsigned short* __restrict__ h_bf,
    const unsigned short* __restrict__ t1, const unsigned short* __restrict__ t2,
    const unsigned short* __restrict__ t3, const unsigned short* __restrict__ t4,
    const float* __restrict__ coeffs, const float* __restrict__ dis,
    const float* __restrict__ sc, const float* __restrict__ bi,
    int layer, int last, void* __restrict__ outv, const int* __restrict__ flag) {
    int lane = threadIdx.x & 63;
    int wv = __builtin_amdgcn_readfirstlane((int)(blockIdx.x * 4 + (threadIdx.x >> 6)));
    int s = __builtin_amdgcn_readfirstlane(row_ptr[wv]);
    int e = __builtin_amdgcn_readfirstlane(row_ptr[wv + 1]);
    float acc = acc_range(txo, pairs4, s, e, lane, 0.f);
    int o = wv * 64 + lane;
    float ds = dis[wv];
    float invd = 1.f / ds;
    float c0 = coeffs[0], c1 = coeffs[1], c2 = coeffs[2],
          c3 = coeffs[3], c4 = coeffs[4], c5 = coeffs[5];
    float v = (1.f + c0) * h[o] +
              invd * (c1 * bu2f(t1[o]) + c2 * bu2f(t2[o]) +
                      c3 * bu2f(t3[o]) + c4 * bu2f(t4[o])) +
              c5 * ds * acc;
    float m = v;
    for (int off = 1; off < 64; off <<= 1) m += __shfl_xor(m, off, 64);
    m *= (1.f / 64.f);
    float d = v - m;
    float q = d * d;
    for (int off = 1; off < 64; off <<= 1) q += __shfl_xor(q, off, 64);
    float var = q * (1.f / 64.f);
    float y = d / sqrtf(var + 1e-5f) * sc[layer * 64 + lane] + bi[layer * 64 + lane];
    h[o] = y;
    h_bf[o] = f2bu(y * ds);   // next layer's scaled state s0
    if (last) {
        if (*flag) ((float*)outv)[N_EDGES + o] = y;
        else       ((unsigned short*)outv)[N_EDGES + o] = f2bu(y);
    }
}

// ---------------- edge predictor (fp16) ----------------

__global__ void __launch_bounds__(256) k_uv(const float* __restrict__ h,
                                            const float* __restrict__ W1,
                                            unsigned short* __restrict__ ub,
                                            unsigned short* __restrict__ vb) {
    __shared__ float Wt[128 * 65];
    __shared__ float hs[4 * 64];
    int t = threadIdx.x;
    for (int idx = t; idx < 8192; idx += 256) {
        int f = idx >> 7, j = idx & 127;
        Wt[j * 65 + f] = W1[idx];
    }
    int node0 = blockIdx.x * 4;
    hs[t] = h[node0 * 64 + t];
    __syncthreads();
    int ni = t >> 6, f = t & 63;
    const float* hr = hs + ni * 64;
    float au = 0.f, av = 0.f;
#pragma unroll 8
    for (int j = 0; j < 64; ++j) {
        float xv = hr[j];
        au += Wt[j * 65 + f] * xv;
        av += Wt[(j + 64) * 65 + f] * xv;
    }
    int i = node0 + ni;
    ub[i * 64 + f] = f2h(au);   // fp16 bits
    vb[i * 64 + f] = f2h(av);
}

// packed fp16 relu(u + v + b) via native _Float16 vectors (avoids __hmax2 overload clash)
__device__ __forceinline__ unsigned h2rel(unsigned uu, unsigned vv, half2v b) {
    half2v a = *(half2v*)&uu + *(half2v*)&vv + b;
    a[0] = a[0] > (_Float16)0 ? a[0] : (_Float16)0;
    a[1] = a[1] > (_Float16)0 ? a[1] : (_Float16)0;
    return *(unsigned*)&a;
}

union U4H8 { uint4 u; half8 h; };

// MFMA f16 edge predictor: 16 CSR-ordered edges per wave-iteration; coalesced tmp output.
// r9: occupancy 40% at grid 1563 (6252 waves vs 8192 slots) -> grid 2500 (10000 waves).
__global__ void __launch_bounds__(256) k_edgepred(
    const unsigned short* __restrict__ ub, const unsigned short* __restrict__ vb,
    const unsigned int* __restrict__ rc,
    const float* __restrict__ eb1, const float* __restrict__ eW2,
    const float* __restrict__ eb2, const float* __restrict__ eW3,
    const float* __restrict__ eb3, float* __restrict__ tmpP) {
    int t = threadIdx.x;
    int lane = t & 63;
    int m = lane & 15, q = lane >> 4;

    half8 B00, B01, B10, B11;
#pragma unroll
    for (int j = 0; j < 8; ++j) {
        B00[j] = (_Float16)eW2[(m) * 64      + q * 8 + j];
        B01[j] = (_Float16)eW2[(m) * 64 + 32 + q * 8 + j];
        B10[j] = (_Float16)eW2[(m + 16) * 64      + q * 8 + j];
        B11[j] = (_Float16)eW2[(m + 16) * 64 + 32 + q * 8 + j];
    }
    half2v b1p0[4], b1p1[4];
#pragma unroll
    for (int wq = 0; wq < 4; ++wq) {
        b1p0[wq][0] = (_Float16)eb1[q * 8 + 2 * wq];
        b1p0[wq][1] = (_Float16)eb1[q * 8 + 2 * wq + 1];
        b1p1[wq][0] = (_Float16)eb1[32 + q * 8 + 2 * wq];
        b1p1[wq][1] = (_Float16)eb1[32 + q * 8 + 2 * wq + 1];
    }
    float w3a = eW3[m], w3b = eW3[16 + m];
    float b2a = eb2[m], b2b = eb2[16 + m];
    float b3v = eb3[0];

    int gw = blockIdx.x * 4 + (t >> 6);
    const int NW = 2500 * 4;
    for (int tile = gw; tile < N_EDGES / 16; tile += NW) {
        int base = tile << 4;
        unsigned rcv = rc[base + m];
        int col = rcv & 0xFFFF;
        int row = rcv >> 16;
        const unsigned short* up = ub + row * 64;
        const unsigned short* vp = vb + col * 64;
        uint4 U0 = *(const uint4*)(up + q * 8);
        uint4 U1 = *(const uint4*)(up + 32 + q * 8);
        uint4 V0 = *(const uint4*)(vp + q * 8);
        uint4 V1 = *(const uint4*)(vp + 32 + q * 8);
        U4H8 a0, a1;
        a0.u.x = h2rel(U0.x, V0.x, b1p0[0]);
        a0.u.y = h2rel(U0.y, V0.y, b1p0[1]);
        a0.u.z = h2rel(U0.z, V0.z, b1p0[2]);
        a0.u.w = h2rel(U0.w, V0.w, b1p0[3]);
        a1.u.x = h2rel(U1.x, V1.x, b1p1[0]);
        a1.u.y = h2rel(U1.y, V1.y, b1p1[1]);
        a1.u.z = h2rel(U1.z, V1.z, b1p1[2]);
        a1.u.w = h2rel(U1.w, V1.w, b1p1[3]);
        f32x4 acc0 = {0.f, 0.f, 0.f, 0.f};
        f32x4 acc1 = {0.f, 0.f, 0.f, 0.f};
        acc0 = __builtin_amdgcn_mfma_f32_16x16x32_f16(a0.h, B00, acc0, 0, 0, 0);
        acc0 = __builtin_amdgcn_mfma_f32_16x16x32_f16(a1.h, B01, acc0, 0, 0, 0);
        acc1 = __builtin_amdgcn_mfma_f32_16x16x32_f16(a0.h, B10, acc1, 0, 0, 0);
        acc1 = __builtin_amdgcn_mfma_f32_16x16x32_f16(a1.h, B11, acc1, 0, 0, 0);
        float z[4];
#pragma unroll
        for (int rr = 0; rr < 4; ++rr) {
            z[rr] = w3a * fmaxf(acc0[rr] + b2a, 0.f) + w3b * fmaxf(acc1[rr] + b2b, 0.f);
            z[rr] += __shfl_xor(z[rr], 1, 64);
            z[rr] += __shfl_xor(z[rr], 2, 64);
            z[rr] += __shfl_xor(z[rr], 4, 64);
            z[rr] += __shfl_xor(z[rr], 8, 64);
        }
        if (m == 0) {
#pragma unroll
            for (int rr = 0; rr < 4; ++rr) {
                float p = 1.f / (1.f + __expf(-(z[rr] + b3v)));
                tmpP[base + (q << 2) + rr] = p;   // coalesced (16 B per lane)
            }
        }
    }
}

// final: out[e] = tmpP[iperm[e]] (coalesced read+write; tmpP gather is L2-resident)
__global__ void k_out(const int* __restrict__ iperm, const float* __restrict__ tmpP,
                      void* __restrict__ outv, const int* __restrict__ flag) {
    int e = blockIdx.x * 256 + threadIdx.x;
    if (e >= N_EDGES) return;
    float p = tmpP[iperm[e]];
    if (*flag) ((float*)outv)[e] = p;
    else       ((unsigned short*)outv)[e] = f2bu(p);
}

// ---------------- launch ----------------

extern "C" void kernel_launch(void* const* d_in, const int* in_sizes, int n_in,
                              void* d_out, int out_size, void* d_ws, size_t ws_size,
                              hipStream_t stream) {
    (void)in_sizes; (void)n_in; (void)out_size; (void)ws_size;
    const void* x_r   = d_in[0];
    const int*  ei    = (const int*)d_in[1];
    const void* ew_r  = d_in[2];

    char* w = (char*)d_ws;
    float* h            = (float*)w;          w += (size_t)NH * 4;       // 12.8 MB
    unsigned short* hbf = (unsigned short*)w; w += (size_t)NH * 2;       // 6.4
    char* txr           = w;                  w += (size_t)NH * 8;       // 25.6 (4 bufs)
    unsigned int* pairs4 = (unsigned int*)w;  w += (size_t)N_EDGES * 4;  // 6.4
    unsigned int* rc    = (unsigned int*)w;   w += (size_t)N_EDGES * 4;  // 6.4 (adjacent!)
    int* iperm          = (int*)w;            w += (size_t)N_EDGES * 4;  // 6.4
    int* row_ptr        = (int*)w;            w += 200192;
    int* cnt            = (int*)w;            w += 200192;
    float* dis          = (float*)w;          w += 200192;
    float* dis2         = (float*)w;          w += 200192;
    float* cWin = (float*)w; w += 2048;
    float* cbin = (float*)w; w += 256;
    float* ccW1 = (float*)w; w += 26112;
    float* ccb1 = (float*)w; w += 384;
    float* ccW2 = (float*)w; w += 2304;
    float* ccb2 = (float*)w; w += 128;
    float* clns = (float*)w; w += 768;
    float* clnb = (float*)w; w += 768;
    float* ceW1 = (float*)w; w += 32768;
    float* ceb1 = (float*)w; w += 256;
    float* ceW2 = (float*)w; w += 8192;
    float* ceb2 = (float*)w; w += 128;
    float* ceW3 = (float*)w; w += 128;
    float* ceb3 = (float*)w; w += 128;
    int* bsum = (int*)w; w += 1024;
    int* bpre = (int*)w; w += 1024;
    char* zero_base = w;
    float* stats = (float*)w; w += 1024;
    size_t zero_bytes = (size_t)(w - zero_base);
    float* coeffs = (float*)w; w += 128;
    int*   flag   = (int*)w;   w += 128;

    // setup-phase overlays (lifetimes disjoint with hosts):
    //  pcnt8  (12.8 MB) -> [pairs4|rc] contiguous region  [hist_row -> merge; dead before placeA writes pairs4]
    //  pref16 (25.6 MB) -> txr                             [merge -> placeA]
    //  pdeg16 (12.8 MB) -> h region                        [deg2 -> k_dis; h first written by inproj]
    //  tmpP   (6.4 MB)  -> pairs4 region                   [edgepred -> k_out; pairs4 dead]
    unsigned int* pcnt_u32 = (unsigned int*)pairs4;
    unsigned char* pcnt8   = (unsigned char*)pairs4;
    unsigned short* pref16 = (unsigned short*)txr;
    unsigned short* pdeg16 = (unsigned short*)h;
    float* tmpP            = (float*)pairs4;

    unsigned short* tx[4];
    for (int k = 0; k < 4; ++k) tx[k] = (unsigned short*)txr + (size_t)k * NH;
    unsigned short* ub = tx[0];   // k_uv runs after last spmm_ln: tx dead
    unsigned short* vb = tx[1];

    (void)hipMemsetAsync(zero_base, 0, zero_bytes, stream);

    k_detect<<<1, 64, 0, stream>>>(ew_r, flag);

    ConvArgs ca;
    const void* srcs[14] = {d_in[3], d_in[4], d_in[5], d_in[6], d_in[7], d_in[8], d_in[9],
                            d_in[10], d_in[11], d_in[12], d_in[13], d_in[14], d_in[15], d_in[16]};
    float* dsts[14] = {cWin, cbin, ccW1, ccb1, ccW2, ccb2, clns,
                       clnb, ceW1, ceb1, ceW2, ceb2, ceW3, ceb3};
    int sizes[14] = {512, 64, 6528, 96, 576, 18, 192, 192, 8192, 64, 2048, 32, 32, 1};
    int c = 0;
    for (int i = 0; i < 14; ++i) { ca.src[i] = srcs[i]; ca.dst[i] = dsts[i]; ca.cum[i] = c; c += sizes[i]; }
    ca.cum[14] = c;
    k_conv_small<<<(c + 255) / 256, 256, 0, stream>>>(ca, flag);

    k_deg2<<<DSLC2, 1024, 0, stream>>>(ei, ew_r, flag, pdeg16);
    k_hist_row<<<RSLC, 1024, 0, stream>>>(ei, pcnt_u32);
    k_merge<<<196, 256, 0, stream>>>(pcnt8, cnt, pref16, bsum);
    k_scan_top<<<1, 256, 0, stream>>>(bsum, bpre, row_ptr);
    k_scan_fin<<<196, 256, 0, stream>>>(cnt, bpre, row_ptr);
    k_placeA<<<RSLC, 1024, 0, stream>>>(ei, ew_r, flag, row_ptr, pref16, pairs4, iperm);
    k_rc<<<12500, 256, 0, stream>>>(row_ptr, pairs4, rc);
    k_dis<<<196, 256, 0, stream>>>(pdeg16, dis, dis2);
    k_inproj<<<12500, 256, 0, stream>>>(x_r, cWin, cbin, dis, h, hbf, flag);

    for (int l = 0; l < NLAYERS; ++l) {
        k_stats<<<400, 256, 0, stream>>>(h, stats + l * 80);
        k_coeffs<<<1, 64, 0, stream>>>(stats + l * 80, ccW1, ccb1, ccW2, ccb2, l,
                                       coeffs + l * 8);
        const unsigned short* src = hbf;
        for (int k = 0; k < 4; ++k) {
            k_spmm<<<12500, 256, 0, stream>>>(src, tx[k], row_ptr, pairs4, dis2);
            src = tx[k];
        }
        k_spmm_ln<<<12500, 256, 0, stream>>>(tx[3], row_ptr, pairs4, h, hbf,
                                             tx[0], tx[1], tx[2], tx[3],
                                             coeffs + l * 8, dis, clns, clnb, l,
                                             (l == NLAYERS - 1) ? 1 : 0, d_out, flag);
    }

    k_uv<<<12500, 256, 0, stream>>>(h, ceW1, ub, vb);
    k_edgepred<<<2500, 256, 0, stream>>>(ub, vb, rc, ceb1, ceW2, ceb2, ceW3, ceb3, tmpP);
    k_out<<<6250, 256, 0, stream>>>(iperm, tmpP, d_out, flag);
}

// Round 12
// 796.685 us; speedup vs baseline: 1.3057x; 1.0390x over previous
//
#include <hip/hip_runtime.h>
#include <hip/hip_bf16.h>
#include <hip/hip_fp16.h>

typedef __hip_bfloat16 bf16;
typedef __attribute__((ext_vector_type(8))) short short8;
typedef __attribute__((ext_vector_type(8))) _Float16 half8;
typedef __attribute__((ext_vector_type(2))) _Float16 half2v;
typedef __attribute__((ext_vector_type(4))) float f32x4;

#define N_NODES 50000
#define N_EDGES 1600000
#define FIN 8
#define HD 64
#define NH (N_NODES * HD)
#define NLAYERS 3

// CSR build geometry
#define RSLC 256                 // row slices, E/RSLC = 6250
#define EPR (N_EDGES / RSLC)
#define NWORDS 12500             // 50000 nodes as packed u8 in u32
// degree build: 128 slices, full-node u16 fixed-point LDS histogram (no global atomics)
// NOTE r10 lesson: blocks partition EDGES; every block must count ALL its edges' cols
// (full-node table). A half-range table drops the complementary cols entirely.
#define DSLC2 128
#define EPD2 (N_EDGES / DSLC2)   // 12500
#define DWORDS 25000             // 50000 nodes as packed u16 in u32 (100 KB LDS)
#define DEGSCALE 512.0f

__device__ __forceinline__ float b2f(bf16 v) { return __bfloat162float(v); }
__device__ __forceinline__ float bu2f(unsigned int u) { return __uint_as_float(u << 16); }
__device__ __forceinline__ unsigned short f2bu(float f) {
    unsigned int x = __float_as_uint(f);
    unsigned int r = x + 0x7FFFu + ((x >> 16) & 1u);
    return (unsigned short)(r >> 16);
}
__device__ __forceinline__ unsigned short f2h(float f) {
    _Float16 h = (_Float16)f;
    return *(unsigned short*)&h;
}
// low 16 bits as fp16 -> float (single v_cvt_f32_f16)
union H16 { unsigned short b; _Float16 h; };
__device__ __forceinline__ float h16f(unsigned u) {
    H16 x; x.b = (unsigned short)u;
    return (float)x.h;
}

// ---------------- dtype detection ----------------
__global__ void k_detect(const void* __restrict__ ew, int* __restrict__ flag) {
    int ok = 1;
    for (int i = threadIdx.x; i < 512; i += 64) {
        float v = b2f(((const bf16*)ew)[i]);
        if (!(v >= 0.f && v <= 1.f)) ok = 0;
    }
    unsigned long long m = __ballot(ok);
    if (threadIdx.x == 0) *flag = (m == 0xFFFFFFFFFFFFFFFFull) ? 0 : 1;
}

struct ConvArgs {
    const void* src[14];
    float* dst[14];
    int cum[15];
};

__global__ void k_conv_small(ConvArgs a, const int* __restrict__ flag) {
    int q = blockIdx.x * 256 + threadIdx.x;
    if (q >= a.cum[14]) return;
    int s = 0;
    while (q >= a.cum[s + 1]) ++s;
    int off = q - a.cum[s];
    if (*flag) a.dst[s][off] = ((const float*)a.src[s])[off];
    else       a.dst[s][off] = bu2f(((const unsigned short*)a.src[s])[off]);
}

// pack ep_W1 (f32 [64][128]) into f16 [128][64]: rows 0-63 = au weights (W1[f][0:64]),
// rows 64-127 = av weights (W1[f][64:128]) — B-operand layout for MFMA k_uv.
__global__ void k_w1h(const float* __restrict__ W1, unsigned short* __restrict__ w1h) {
    int i = blockIdx.x * 256 + threadIdx.x;
    if (i >= 8192) return;
    int r = i >> 6, k = i & 63;
    float v = (r < 64) ? W1[r * 128 + k] : W1[(r - 64) * 128 + 64 + k];
    w1h[i] = f2h(v);
}

// ---------------- degree: LDS u16 fixed-point histogram, NO global atomics ----------------
// 128 blocks x 12500 edges; full 50000-node LDS table (u16 fp, scale 512, 2/u32, 100KB).
// Carry between packed halves needs >=128 edges on one node in one slice: P~0.
// Partials dumped (full, no pre-zero needed); k_dis sums 128 u16 slices EXACTLY in integer.
__global__ void __launch_bounds__(1024) k_deg2(const int* __restrict__ ei,
                                               const void* __restrict__ ewr,
                                               const int* __restrict__ flag,
                                               unsigned short* __restrict__ pdeg16) {
    __shared__ unsigned int sm[DWORDS];
    int b = blockIdx.x, t = threadIdx.x;
    for (int i = t; i < DWORDS; i += 1024) sm[i] = 0;
    __syncthreads();
    int f32 = *flag;
    int ebase = b * EPD2;
    for (int el = t; el < EPD2; el += 1024) {
        int e = ebase + el;
        int c = ei[N_EDGES + e];
        float w = f32 ? ((const float*)ewr)[e] : bu2f(((const unsigned short*)ewr)[e]);
        unsigned fx = (unsigned)__float2int_rn(w * DEGSCALE);
        atomicAdd(&sm[c >> 1], fx << ((c & 1) * 16));
    }
    __syncthreads();
    unsigned int* dst = (unsigned int*)(pdeg16 + (size_t)b * N_NODES);
    for (int i = t; i < DWORDS; i += 1024) dst[i] = sm[i];
}

// dis/dis2 from the 128 u16 partial slices (integer-exact sum)
__global__ void k_dis(const unsigned short* __restrict__ pdeg16,
                      float* __restrict__ dis, float* __restrict__ dis2) {
    int n = blockIdx.x * 256 + threadIdx.x;
    if (n >= N_NODES) return;
    unsigned s = 0;
#pragma unroll 8
    for (int k = 0; k < DSLC2; ++k) s += pdeg16[(size_t)k * N_NODES + n];
    float d = (float)s * (1.f / DEGSCALE);
    float di = fminf(rsqrtf(d), 1e6f);   // rsqrt(0)=inf -> 1e6, matches ref clamp
    dis[n] = di;
    dis2[n] = di * di;
}

// ---------------- CSR build: byte-packed LDS histograms, no global atomics ----------------
// 1024 threads: grid=256 is 1 block/CU (50KB LDS); 16 waves/CU vs 4 -> 4x latency hiding.

__global__ void __launch_bounds__(1024) k_hist_row(const int* __restrict__ ei,
                                                   unsigned int* __restrict__ pcnt_u32) {
    __shared__ unsigned int sm[NWORDS];
    int b = blockIdx.x, t = threadIdx.x;
    for (int i = t; i < NWORDS; i += 1024) sm[i] = 0;
    __syncthreads();
    int ebase = b * EPR;
    for (int el = t; el < EPR; el += 1024) {
        int r = ei[ebase + el];
        atomicAdd(&sm[r >> 2], 1u << ((r & 3) * 8));
    }
    __syncthreads();
    unsigned int* dst = pcnt_u32 + (size_t)b * NWORDS;
    for (int i = t; i < NWORDS; i += 1024) dst[i] = sm[i];
}

// per-node: 256-slice u8 prefix -> pref16, total -> cnt, block sums
__global__ void k_merge(const unsigned char* __restrict__ pcnt8,
                        int* __restrict__ cnt,
                        unsigned short* __restrict__ pref16, int* __restrict__ bsum) {
    __shared__ int red[256];
    int t = threadIdx.x;
    int n = blockIdx.x * 256 + t;
    int run = 0;
    if (n < N_NODES) {
#pragma unroll 8
        for (int s = 0; s < RSLC; ++s) {
            pref16[(size_t)s * N_NODES + n] = (unsigned short)run;
            run += pcnt8[(size_t)s * N_NODES + n];
        }
        cnt[n] = run;
    }
    red[t] = run;
    __syncthreads();
    for (int off = 128; off; off >>= 1) {
        if (t < off) red[t] += red[t + off];
        __syncthreads();
    }
    if (t == 0) bsum[blockIdx.x] = red[0];
}

__global__ void k_scan_top(const int* __restrict__ bsum, int* __restrict__ bpre,
                           int* __restrict__ row_ptr) {
    __shared__ int sm[256];
    int t = threadIdx.x;
    int v = (t < 196) ? bsum[t] : 0;
    sm[t] = v;
    __syncthreads();
    int val = v;
    for (int off = 1; off < 256; off <<= 1) {
        int other = (t >= off) ? sm[t - off] : 0;
        __syncthreads();
        val += other;
        sm[t] = val;
        __syncthreads();
    }
    bpre[t] = val - v;
    if (t == 0) row_ptr[N_NODES] = N_EDGES;
}

__global__ void k_scan_fin(const int* __restrict__ cnt, const int* __restrict__ bpre,
                           int* __restrict__ row_ptr) {
    __shared__ int sm[256];
    int t = threadIdx.x;
    int n = blockIdx.x * 256 + t;
    int v = (n < N_NODES) ? cnt[n] : 0;
    sm[t] = v;
    __syncthreads();
    int val = v;
    for (int off = 1; off < 256; off <<= 1) {
        int other = (t >= off) ? sm[t - off] : 0;
        __syncthreads();
        val += other;
        sm[t] = val;
        __syncthreads();
    }
    if (n < N_NODES) row_ptr[n] = bpre[blockIdx.x] + val - v;
}

// placement: per-slice u8 ordinal in LDS; writes pairs4[pos]=(c<<16|w_fp16) scattered (4 B)
// + iperm[e]=pos coalesced. ei/ew reads coalesced. 1024 threads (16 waves/CU at 1 blk/CU).
__global__ void __launch_bounds__(1024) k_placeA(const int* __restrict__ ei,
                                                 const void* __restrict__ ewr,
                                                 const int* __restrict__ flag,
                                                 const int* __restrict__ row_ptr,
                                                 const unsigned short* __restrict__ pref16,
                                                 unsigned int* __restrict__ pairs4,
                                                 int* __restrict__ iperm) {
    __shared__ unsigned int sm[NWORDS];
    int b = blockIdx.x, t = threadIdx.x;
    for (int i = t; i < NWORDS; i += 1024) sm[i] = 0;
    __syncthreads();
    int f32 = *flag;
    int ebase = b * EPR;
    const unsigned short* pr = pref16 + (size_t)b * N_NODES;
    for (int el = t; el < EPR; el += 1024) {
        int e = ebase + el;
        int r = ei[e];
        int c = ei[N_EDGES + e];
        float w = f32 ? ((const float*)ewr)[e] : bu2f(((const unsigned short*)ewr)[e]);
        int sh = (r & 3) * 8;
        unsigned old = atomicAdd(&sm[r >> 2], 1u << sh);
        int ord = (old >> sh) & 0xFF;
        int pos = row_ptr[r] + pr[r] + ord;
        pairs4[pos] = ((unsigned)c << 16) | (unsigned)f2h(w);  // scattered 4 B
        iperm[e] = pos;                                        // coalesced
    }
}

// rc rebuild: wave per node, coalesced read of pairs4 + coalesced write of rc
__global__ void __launch_bounds__(256) k_rc(const int* __restrict__ row_ptr,
                                            const unsigned int* __restrict__ pairs4,
                                            unsigned int* __restrict__ rc) {
    int lane = threadIdx.x & 63;
    int wv = __builtin_amdgcn_readfirstlane((int)(blockIdx.x * 4 + (threadIdx.x >> 6)));
    int s = __builtin_amdgcn_readfirstlane(row_ptr[wv]);
    int e = __builtin_amdgcn_readfirstlane(row_ptr[wv + 1]);
    unsigned rhi = ((unsigned)wv) << 16;
    for (int pos = s + lane; pos < e; pos += 64)
        rc[pos] = (pairs4[pos] >> 16) | rhi;
}

// ---------------- input projection: h (f32, unscaled) + hbf = bf16(dis*h) scaled state ----

__global__ void k_inproj(const void* __restrict__ xr_, const float* __restrict__ W,
                         const float* __restrict__ b, const float* __restrict__ dis,
                         float* __restrict__ h,
                         unsigned short* __restrict__ h_bf, const int* __restrict__ flag) {
    __shared__ float Wt[FIN * HD];
    __shared__ float bs[HD];
    int t = threadIdx.x;
    int f32 = *flag;
    for (int idx = t; idx < FIN * HD; idx += 256) {
        int f = idx >> 3, j = idx & 7;
        Wt[j * 64 + f] = W[idx];
    }
    if (t < 64) bs[t] = b[t];
    __syncthreads();
    int gid = blockIdx.x * 256 + t;
    if (gid < NH) {
        int i = gid >> 6, f = gid & 63;
        const float* xf = (const float*)xr_ + i * FIN;
        const unsigned short* xb = (const unsigned short*)xr_ + i * FIN;
        float acc = bs[f];
#pragma unroll
        for (int j = 0; j < FIN; ++j) {
            float xv = f32 ? xf[j] : bu2f(xb[j]);
            acc += xv * Wt[j * 64 + f];
        }
        h[gid] = acc;
        h_bf[gid] = f2bu(acc * dis[i]);   // scaled state s0 = dis .* h
    }
}

// ---------------- stats + coefficient MLP ----------------

__global__ void k_stats(const float* __restrict__ h, float* __restrict__ stats) {
    __shared__ float ssum[256], ssq[256];
    int t = threadIdx.x;
    float ls = 0.f, lq = 0.f;
    for (int idx = blockIdx.x * 256 + t; idx < NH; idx += 102400) {
        float v = h[idx];
        ls += v; lq += v * v;
    }
    ssum[t] = ls; ssq[t] = lq;
    __syncthreads();
    if (t < 64) {
        float a = ssum[t] + ssum[t + 64] + ssum[t + 128] + ssum[t + 192];
        atomicAdd(&stats[t], a);
        float q = ssq[t] + ssq[t + 64] + ssq[t + 128] + ssq[t + 192];
        for (int off = 32; off; off >>= 1) q += __shfl_down(q, off, 64);
        if (t == 0) atomicAdd(&stats[64], q);
    }
}

__global__ void k_coeffs(const float* __restrict__ stats,
                         const float* __restrict__ W1, const float* __restrict__ b1,
                         const float* __restrict__ W2, const float* __restrict__ b2,
                         int layer, float* __restrict__ coeffs) {
    __shared__ float ci[68];
    __shared__ float hid[32];
    __shared__ float lg[6];
    int t = threadIdx.x;
    float sf = stats[t];
    float tot = sf;
    for (int off = 1; off < 64; off <<= 1) tot += __shfl_xor(tot, off, 64);
    ci[t] = sf / (float)N_NODES;
    if (t == 0) {
        float sumsq = stats[64];
        float mean = tot / (float)NH;
        float var = (sumsq - (float)NH * mean * mean) / (float)(NH - 1);
        ci[64] = mean;
        ci[65] = sqrtf(fmaxf(var, 0.f));
        ci[66] = (float)N_NODES;
        ci[67] = (float)N_EDGES;
    }
    __syncthreads();
    if (t < 32) {
        float a = b1[layer * 32 + t];
        const float* wr = W1 + (layer * 32 + t) * 68;
        for (int j = 0; j < 68; ++j) a += ci[j] * wr[j];
        hid[t] = fmaxf(a, 0.f);
    }
    __syncthreads();
    if (t < 6) {
        float a = b2[layer * 6 + t];
        const float* wr = W2 + (layer * 6 + t) * 32;
        for (int g = 0; g < 32; ++g) a += hid[g] * wr[g];
        lg[t] = a;
    }
    __syncthreads();
    if (t == 0) {
        float mx = lg[0];
        for (int p = 1; p < 6; ++p) mx = fmaxf(mx, lg[p]);
        float s = 0.f, e[6];
        for (int p = 0; p < 6; ++p) { e[p] = expf(lg[p] - mx); s += e[p]; }
        for (int p = 0; p < 6; ++p) coeffs[p] = e[p] / s;
    }
}

// ---------------- SpMM hop: wave per node, scalar pair loads, 16-deep gather unroll -------
// scaled-state algebra: s_{k+1}[r] = dis2[r] * sum_e w_e * s_k[col]
// (measured-good structure; two XCD-split variants both regressed — keep this.)

__device__ __forceinline__ float acc_range(const unsigned short* __restrict__ txo,
                                           const unsigned int* __restrict__ pairs4,
                                           int j0, int j1, int lane, float acc) {
    int j = j0;
    for (; j + 15 < j1; j += 16) {
        unsigned p0 = pairs4[j],      p1 = pairs4[j + 1],  p2 = pairs4[j + 2],  p3 = pairs4[j + 3];
        unsigned p4 = pairs4[j + 4],  p5 = pairs4[j + 5],  p6 = pairs4[j + 6],  p7 = pairs4[j + 7];
        unsigned p8 = pairs4[j + 8],  p9 = pairs4[j + 9],  pa = pairs4[j + 10], pb = pairs4[j + 11];
        unsigned pc = pairs4[j + 12], pd = pairs4[j + 13], pe = pairs4[j + 14], pf = pairs4[j + 15];
        float g0 = bu2f(txo[(p0 >> 16) * 64 + lane]);
        float g1 = bu2f(txo[(p1 >> 16) * 64 + lane]);
        float g2 = bu2f(txo[(p2 >> 16) * 64 + lane]);
        float g3 = bu2f(txo[(p3 >> 16) * 64 + lane]);
        float g4 = bu2f(txo[(p4 >> 16) * 64 + lane]);
        float g5 = bu2f(txo[(p5 >> 16) * 64 + lane]);
        float g6 = bu2f(txo[(p6 >> 16) * 64 + lane]);
        float g7 = bu2f(txo[(p7 >> 16) * 64 + lane]);
        float g8 = bu2f(txo[(p8 >> 16) * 64 + lane]);
        float g9 = bu2f(txo[(p9 >> 16) * 64 + lane]);
        float ga = bu2f(txo[(pa >> 16) * 64 + lane]);
        float gb = bu2f(txo[(pb >> 16) * 64 + lane]);
        float gc = bu2f(txo[(pc >> 16) * 64 + lane]);
        float gd = bu2f(txo[(pd >> 16) * 64 + lane]);
        float ge = bu2f(txo[(pe >> 16) * 64 + lane]);
        float gf = bu2f(txo[(pf >> 16) * 64 + lane]);
        acc += h16f(p0) * g0 + h16f(p1) * g1 + h16f(p2) * g2 + h16f(p3) * g3;
        acc += h16f(p4) * g4 + h16f(p5) * g5 + h16f(p6) * g6 + h16f(p7) * g7;
        acc += h16f(p8) * g8 + h16f(p9) * g9 + h16f(pa) * ga + h16f(pb) * gb;
        acc += h16f(pc) * gc + h16f(pd) * gd + h16f(pe) * ge + h16f(pf) * gf;
    }
    for (; j + 7 < j1; j += 8) {
        unsigned p0 = pairs4[j],     p1 = pairs4[j + 1], p2 = pairs4[j + 2], p3 = pairs4[j + 3];
        unsigned p4 = pairs4[j + 4], p5 = pairs4[j + 5], p6 = pairs4[j + 6], p7 = pairs4[j + 7];
        float g0 = bu2f(txo[(p0 >> 16) * 64 + lane]);
        float g1 = bu2f(txo[(p1 >> 16) * 64 + lane]);
        float g2 = bu2f(txo[(p2 >> 16) * 64 + lane]);
        float g3 = bu2f(txo[(p3 >> 16) * 64 + lane]);
        float g4 = bu2f(txo[(p4 >> 16) * 64 + lane]);
        float g5 = bu2f(txo[(p5 >> 16) * 64 + lane]);
        float g6 = bu2f(txo[(p6 >> 16) * 64 + lane]);
        float g7 = bu2f(txo[(p7 >> 16) * 64 + lane]);
        acc += h16f(p0) * g0 + h16f(p1) * g1 + h16f(p2) * g2 + h16f(p3) * g3;
        acc += h16f(p4) * g4 + h16f(p5) * g5 + h16f(p6) * g6 + h16f(p7) * g7;
    }
    for (; j < j1; ++j) {
        unsigned p = pairs4[j];
        acc += h16f(p) * bu2f(txo[(p >> 16) * 64 + lane]);
    }
    return acc;
}

__global__ void __launch_bounds__(256) k_spmm(
    const unsigned short* __restrict__ txo, unsigned short* __restrict__ txn,
    const int* __restrict__ row_ptr, const unsigned int* __restrict__ pairs4,
    const float* __restrict__ dis2) {
    int lane = threadIdx.x & 63;
    int wv = __builtin_amdgcn_readfirstlane((int)(blockIdx.x * 4 + (threadIdx.x >> 6)));
    int s = __builtin_amdgcn_readfirstlane(row_ptr[wv]);
    int e = __builtin_amdgcn_readfirstlane(row_ptr[wv + 1]);
    float acc = acc_range(txo, pairs4, s, e, lane, 0.f);
    float d2 = dis2[wv];
    txn[wv * 64 + lane] = f2bu(acc * d2);
}

// ---------------- fused last hop + polynomial combine + layernorm ----------------
// t1..t4 hold scaled s_k; tx_k = s_k / dis[r]; hop5: tx5 = dis[r] * acc

__global__ void __launch_bounds__(256) k_spmm_ln(
    const unsigned short* __restrict__ txo,
    const int* __restrict__ row_ptr, const unsigned int* __restrict__ pairs4,
    float* __restrict__ h, unsigned short* __restrict__ h_bf,
    const unsigned short* __restrict__ t1, const unsigned short* __restrict__ t2,
    const unsigned short* __restrict__ t3, const unsigned short* __restrict__ t4,
    const float* __restrict__ coeffs, const float* __restrict__ dis,
    const float* __restrict__ sc, const float* __restrict__ bi,
    int layer, int last, void* __restrict__ outv, const int* __restrict__ flag) {
    int lane = threadIdx.x & 63;
    int wv = __builtin_amdgcn_readfirstlane((int)(blockIdx.x * 4 + (threadIdx.x >> 6)));
    int s = __builtin_amdgcn_readfirstlane(row_ptr[wv]);
    int e = __builtin_amdgcn_readfirstlane(row_ptr[wv + 1]);
    float acc = acc_range(txo, pairs4, s, e, lane, 0.f);
    int o = wv * 64 + lane;
    float ds = dis[wv];
    float invd = 1.f / ds;
    float c0 = coeffs[0], c1 = coeffs[1], c2 = coeffs[2],
          c3 = coeffs[3], c4 = coeffs[4], c5 = coeffs[5];
    float v = (1.f + c0) * h[o] +
              invd * (c1 * bu2f(t1[o]) + c2 * bu2f(t2[o]) +
                      c3 * bu2f(t3[o]) + c4 * bu2f(t4[o])) +
              c5 * ds * acc;
    float m = v;
    for (int off = 1; off < 64; off <<= 1) m += __shfl_xor(m, off, 64);
    m *= (1.f / 64.f);
    float d = v - m;
    float q = d * d;
    for (int off = 1; off < 64; off <<= 1) q += __shfl_xor(q, off, 64);
    float var = q * (1.f / 64.f);
    float y = d / sqrtf(var + 1e-5f) * sc[layer * 64 + lane] + bi[layer * 64 + lane];
    h[o] = y;
    h_bf[o] = f2bu(y * ds);   // next layer's scaled state s0
    if (last) {
        if (*flag) ((float*)outv)[N_EDGES + o] = y;
        else       ((unsigned short*)outv)[N_EDGES + o] = f2bu(y);
    }
}

union U4H8 { uint4 u; half8 h; };

// ---------------- edge predictor projection: MFMA GEMM h[50000x64] @ w1h^T -> ub|vb ------
// r11 counters: scalar k_uv was LDS-read-issue-bound (192 ds_read/thread, 52 us, 68% VALU).
// One wave per 16-node tile (3125 exact), 8 col-tiles x 2 MFMA (K=64); fragment mapping
// identical to the verified k_edgepred pattern. ~4 us memory floor.
__global__ void __launch_bounds__(256) k_uv(const float* __restrict__ h,
                                            const unsigned short* __restrict__ w1h,
                                            unsigned short* __restrict__ ub,
                                            unsigned short* __restrict__ vb) {
    int t = threadIdx.x;
    int lane = t & 63;
    int m = lane & 15, q = lane >> 4;
    int wv = blockIdx.x * 4 + (t >> 6);
    if (wv >= N_NODES / 16) return;
    int node0 = wv * 16;
    const float* hrow = h + (size_t)(node0 + m) * 64 + q * 8;
    U4H8 a0, a1;
#pragma unroll
    for (int j = 0; j < 8; ++j) a0.h[j] = (_Float16)hrow[j];
#pragma unroll
    for (int j = 0; j < 8; ++j) a1.h[j] = (_Float16)hrow[32 + j];
#pragma unroll
    for (int ct = 0; ct < 8; ++ct) {
        const unsigned short* wrow = w1h + (size_t)(ct * 16 + m) * 64 + q * 8;
        U4H8 b0, b1;
        b0.u = *(const uint4*)wrow;
        b1.u = *(const uint4*)(wrow + 32);
        f32x4 acc = {0.f, 0.f, 0.f, 0.f};
        acc = __builtin_amdgcn_mfma_f32_16x16x32_f16(a0.h, b0.h, acc, 0, 0, 0);
        acc = __builtin_amdgcn_mfma_f32_16x16x32_f16(a1.h, b1.h, acc, 0, 0, 0);
        int feat = ct * 16 + m;
        unsigned short* dst = (feat < 64) ? (ub + feat) : (vb + (feat - 64));
#pragma unroll
        for (int r = 0; r < 4; ++r) {
            int node = node0 + q * 4 + r;
            dst[(size_t)node * 64] = f2h(acc[r]);
        }
    }
}

// packed fp16 relu(u + v + b) via native _Float16 vectors (avoids __hmax2 overload clash)
__device__ __forceinline__ unsigned h2rel(unsigned uu, unsigned vv, half2v b) {
    half2v a = *(half2v*)&uu + *(half2v*)&vv + b;
    a[0] = a[0] > (_Float16)0 ? a[0] : (_Float16)0;
    a[1] = a[1] > (_Float16)0 ? a[1] : (_Float16)0;
    return *(unsigned*)&a;
}

// MFMA f16 edge predictor: 16 CSR-ordered edges per wave-iteration; coalesced tmp output.
// r9: occupancy 40% at grid 1563 (6252 waves vs 8192 slots) -> grid 2500 (10000 waves).
__global__ void __launch_bounds__(256) k_edgepred(
    const unsigned short* __restrict__ ub, const unsigned short* __restrict__ vb,
    const unsigned int* __restrict__ rc,
    const float* __restrict__ eb1, const float* __restrict__ eW2,
    const float* __restrict__ eb2, const float* __restrict__ eW3,
    const float* __restrict__ eb3, float* __restrict__ tmpP) {
    int t = threadIdx.x;
    int lane = t & 63;
    int m = lane & 15, q = lane >> 4;

    half8 B00, B01, B10, B11;
#pragma unroll
    for (int j = 0; j < 8; ++j) {
        B00[j] = (_Float16)eW2[(m) * 64      + q * 8 + j];
        B01[j] = (_Float16)eW2[(m) * 64 + 32 + q * 8 + j];
        B10[j] = (_Float16)eW2[(m + 16) * 64      + q * 8 + j];
        B11[j] = (_Float16)eW2[(m + 16) * 64 + 32 + q * 8 + j];
    }
    half2v b1p0[4], b1p1[4];
#pragma unroll
    for (int wq = 0; wq < 4; ++wq) {
        b1p0[wq][0] = (_Float16)eb1[q * 8 + 2 * wq];
        b1p0[wq][1] = (_Float16)eb1[q * 8 + 2 * wq + 1];
        b1p1[wq][0] = (_Float16)eb1[32 + q * 8 + 2 * wq];
        b1p1[wq][1] = (_Float16)eb1[32 + q * 8 + 2 * wq + 1];
    }
    float w3a = eW3[m], w3b = eW3[16 + m];
    float b2a = eb2[m], b2b = eb2[16 + m];
    float b3v = eb3[0];

    int gw = blockIdx.x * 4 + (t >> 6);
    const int NW = 2500 * 4;
    for (int tile = gw; tile < N_EDGES / 16; tile += NW) {
        int base = tile << 4;
        unsigned rcv = rc[base + m];
        int col = rcv & 0xFFFF;
        int row = rcv >> 16;
        const unsigned short* up = ub + row * 64;
        const unsigned short* vp = vb + col * 64;
        uint4 U0 = *(const uint4*)(up + q * 8);
        uint4 U1 = *(const uint4*)(up + 32 + q * 8);
        uint4 V0 = *(const uint4*)(vp + q * 8);
        uint4 V1 = *(const uint4*)(vp + 32 + q * 8);
        U4H8 a0, a1;
        a0.u.x = h2rel(U0.x, V0.x, b1p0[0]);
        a0.u.y = h2rel(U0.y, V0.y, b1p0[1]);
        a0.u.z = h2rel(U0.z, V0.z, b1p0[2]);
        a0.u.w = h2rel(U0.w, V0.w, b1p0[3]);
        a1.u.x = h2rel(U1.x, V1.x, b1p1[0]);
        a1.u.y = h2rel(U1.y, V1.y, b1p1[1]);
        a1.u.z = h2rel(U1.z, V1.z, b1p1[2]);
        a1.u.w = h2rel(U1.w, V1.w, b1p1[3]);
        f32x4 acc0 = {0.f, 0.f, 0.f, 0.f};
        f32x4 acc1 = {0.f, 0.f, 0.f, 0.f};
        acc0 = __builtin_amdgcn_mfma_f32_16x16x32_f16(a0.h, B00, acc0, 0, 0, 0);
        acc0 = __builtin_amdgcn_mfma_f32_16x16x32_f16(a1.h, B01, acc0, 0, 0, 0);
        acc1 = __builtin_amdgcn_mfma_f32_16x16x32_f16(a0.h, B10, acc1, 0, 0, 0);
        acc1 = __builtin_amdgcn_mfma_f32_16x16x32_f16(a1.h, B11, acc1, 0, 0, 0);
        float z[4];
#pragma unroll
        for (int rr = 0; rr < 4; ++rr) {
            z[rr] = w3a * fmaxf(acc0[rr] + b2a, 0.f) + w3b * fmaxf(acc1[rr] + b2b, 0.f);
            z[rr] += __shfl_xor(z[rr], 1, 64);
            z[rr] += __shfl_xor(z[rr], 2, 64);
            z[rr] += __shfl_xor(z[rr], 4, 64);
            z[rr] += __shfl_xor(z[rr], 8, 64);
        }
        if (m == 0) {
#pragma unroll
            for (int rr = 0; rr < 4; ++rr) {
                float p = 1.f / (1.f + __expf(-(z[rr] + b3v)));
                tmpP[base + (q << 2) + rr] = p;   // coalesced (16 B per lane)
            }
        }
    }
}

// final: out[e] = tmpP[iperm[e]] (coalesced read+write; tmpP gather is L2-resident)
__global__ void k_out(const int* __restrict__ iperm, const float* __restrict__ tmpP,
                      void* __restrict__ outv, const int* __restrict__ flag) {
    int e = blockIdx.x * 256 + threadIdx.x;
    if (e >= N_EDGES) return;
    float p = tmpP[iperm[e]];
    if (*flag) ((float*)outv)[e] = p;
    else       ((unsigned short*)outv)[e] = f2bu(p);
}

// ---------------- launch ----------------

extern "C" void kernel_launch(void* const* d_in, const int* in_sizes, int n_in,
                              void* d_out, int out_size, void* d_ws, size_t ws_size,
                              hipStream_t stream) {
    (void)in_sizes; (void)n_in; (void)out_size; (void)ws_size;
    const void* x_r   = d_in[0];
    const int*  ei    = (const int*)d_in[1];
    const void* ew_r  = d_in[2];

    char* w = (char*)d_ws;
    float* h            = (float*)w;          w += (size_t)NH * 4;       // 12.8 MB
    unsigned short* hbf = (unsigned short*)w; w += (size_t)NH * 2;       // 6.4
    char* txr           = w;                  w += (size_t)NH * 8;       // 25.6 (4 bufs)
    unsigned int* pairs4 = (unsigned int*)w;  w += (size_t)N_EDGES * 4;  // 6.4
    unsigned int* rc    = (unsigned int*)w;   w += (size_t)N_EDGES * 4;  // 6.4 (adjacent!)
    int* iperm          = (int*)w;            w += (size_t)N_EDGES * 4;  // 6.4
    int* row_ptr        = (int*)w;            w += 200192;
    int* cnt            = (int*)w;            w += 200192;
    float* dis          = (float*)w;          w += 200192;
    float* dis2         = (float*)w;          w += 200192;
    float* cWin = (float*)w; w += 2048;
    float* cbin = (float*)w; w += 256;
    float* ccW1 = (float*)w; w += 26112;
    float* ccb1 = (float*)w; w += 384;
    float* ccW2 = (float*)w; w += 2304;
    float* ccb2 = (float*)w; w += 128;
    float* clns = (float*)w; w += 768;
    float* clnb = (float*)w; w += 768;
    float* ceW1 = (float*)w; w += 32768;
    float* ceb1 = (float*)w; w += 256;
    float* ceW2 = (float*)w; w += 8192;
    float* ceb2 = (float*)w; w += 128;
    float* ceW3 = (float*)w; w += 128;
    float* ceb3 = (float*)w; w += 128;
    unsigned short* w1h = (unsigned short*)w; w += 16384;   // f16 [128][64] packed ep_W1
    int* bsum = (int*)w; w += 1024;
    int* bpre = (int*)w; w += 1024;
    char* zero_base = w;
    float* stats = (float*)w; w += 1024;
    size_t zero_bytes = (size_t)(w - zero_base);
    float* coeffs = (float*)w; w += 128;
    int*   flag   = (int*)w;   w += 128;

    // setup-phase overlays (lifetimes disjoint with hosts):
    //  pcnt8  (12.8 MB) -> [pairs4|rc] contiguous region  [hist_row -> merge; dead before placeA writes pairs4]
    //  pref16 (25.6 MB) -> txr                             [merge -> placeA]
    //  pdeg16 (12.8 MB) -> h region                        [deg2 -> k_dis; h first written by inproj]
    //  tmpP   (6.4 MB)  -> pairs4 region                   [edgepred -> k_out; pairs4 dead]
    unsigned int* pcnt_u32 = (unsigned int*)pairs4;
    unsigned char* pcnt8   = (unsigned char*)pairs4;
    unsigned short* pref16 = (unsigned short*)txr;
    unsigned short* pdeg16 = (unsigned short*)h;
    float* tmpP            = (float*)pairs4;

    unsigned short* tx[4];
    for (int k = 0; k < 4; ++k) tx[k] = (unsigned short*)txr + (size_t)k * NH;
    unsigned short* ub = tx[0];   // k_uv runs after last spmm_ln: tx dead
    unsigned short* vb = tx[1];

    (void)hipMemsetAsync(zero_base, 0, zero_bytes, stream);

    k_detect<<<1, 64, 0, stream>>>(ew_r, flag);

    ConvArgs ca;
    const void* srcs[14] = {d_in[3], d_in[4], d_in[5], d_in[6], d_in[7], d_in[8], d_in[9],
                            d_in[10], d_in[11], d_in[12], d_in[13], d_in[14], d_in[15], d_in[16]};
    float* dsts[14] = {cWin, cbin, ccW1, ccb1, ccW2, ccb2, clns,
                       clnb, ceW1, ceb1, ceW2, ceb2, ceW3, ceb3};
    int sizes[14] = {512, 64, 6528, 96, 576, 18, 192, 192, 8192, 64, 2048, 32, 32, 1};
    int c = 0;
    for (int i = 0; i < 14; ++i) { ca.src[i] = srcs[i]; ca.dst[i] = dsts[i]; ca.cum[i] = c; c += sizes[i]; }
    ca.cum[14] = c;
    k_conv_small<<<(c + 255) / 256, 256, 0, stream>>>(ca, flag);
    k_w1h<<<32, 256, 0, stream>>>(ceW1, w1h);

    k_deg2<<<DSLC2, 1024, 0, stream>>>(ei, ew_r, flag, pdeg16);
    k_hist_row<<<RSLC, 1024, 0, stream>>>(ei, pcnt_u32);
    k_merge<<<196, 256, 0, stream>>>(pcnt8, cnt, pref16, bsum);
    k_scan_top<<<1, 256, 0, stream>>>(bsum, bpre, row_ptr);
    k_scan_fin<<<196, 256, 0, stream>>>(cnt, bpre, row_ptr);
    k_placeA<<<RSLC, 1024, 0, stream>>>(ei, ew_r, flag, row_ptr, pref16, pairs4, iperm);
    k_rc<<<12500, 256, 0, stream>>>(row_ptr, pairs4, rc);
    k_dis<<<196, 256, 0, stream>>>(pdeg16, dis, dis2);
    k_inproj<<<12500, 256, 0, stream>>>(x_r, cWin, cbin, dis, h, hbf, flag);

    for (int l = 0; l < NLAYERS; ++l) {
        k_stats<<<400, 256, 0, stream>>>(h, stats + l * 80);
        k_coeffs<<<1, 64, 0, stream>>>(stats + l * 80, ccW1, ccb1, ccW2, ccb2, l,
                                       coeffs + l * 8);
        const unsigned short* src = hbf;
        for (int k = 0; k < 4; ++k) {
            k_spmm<<<12500, 256, 0, stream>>>(src, tx[k], row_ptr, pairs4, dis2);
            src = tx[k];
        }
        k_spmm_ln<<<12500, 256, 0, stream>>>(tx[3], row_ptr, pairs4, h, hbf,
                                             tx[0], tx[1], tx[2], tx[3],
                                             coeffs + l * 8, dis, clns, clnb, l,
                                             (l == NLAYERS - 1) ? 1 : 0, d_out, flag);
    }

    k_uv<<<782, 256, 0, stream>>>(h, w1h, ub, vb);
    k_edgepred<<<2500, 256, 0, stream>>>(ub, vb, rc, ceb1, ceW2, ceb2, ceW3, ceb3, tmpP);
    k_out<<<6250, 256, 0, stream>>>(iperm, tmpP, d_out, flag);
}

// Round 13
// 795.954 us; speedup vs baseline: 1.3069x; 1.0009x over previous
//
#include <hip/hip_runtime.h>
#include <hip/hip_bf16.h>
#include <hip/hip_fp16.h>

typedef __hip_bfloat16 bf16;
typedef __attribute__((ext_vector_type(8))) short short8;
typedef __attribute__((ext_vector_type(8))) _Float16 half8;
typedef __attribute__((ext_vector_type(2))) _Float16 half2v;
typedef __attribute__((ext_vector_type(4))) float f32x4;

#define N_NODES 50000
#define N_EDGES 1600000
#define FIN 8
#define HD 64
#define NH (N_NODES * HD)
#define NLAYERS 3

// CSR build geometry
#define RSLC 256                 // row slices, E/RSLC = 6250
#define EPR (N_EDGES / RSLC)
#define NWORDS 12500             // 50000 nodes as packed u8 in u32
// degree build: 128 slices, full-node u16 fixed-point LDS histogram (no global atomics)
// NOTE r10 lesson: blocks partition EDGES; every block must count ALL its edges' cols
// (full-node table). A half-range table drops the complementary cols entirely.
#define DSLC2 128
#define EPD2 (N_EDGES / DSLC2)   // 12500
#define DWORDS 25000             // 50000 nodes as packed u16 in u32 (100 KB LDS)
#define DEGSCALE 512.0f

__device__ __forceinline__ float b2f(bf16 v) { return __bfloat162float(v); }
__device__ __forceinline__ float bu2f(unsigned int u) { return __uint_as_float(u << 16); }
__device__ __forceinline__ unsigned short f2bu(float f) {
    unsigned int x = __float_as_uint(f);
    unsigned int r = x + 0x7FFFu + ((x >> 16) & 1u);
    return (unsigned short)(r >> 16);
}
__device__ __forceinline__ unsigned short f2h(float f) {
    _Float16 h = (_Float16)f;
    return *(unsigned short*)&h;
}
// low 16 bits as fp16 -> float (single v_cvt_f32_f16)
union H16 { unsigned short b; _Float16 h; };
__device__ __forceinline__ float h16f(unsigned u) {
    H16 x; x.b = (unsigned short)u;
    return (float)x.h;
}

// ---------------- dtype detection ----------------
__global__ void k_detect(const void* __restrict__ ew, int* __restrict__ flag) {
    int ok = 1;
    for (int i = threadIdx.x; i < 512; i += 64) {
        float v = b2f(((const bf16*)ew)[i]);
        if (!(v >= 0.f && v <= 1.f)) ok = 0;
    }
    unsigned long long m = __ballot(ok);
    if (threadIdx.x == 0) *flag = (m == 0xFFFFFFFFFFFFFFFFull) ? 0 : 1;
}

struct ConvArgs {
    const void* src[14];
    float* dst[14];
    int cum[15];
};

__global__ void k_conv_small(ConvArgs a, const int* __restrict__ flag) {
    int q = blockIdx.x * 256 + threadIdx.x;
    if (q >= a.cum[14]) return;
    int s = 0;
    while (q >= a.cum[s + 1]) ++s;
    int off = q - a.cum[s];
    if (*flag) a.dst[s][off] = ((const float*)a.src[s])[off];
    else       a.dst[s][off] = bu2f(((const unsigned short*)a.src[s])[off]);
}

// pack ep_W1 (f32 [64][128]) into f16 [128][64]: rows 0-63 = au weights (W1[f][0:64]),
// rows 64-127 = av weights (W1[f][64:128]) — B-operand layout for MFMA k_uv.
__global__ void k_w1h(const float* __restrict__ W1, unsigned short* __restrict__ w1h) {
    int i = blockIdx.x * 256 + threadIdx.x;
    if (i >= 8192) return;
    int r = i >> 6, k = i & 63;
    float v = (r < 64) ? W1[r * 128 + k] : W1[(r - 64) * 128 + 64 + k];
    w1h[i] = f2h(v);
}

// ---------------- degree: LDS u16 fixed-point histogram, NO global atomics ----------------
// 128 blocks x 12500 edges; full 50000-node LDS table (u16 fp, scale 512, 2/u32, 100KB).
// Carry between packed halves needs >=128 edges on one node in one slice: P~0.
// Partials dumped (full, no pre-zero needed); k_dis sums 128 u16 slices EXACTLY in integer.
__global__ void __launch_bounds__(1024) k_deg2(const int* __restrict__ ei,
                                               const void* __restrict__ ewr,
                                               const int* __restrict__ flag,
                                               unsigned short* __restrict__ pdeg16) {
    __shared__ unsigned int sm[DWORDS];
    int b = blockIdx.x, t = threadIdx.x;
    for (int i = t; i < DWORDS; i += 1024) sm[i] = 0;
    __syncthreads();
    int f32 = *flag;
    int ebase = b * EPD2;
    for (int el = t; el < EPD2; el += 1024) {
        int e = ebase + el;
        int c = ei[N_EDGES + e];
        float w = f32 ? ((const float*)ewr)[e] : bu2f(((const unsigned short*)ewr)[e]);
        unsigned fx = (unsigned)__float2int_rn(w * DEGSCALE);
        atomicAdd(&sm[c >> 1], fx << ((c & 1) * 16));
    }
    __syncthreads();
    unsigned int* dst = (unsigned int*)(pdeg16 + (size_t)b * N_NODES);
    for (int i = t; i < DWORDS; i += 1024) dst[i] = sm[i];
}

// dis/dis2 from the 128 u16 partial slices (integer-exact sum)
__global__ void k_dis(const unsigned short* __restrict__ pdeg16,
                      float* __restrict__ dis, float* __restrict__ dis2) {
    int n = blockIdx.x * 256 + threadIdx.x;
    if (n >= N_NODES) return;
    unsigned s = 0;
#pragma unroll 8
    for (int k = 0; k < DSLC2; ++k) s += pdeg16[(size_t)k * N_NODES + n];
    float d = (float)s * (1.f / DEGSCALE);
    float di = fminf(rsqrtf(d), 1e6f);   // rsqrt(0)=inf -> 1e6, matches ref clamp
    dis[n] = di;
    dis2[n] = di * di;
}

// ---------------- CSR build: byte-packed LDS histograms, no global atomics ----------------
// 1024 threads: grid=256 is 1 block/CU (50KB LDS); 16 waves/CU vs 4 -> 4x latency hiding.

__global__ void __launch_bounds__(1024) k_hist_row(const int* __restrict__ ei,
                                                   unsigned int* __restrict__ pcnt_u32) {
    __shared__ unsigned int sm[NWORDS];
    int b = blockIdx.x, t = threadIdx.x;
    for (int i = t; i < NWORDS; i += 1024) sm[i] = 0;
    __syncthreads();
    int ebase = b * EPR;
    for (int el = t; el < EPR; el += 1024) {
        int r = ei[ebase + el];
        atomicAdd(&sm[r >> 2], 1u << ((r & 3) * 8));
    }
    __syncthreads();
    unsigned int* dst = pcnt_u32 + (size_t)b * NWORDS;
    for (int i = t; i < NWORDS; i += 1024) dst[i] = sm[i];
}

// per-node: 256-slice u8 prefix -> pref16, total -> cnt, block sums
__global__ void k_merge(const unsigned char* __restrict__ pcnt8,
                        int* __restrict__ cnt,
                        unsigned short* __restrict__ pref16, int* __restrict__ bsum) {
    __shared__ int red[256];
    int t = threadIdx.x;
    int n = blockIdx.x * 256 + t;
    int run = 0;
    if (n < N_NODES) {
#pragma unroll 8
        for (int s = 0; s < RSLC; ++s) {
            pref16[(size_t)s * N_NODES + n] = (unsigned short)run;
            run += pcnt8[(size_t)s * N_NODES + n];
        }
        cnt[n] = run;
    }
    red[t] = run;
    __syncthreads();
    for (int off = 128; off; off >>= 1) {
        if (t < off) red[t] += red[t + off];
        __syncthreads();
    }
    if (t == 0) bsum[blockIdx.x] = red[0];
}

__global__ void k_scan_top(const int* __restrict__ bsum, int* __restrict__ bpre,
                           int* __restrict__ row_ptr) {
    __shared__ int sm[256];
    int t = threadIdx.x;
    int v = (t < 196) ? bsum[t] : 0;
    sm[t] = v;
    __syncthreads();
    int val = v;
    for (int off = 1; off < 256; off <<= 1) {
        int other = (t >= off) ? sm[t - off] : 0;
        __syncthreads();
        val += other;
        sm[t] = val;
        __syncthreads();
    }
    bpre[t] = val - v;
    if (t == 0) row_ptr[N_NODES] = N_EDGES;
}

__global__ void k_scan_fin(const int* __restrict__ cnt, const int* __restrict__ bpre,
                           int* __restrict__ row_ptr) {
    __shared__ int sm[256];
    int t = threadIdx.x;
    int n = blockIdx.x * 256 + t;
    int v = (n < N_NODES) ? cnt[n] : 0;
    sm[t] = v;
    __syncthreads();
    int val = v;
    for (int off = 1; off < 256; off <<= 1) {
        int other = (t >= off) ? sm[t - off] : 0;
        __syncthreads();
        val += other;
        sm[t] = val;
        __syncthreads();
    }
    if (n < N_NODES) row_ptr[n] = bpre[blockIdx.x] + val - v;
}

// placement: per-slice u8 ordinal in LDS; writes pairs4[pos]=(c<<16|w_fp16) scattered (4 B)
// + iperm[e]=pos coalesced. ei/ew reads coalesced. 1024 threads (16 waves/CU at 1 blk/CU).
__global__ void __launch_bounds__(1024) k_placeA(const int* __restrict__ ei,
                                                 const void* __restrict__ ewr,
                                                 const int* __restrict__ flag,
                                                 const int* __restrict__ row_ptr,
                                                 const unsigned short* __restrict__ pref16,
                                                 unsigned int* __restrict__ pairs4,
                                                 int* __restrict__ iperm) {
    __shared__ unsigned int sm[NWORDS];
    int b = blockIdx.x, t = threadIdx.x;
    for (int i = t; i < NWORDS; i += 1024) sm[i] = 0;
    __syncthreads();
    int f32 = *flag;
    int ebase = b * EPR;
    const unsigned short* pr = pref16 + (size_t)b * N_NODES;
    for (int el = t; el < EPR; el += 1024) {
        int e = ebase + el;
        int r = ei[e];
        int c = ei[N_EDGES + e];
        float w = f32 ? ((const float*)ewr)[e] : bu2f(((const unsigned short*)ewr)[e]);
        int sh = (r & 3) * 8;
        unsigned old = atomicAdd(&sm[r >> 2], 1u << sh);
        int ord = (old >> sh) & 0xFF;
        int pos = row_ptr[r] + pr[r] + ord;
        pairs4[pos] = ((unsigned)c << 16) | (unsigned)f2h(w);  // scattered 4 B
        iperm[e] = pos;                                        // coalesced
    }
}

// rc rebuild: wave per node, coalesced read of pairs4 + coalesced write of rc
__global__ void __launch_bounds__(256) k_rc(const int* __restrict__ row_ptr,
                                            const unsigned int* __restrict__ pairs4,
                                            unsigned int* __restrict__ rc) {
    int lane = threadIdx.x & 63;
    int wv = __builtin_amdgcn_readfirstlane((int)(blockIdx.x * 4 + (threadIdx.x >> 6)));
    int s = __builtin_amdgcn_readfirstlane(row_ptr[wv]);
    int e = __builtin_amdgcn_readfirstlane(row_ptr[wv + 1]);
    unsigned rhi = ((unsigned)wv) << 16;
    for (int pos = s + lane; pos < e; pos += 64)
        rc[pos] = (pairs4[pos] >> 16) | rhi;
}

// ---------------- input projection: h (f32, unscaled) + hbf = bf16(dis*h) scaled state ----

__global__ void k_inproj(const void* __restrict__ xr_, const float* __restrict__ W,
                         const float* __restrict__ b, const float* __restrict__ dis,
                         float* __restrict__ h,
                         unsigned short* __restrict__ h_bf, const int* __restrict__ flag) {
    __shared__ float Wt[FIN * HD];
    __shared__ float bs[HD];
    int t = threadIdx.x;
    int f32 = *flag;
    for (int idx = t; idx < FIN * HD; idx += 256) {
        int f = idx >> 3, j = idx & 7;
        Wt[j * 64 + f] = W[idx];
    }
    if (t < 64) bs[t] = b[t];
    __syncthreads();
    int gid = blockIdx.x * 256 + t;
    if (gid < NH) {
        int i = gid >> 6, f = gid & 63;
        const float* xf = (const float*)xr_ + i * FIN;
        const unsigned short* xb = (const unsigned short*)xr_ + i * FIN;
        float acc = bs[f];
#pragma unroll
        for (int j = 0; j < FIN; ++j) {
            float xv = f32 ? xf[j] : bu2f(xb[j]);
            acc += xv * Wt[j * 64 + f];
        }
        h[gid] = acc;
        h_bf[gid] = f2bu(acc * dis[i]);   // scaled state s0 = dis .* h
    }
}

// ---------------- stats + coefficient MLP ----------------

__global__ void k_stats(const float* __restrict__ h, float* __restrict__ stats) {
    __shared__ float ssum[256], ssq[256];
    int t = threadIdx.x;
    float ls = 0.f, lq = 0.f;
    for (int idx = blockIdx.x * 256 + t; idx < NH; idx += 102400) {
        float v = h[idx];
        ls += v; lq += v * v;
    }
    ssum[t] = ls; ssq[t] = lq;
    __syncthreads();
    if (t < 64) {
        float a = ssum[t] + ssum[t + 64] + ssum[t + 128] + ssum[t + 192];
        atomicAdd(&stats[t], a);
        float q = ssq[t] + ssq[t + 64] + ssq[t + 128] + ssq[t + 192];
        for (int off = 32; off; off >>= 1) q += __shfl_down(q, off, 64);
        if (t == 0) atomicAdd(&stats[64], q);
    }
}

__global__ void k_coeffs(const float* __restrict__ stats,
                         const float* __restrict__ W1, const float* __restrict__ b1,
                         const float* __restrict__ W2, const float* __restrict__ b2,
                         int layer, float* __restrict__ coeffs) {
    __shared__ float ci[68];
    __shared__ float hid[32];
    __shared__ float lg[6];
    int t = threadIdx.x;
    float sf = stats[t];
    float tot = sf;
    for (int off = 1; off < 64; off <<= 1) tot += __shfl_xor(tot, off, 64);
    ci[t] = sf / (float)N_NODES;
    if (t == 0) {
        float sumsq = stats[64];
        float mean = tot / (float)NH;
        float var = (sumsq - (float)NH * mean * mean) / (float)(NH - 1);
        ci[64] = mean;
        ci[65] = sqrtf(fmaxf(var, 0.f));
        ci[66] = (float)N_NODES;
        ci[67] = (float)N_EDGES;
    }
    __syncthreads();
    if (t < 32) {
        float a = b1[layer * 32 + t];
        const float* wr = W1 + (layer * 32 + t) * 68;
        for (int j = 0; j < 68; ++j) a += ci[j] * wr[j];
        hid[t] = fmaxf(a, 0.f);
    }
    __syncthreads();
    if (t < 6) {
        float a = b2[layer * 6 + t];
        const float* wr = W2 + (layer * 6 + t) * 32;
        for (int g = 0; g < 32; ++g) a += hid[g] * wr[g];
        lg[t] = a;
    }
    __syncthreads();
    if (t == 0) {
        float mx = lg[0];
        for (int p = 1; p < 6; ++p) mx = fmaxf(mx, lg[p]);
        float s = 0.f, e[6];
        for (int p = 0; p < 6; ++p) { e[p] = expf(lg[p] - mx); s += e[p]; }
        for (int p = 0; p < 6; ++p) coeffs[p] = e[p] / s;
    }
}

// ---------------- SpMM hop: wave per node, scalar pair loads, 16-deep gather unroll -------
// scaled-state algebra: s_{k+1}[r] = dis2[r] * sum_e w_e * s_k[col]
// (measured-good structure; two XCD-split variants both regressed — keep this.)

__device__ __forceinline__ float acc_range(const unsigned short* __restrict__ txo,
                                           const unsigned int* __restrict__ pairs4,
                                           int j0, int j1, int lane, float acc) {
    int j = j0;
    for (; j + 15 < j1; j += 16) {
        unsigned p0 = pairs4[j],      p1 = pairs4[j + 1],  p2 = pairs4[j + 2],  p3 = pairs4[j + 3];
        unsigned p4 = pairs4[j + 4],  p5 = pairs4[j + 5],  p6 = pairs4[j + 6],  p7 = pairs4[j + 7];
        unsigned p8 = pairs4[j + 8],  p9 = pairs4[j + 9],  pa = pairs4[j + 10], pb = pairs4[j + 11];
        unsigned pc = pairs4[j + 12], pd = pairs4[j + 13], pe = pairs4[j + 14], pf = pairs4[j + 15];
        float g0 = bu2f(txo[(p0 >> 16) * 64 + lane]);
        float g1 = bu2f(txo[(p1 >> 16) * 64 + lane]);
        float g2 = bu2f(txo[(p2 >> 16) * 64 + lane]);
        float g3 = bu2f(txo[(p3 >> 16) * 64 + lane]);
        float g4 = bu2f(txo[(p4 >> 16) * 64 + lane]);
        float g5 = bu2f(txo[(p5 >> 16) * 64 + lane]);
        float g6 = bu2f(txo[(p6 >> 16) * 64 + lane]);
        float g7 = bu2f(txo[(p7 >> 16) * 64 + lane]);
        float g8 = bu2f(txo[(p8 >> 16) * 64 + lane]);
        float g9 = bu2f(txo[(p9 >> 16) * 64 + lane]);
        float ga = bu2f(txo[(pa >> 16) * 64 + lane]);
        float gb = bu2f(txo[(pb >> 16) * 64 + lane]);
        float gc = bu2f(txo[(pc >> 16) * 64 + lane]);
        float gd = bu2f(txo[(pd >> 16) * 64 + lane]);
        float ge = bu2f(txo[(pe >> 16) * 64 + lane]);
        float gf = bu2f(txo[(pf >> 16) * 64 + lane]);
        acc += h16f(p0) * g0 + h16f(p1) * g1 + h16f(p2) * g2 + h16f(p3) * g3;
        acc += h16f(p4) * g4 + h16f(p5) * g5 + h16f(p6) * g6 + h16f(p7) * g7;
        acc += h16f(p8) * g8 + h16f(p9) * g9 + h16f(pa) * ga + h16f(pb) * gb;
        acc += h16f(pc) * gc + h16f(pd) * gd + h16f(pe) * ge + h16f(pf) * gf;
    }
    for (; j + 7 < j1; j += 8) {
        unsigned p0 = pairs4[j],     p1 = pairs4[j + 1], p2 = pairs4[j + 2], p3 = pairs4[j + 3];
        unsigned p4 = pairs4[j + 4], p5 = pairs4[j + 5], p6 = pairs4[j + 6], p7 = pairs4[j + 7];
        float g0 = bu2f(txo[(p0 >> 16) * 64 + lane]);
        float g1 = bu2f(txo[(p1 >> 16) * 64 + lane]);
        float g2 = bu2f(txo[(p2 >> 16) * 64 + lane]);
        float g3 = bu2f(txo[(p3 >> 16) * 64 + lane]);
        float g4 = bu2f(txo[(p4 >> 16) * 64 + lane]);
        float g5 = bu2f(txo[(p5 >> 16) * 64 + lane]);
        float g6 = bu2f(txo[(p6 >> 16) * 64 + lane]);
        float g7 = bu2f(txo[(p7 >> 16) * 64 + lane]);
        acc += h16f(p0) * g0 + h16f(p1) * g1 + h16f(p2) * g2 + h16f(p3) * g3;
        acc += h16f(p4) * g4 + h16f(p5) * g5 + h16f(p6) * g6 + h16f(p7) * g7;
    }
    for (; j < j1; ++j) {
        unsigned p = pairs4[j];
        acc += h16f(p) * bu2f(txo[(p >> 16) * 64 + lane]);
    }
    return acc;
}

__global__ void __launch_bounds__(256) k_spmm(
    const unsigned short* __restrict__ txo, unsigned short* __restrict__ txn,
    const int* __restrict__ row_ptr, const unsigned int* __restrict__ pairs4,
    const float* __restrict__ dis2) {
    int lane = threadIdx.x & 63;
    int wv = __builtin_amdgcn_readfirstlane((int)(blockIdx.x * 4 + (threadIdx.x >> 6)));
    int s = __builtin_amdgcn_readfirstlane(row_ptr[wv]);
    int e = __builtin_amdgcn_readfirstlane(row_ptr[wv + 1]);
    float acc = acc_range(txo, pairs4, s, e, lane, 0.f);
    float d2 = dis2[wv];
    txn[wv * 64 + lane] = f2bu(acc * d2);
}

// ---------------- fused last hop + polynomial combine + layernorm ----------------
// t1..t4 hold scaled s_k; tx_k = s_k / dis[r]; hop5: tx5 = dis[r] * acc

__global__ void __launch_bounds__(256) k_spmm_ln(
    const unsigned short* __restrict__ txo,
    const int* __restrict__ row_ptr, const unsigned int* __restrict__ pairs4,
    float* __restrict__ h, unsigned short* __restrict__ h_bf,
    const unsigned short* __restrict__ t1, const unsigned short* __restrict__ t2,
    const unsigned short* __restrict__ t3, const unsigned short* __restrict__ t4,
    const float* __restrict__ coeffs, const float* __restrict__ dis,
    const float* __restrict__ sc, const float* __restrict__ bi,
    int layer, int last, void* __restrict__ outv, const int* __restrict__ flag) {
    int lane = threadIdx.x & 63;
    int wv = __builtin_amdgcn_readfirstlane((int)(blockIdx.x * 4 + (threadIdx.x >> 6)));
    int s = __builtin_amdgcn_readfirstlane(row_ptr[wv]);
    int e = __builtin_amdgcn_readfirstlane(row_ptr[wv + 1]);
    float acc = acc_range(txo, pairs4, s, e, lane, 0.f);
    int o = wv * 64 + lane;
    float ds = dis[wv];
    float invd = 1.f / ds;
    float c0 = coeffs[0], c1 = coeffs[1], c2 = coeffs[2],
          c3 = coeffs[3], c4 = coeffs[4], c5 = coeffs[5];
    float v = (1.f + c0) * h[o] +
              invd * (c1 * bu2f(t1[o]) + c2 * bu2f(t2[o]) +
                      c3 * bu2f(t3[o]) + c4 * bu2f(t4[o])) +
              c5 * ds * acc;
    float m = v;
    for (int off = 1; off < 64; off <<= 1) m += __shfl_xor(m, off, 64);
    m *= (1.f / 64.f);
    float d = v - m;
    float q = d * d;
    for (int off = 1; off < 64; off <<= 1) q += __shfl_xor(q, off, 64);
    float var = q * (1.f / 64.f);
    float y = d / sqrtf(var + 1e-5f) * sc[layer * 64 + lane] + bi[layer * 64 + lane];
    h[o] = y;
    h_bf[o] = f2bu(y * ds);   // next layer's scaled state s0
    if (last) {
        if (*flag) ((float*)outv)[N_EDGES + o] = y;
        else       ((unsigned short*)outv)[N_EDGES + o] = f2bu(y);
    }
}

union U4H8 { uint4 u; half8 h; };

// ---------------- edge predictor projection: MFMA GEMM h[50000x64] @ w1h^T -> ub|vb ------
// r11 counters: scalar k_uv was LDS-read-issue-bound (192 ds_read/thread, 52 us, 68% VALU).
// One wave per 16-node tile (3125 exact), 8 col-tiles x 2 MFMA (K=64); fragment mapping
// identical to the verified k_edgepred pattern.
__global__ void __launch_bounds__(256) k_uv(const float* __restrict__ h,
                                            const unsigned short* __restrict__ w1h,
                                            unsigned short* __restrict__ ub,
                                            unsigned short* __restrict__ vb) {
    int t = threadIdx.x;
    int lane = t & 63;
    int m = lane & 15, q = lane >> 4;
    int wv = blockIdx.x * 4 + (t >> 6);
    if (wv >= N_NODES / 16) return;
    int node0 = wv * 16;
    const float* hrow = h + (size_t)(node0 + m) * 64 + q * 8;
    U4H8 a0, a1;
#pragma unroll
    for (int j = 0; j < 8; ++j) a0.h[j] = (_Float16)hrow[j];
#pragma unroll
    for (int j = 0; j < 8; ++j) a1.h[j] = (_Float16)hrow[32 + j];
#pragma unroll
    for (int ct = 0; ct < 8; ++ct) {
        const unsigned short* wrow = w1h + (size_t)(ct * 16 + m) * 64 + q * 8;
        U4H8 b0, b1;
        b0.u = *(const uint4*)wrow;
        b1.u = *(const uint4*)(wrow + 32);
        f32x4 acc = {0.f, 0.f, 0.f, 0.f};
        acc = __builtin_amdgcn_mfma_f32_16x16x32_f16(a0.h, b0.h, acc, 0, 0, 0);
        acc = __builtin_amdgcn_mfma_f32_16x16x32_f16(a1.h, b1.h, acc, 0, 0, 0);
        int feat = ct * 16 + m;
        unsigned short* dst = (feat < 64) ? (ub + feat) : (vb + (feat - 64));
#pragma unroll
        for (int r = 0; r < 4; ++r) {
            int node = node0 + q * 4 + r;
            dst[(size_t)node * 64] = f2h(acc[r]);
        }
    }
}

// packed fp16 relu(u + v + b) via native _Float16 vectors (avoids __hmax2 overload clash)
__device__ __forceinline__ unsigned h2rel(unsigned uu, unsigned vv, half2v b) {
    half2v a = *(half2v*)&uu + *(half2v*)&vv + b;
    a[0] = a[0] > (_Float16)0 ? a[0] : (_Float16)0;
    a[1] = a[1] > (_Float16)0 ? a[1] : (_Float16)0;
    return *(unsigned*)&a;
}

// MFMA f16 edge predictor, 2-tile unrolled: 32 CSR-ordered edges per wave-iteration.
// r12 counters: 4 independent gathers/iter -> VMEM-queue/latency-bound (52 us, 46% VALU,
// 15% HBM, 4.5% Mfma). Issue all 8 row-gather pairs for 2 tiles up front -> 2x MLP.
// 100000 tiles = 50000 pairs; grid 2500 x 4 waves -> 5 iterations/wave exactly.
__global__ void __launch_bounds__(256) k_edgepred(
    const unsigned short* __restrict__ ub, const unsigned short* __restrict__ vb,
    const unsigned int* __restrict__ rc,
    const float* __restrict__ eb1, const float* __restrict__ eW2,
    const float* __restrict__ eb2, const float* __restrict__ eW3,
    const float* __restrict__ eb3, float* __restrict__ tmpP) {
    int t = threadIdx.x;
    int lane = t & 63;
    int m = lane & 15, q = lane >> 4;

    half8 B00, B01, B10, B11;
#pragma unroll
    for (int j = 0; j < 8; ++j) {
        B00[j] = (_Float16)eW2[(m) * 64      + q * 8 + j];
        B01[j] = (_Float16)eW2[(m) * 64 + 32 + q * 8 + j];
        B10[j] = (_Float16)eW2[(m + 16) * 64      + q * 8 + j];
        B11[j] = (_Float16)eW2[(m + 16) * 64 + 32 + q * 8 + j];
    }
    half2v b1p0[4], b1p1[4];
#pragma unroll
    for (int wq = 0; wq < 4; ++wq) {
        b1p0[wq][0] = (_Float16)eb1[q * 8 + 2 * wq];
        b1p0[wq][1] = (_Float16)eb1[q * 8 + 2 * wq + 1];
        b1p1[wq][0] = (_Float16)eb1[32 + q * 8 + 2 * wq];
        b1p1[wq][1] = (_Float16)eb1[32 + q * 8 + 2 * wq + 1];
    }
    float w3a = eW3[m], w3b = eW3[16 + m];
    float b2a = eb2[m], b2b = eb2[16 + m];
    float b3v = eb3[0];

    int gw = blockIdx.x * 4 + (t >> 6);
    const int NW = 2500 * 4;
    for (int tp = gw; tp < N_EDGES / 32; tp += NW) {
        int base0 = (tp * 2) << 4;
        int base1 = base0 + 16;
        unsigned rcv0 = rc[base0 + m];
        unsigned rcv1 = rc[base1 + m];
        const unsigned short* up0 = ub + (rcv0 >> 16) * 64;
        const unsigned short* vp0 = vb + (rcv0 & 0xFFFFu) * 64;
        const unsigned short* up1 = ub + (rcv1 >> 16) * 64;
        const unsigned short* vp1 = vb + (rcv1 & 0xFFFFu) * 64;
        uint4 U00 = *(const uint4*)(up0 + q * 8);
        uint4 U01 = *(const uint4*)(up0 + 32 + q * 8);
        uint4 V00 = *(const uint4*)(vp0 + q * 8);
        uint4 V01 = *(const uint4*)(vp0 + 32 + q * 8);
        uint4 U10 = *(const uint4*)(up1 + q * 8);
        uint4 U11 = *(const uint4*)(up1 + 32 + q * 8);
        uint4 V10 = *(const uint4*)(vp1 + q * 8);
        uint4 V11 = *(const uint4*)(vp1 + 32 + q * 8);

        // ---- tile 0 ----
        U4H8 a0, a1;
        a0.u.x = h2rel(U00.x, V00.x, b1p0[0]);
        a0.u.y = h2rel(U00.y, V00.y, b1p0[1]);
        a0.u.z = h2rel(U00.z, V00.z, b1p0[2]);
        a0.u.w = h2rel(U00.w, V00.w, b1p0[3]);
        a1.u.x = h2rel(U01.x, V01.x, b1p1[0]);
        a1.u.y = h2rel(U01.y, V01.y, b1p1[1]);
        a1.u.z = h2rel(U01.z, V01.z, b1p1[2]);
        a1.u.w = h2rel(U01.w, V01.w, b1p1[3]);
        f32x4 acc0 = {0.f, 0.f, 0.f, 0.f};
        f32x4 acc1 = {0.f, 0.f, 0.f, 0.f};
        acc0 = __builtin_amdgcn_mfma_f32_16x16x32_f16(a0.h, B00, acc0, 0, 0, 0);
        acc0 = __builtin_amdgcn_mfma_f32_16x16x32_f16(a1.h, B01, acc0, 0, 0, 0);
        acc1 = __builtin_amdgcn_mfma_f32_16x16x32_f16(a0.h, B10, acc1, 0, 0, 0);
        acc1 = __builtin_amdgcn_mfma_f32_16x16x32_f16(a1.h, B11, acc1, 0, 0, 0);
        float z0[4];
#pragma unroll
        for (int rr = 0; rr < 4; ++rr) {
            z0[rr] = w3a * fmaxf(acc0[rr] + b2a, 0.f) + w3b * fmaxf(acc1[rr] + b2b, 0.f);
            z0[rr] += __shfl_xor(z0[rr], 1, 64);
            z0[rr] += __shfl_xor(z0[rr], 2, 64);
            z0[rr] += __shfl_xor(z0[rr], 4, 64);
            z0[rr] += __shfl_xor(z0[rr], 8, 64);
        }

        // ---- tile 1 ----
        U4H8 c0, c1;
        c0.u.x = h2rel(U10.x, V10.x, b1p0[0]);
        c0.u.y = h2rel(U10.y, V10.y, b1p0[1]);
        c0.u.z = h2rel(U10.z, V10.z, b1p0[2]);
        c0.u.w = h2rel(U10.w, V10.w, b1p0[3]);
        c1.u.x = h2rel(U11.x, V11.x, b1p1[0]);
        c1.u.y = h2rel(U11.y, V11.y, b1p1[1]);
        c1.u.z = h2rel(U11.z, V11.z, b1p1[2]);
        c1.u.w = h2rel(U11.w, V11.w, b1p1[3]);
        f32x4 acc2 = {0.f, 0.f, 0.f, 0.f};
        f32x4 acc3 = {0.f, 0.f, 0.f, 0.f};
        acc2 = __builtin_amdgcn_mfma_f32_16x16x32_f16(c0.h, B00, acc2, 0, 0, 0);
        acc2 = __builtin_amdgcn_mfma_f32_16x16x32_f16(c1.h, B01, acc2, 0, 0, 0);
        acc3 = __builtin_amdgcn_mfma_f32_16x16x32_f16(c0.h, B10, acc3, 0, 0, 0);
        acc3 = __builtin_amdgcn_mfma_f32_16x16x32_f16(c1.h, B11, acc3, 0, 0, 0);
        float z1[4];
#pragma unroll
        for (int rr = 0; rr < 4; ++rr) {
            z1[rr] = w3a * fmaxf(acc2[rr] + b2a, 0.f) + w3b * fmaxf(acc3[rr] + b2b, 0.f);
            z1[rr] += __shfl_xor(z1[rr], 1, 64);
            z1[rr] += __shfl_xor(z1[rr], 2, 64);
            z1[rr] += __shfl_xor(z1[rr], 4, 64);
            z1[rr] += __shfl_xor(z1[rr], 8, 64);
        }

        if (m == 0) {
#pragma unroll
            for (int rr = 0; rr < 4; ++rr) {
                float p0 = 1.f / (1.f + __expf(-(z0[rr] + b3v)));
                float p1 = 1.f / (1.f + __expf(-(z1[rr] + b3v)));
                tmpP[base0 + (q << 2) + rr] = p0;
                tmpP[base1 + (q << 2) + rr] = p1;
            }
        }
    }
}

// final: out[e] = tmpP[iperm[e]] (coalesced read+write; tmpP gather is L2-resident)
__global__ void k_out(const int* __restrict__ iperm, const float* __restrict__ tmpP,
                      void* __restrict__ outv, const int* __restrict__ flag) {
    int e = blockIdx.x * 256 + threadIdx.x;
    if (e >= N_EDGES) return;
    float p = tmpP[iperm[e]];
    if (*flag) ((float*)outv)[e] = p;
    else       ((unsigned short*)outv)[e] = f2bu(p);
}

// ---------------- launch ----------------

extern "C" void kernel_launch(void* const* d_in, const int* in_sizes, int n_in,
                              void* d_out, int out_size, void* d_ws, size_t ws_size,
                              hipStream_t stream) {
    (void)in_sizes; (void)n_in; (void)out_size; (void)ws_size;
    const void* x_r   = d_in[0];
    const int*  ei    = (const int*)d_in[1];
    const void* ew_r  = d_in[2];

    char* w = (char*)d_ws;
    float* h            = (float*)w;          w += (size_t)NH * 4;       // 12.8 MB
    unsigned short* hbf = (unsigned short*)w; w += (size_t)NH * 2;       // 6.4
    char* txr           = w;                  w += (size_t)NH * 8;       // 25.6 (4 bufs)
    unsigned int* pairs4 = (unsigned int*)w;  w += (size_t)N_EDGES * 4;  // 6.4
    unsigned int* rc    = (unsigned int*)w;   w += (size_t)N_EDGES * 4;  // 6.4 (adjacent!)
    int* iperm          = (int*)w;            w += (size_t)N_EDGES * 4;  // 6.4
    int* row_ptr        = (int*)w;            w += 200192;
    int* cnt            = (int*)w;            w += 200192;
    float* dis          = (float*)w;          w += 200192;
    float* dis2         = (float*)w;          w += 200192;
    float* cWin = (float*)w; w += 2048;
    float* cbin = (float*)w; w += 256;
    float* ccW1 = (float*)w; w += 26112;
    float* ccb1 = (float*)w; w += 384;
    float* ccW2 = (float*)w; w += 2304;
    float* ccb2 = (float*)w; w += 128;
    float* clns = (float*)w; w += 768;
    float* clnb = (float*)w; w += 768;
    float* ceW1 = (float*)w; w += 32768;
    float* ceb1 = (float*)w; w += 256;
    float* ceW2 = (float*)w; w += 8192;
    float* ceb2 = (float*)w; w += 128;
    float* ceW3 = (float*)w; w += 128;
    float* ceb3 = (float*)w; w += 128;
    unsigned short* w1h = (unsigned short*)w; w += 16384;   // f16 [128][64] packed ep_W1
    int* bsum = (int*)w; w += 1024;
    int* bpre = (int*)w; w += 1024;
    char* zero_base = w;
    float* stats = (float*)w; w += 1024;
    size_t zero_bytes = (size_t)(w - zero_base);
    float* coeffs = (float*)w; w += 128;
    int*   flag   = (int*)w;   w += 128;

    // setup-phase overlays (lifetimes disjoint with hosts):
    //  pcnt8  (12.8 MB) -> [pairs4|rc] contiguous region  [hist_row -> merge; dead before placeA writes pairs4]
    //  pref16 (25.6 MB) -> txr                             [merge -> placeA]
    //  pdeg16 (12.8 MB) -> h region                        [deg2 -> k_dis; h first written by inproj]
    //  tmpP   (6.4 MB)  -> pairs4 region                   [edgepred -> k_out; pairs4 dead]
    unsigned int* pcnt_u32 = (unsigned int*)pairs4;
    unsigned char* pcnt8   = (unsigned char*)pairs4;
    unsigned short* pref16 = (unsigned short*)txr;
    unsigned short* pdeg16 = (unsigned short*)h;
    float* tmpP            = (float*)pairs4;

    unsigned short* tx[4];
    for (int k = 0; k < 4; ++k) tx[k] = (unsigned short*)txr + (size_t)k * NH;
    unsigned short* ub = tx[0];   // k_uv runs after last spmm_ln: tx dead
    unsigned short* vb = tx[1];

    (void)hipMemsetAsync(zero_base, 0, zero_bytes, stream);

    k_detect<<<1, 64, 0, stream>>>(ew_r, flag);

    ConvArgs ca;
    const void* srcs[14] = {d_in[3], d_in[4], d_in[5], d_in[6], d_in[7], d_in[8], d_in[9],
                            d_in[10], d_in[11], d_in[12], d_in[13], d_in[14], d_in[15], d_in[16]};
    float* dsts[14] = {cWin, cbin, ccW1, ccb1, ccW2, ccb2, clns,
                       clnb, ceW1, ceb1, ceW2, ceb2, ceW3, ceb3};
    int sizes[14] = {512, 64, 6528, 96, 576, 18, 192, 192, 8192, 64, 2048, 32, 32, 1};
    int c = 0;
    for (int i = 0; i < 14; ++i) { ca.src[i] = srcs[i]; ca.dst[i] = dsts[i]; ca.cum[i] = c; c += sizes[i]; }
    ca.cum[14] = c;
    k_conv_small<<<(c + 255) / 256, 256, 0, stream>>>(ca, flag);
    k_w1h<<<32, 256, 0, stream>>>(ceW1, w1h);

    k_deg2<<<DSLC2, 1024, 0, stream>>>(ei, ew_r, flag, pdeg16);
    k_hist_row<<<RSLC, 1024, 0, stream>>>(ei, pcnt_u32);
    k_merge<<<196, 256, 0, stream>>>(pcnt8, cnt, pref16, bsum);
    k_scan_top<<<1, 256, 0, stream>>>(bsum, bpre, row_ptr);
    k_scan_fin<<<196, 256, 0, stream>>>(cnt, bpre, row_ptr);
    k_placeA<<<RSLC, 1024, 0, stream>>>(ei, ew_r, flag, row_ptr, pref16, pairs4, iperm);
    k_rc<<<12500, 256, 0, stream>>>(row_ptr, pairs4, rc);
    k_dis<<<196, 256, 0, stream>>>(pdeg16, dis, dis2);
    k_inproj<<<12500, 256, 0, stream>>>(x_r, cWin, cbin, dis, h, hbf, flag);

    for (int l = 0; l < NLAYERS; ++l) {
        k_stats<<<400, 256, 0, stream>>>(h, stats + l * 80);
        k_coeffs<<<1, 64, 0, stream>>>(stats + l * 80, ccW1, ccb1, ccW2, ccb2, l,
                                       coeffs + l * 8);
        const unsigned short* src = hbf;
        for (int k = 0; k < 4; ++k) {
            k_spmm<<<12500, 256, 0, stream>>>(src, tx[k], row_ptr, pairs4, dis2);
            src = tx[k];
        }
        k_spmm_ln<<<12500, 256, 0, stream>>>(tx[3], row_ptr, pairs4, h, hbf,
                                             tx[0], tx[1], tx[2], tx[3],
                                             coeffs + l * 8, dis, clns, clnb, l,
                                             (l == NLAYERS - 1) ? 1 : 0, d_out, flag);
    }

    k_uv<<<782, 256, 0, stream>>>(h, w1h, ub, vb);
    k_edgepred<<<2500, 256, 0, stream>>>(ub, vb, rc, ceb1, ceW2, ceb2, ceW3, ceb3, tmpP);
    k_out<<<6250, 256, 0, stream>>>(iperm, tmpP, d_out, flag);
}

// Round 14
// 791.961 us; speedup vs baseline: 1.3135x; 1.0050x over previous
//
#include <hip/hip_runtime.h>
#include <hip/hip_bf16.h>
#include <hip/hip_fp16.h>

typedef __hip_bfloat16 bf16;
typedef __attribute__((ext_vector_type(8))) short short8;
typedef __attribute__((ext_vector_type(8))) _Float16 half8;
typedef __attribute__((ext_vector_type(2))) _Float16 half2v;
typedef __attribute__((ext_vector_type(4))) float f32x4;

#define N_NODES 50000
#define N_EDGES 1600000
#define FIN 8
#define HD 64
#define NH (N_NODES * HD)
#define NLAYERS 3

// CSR build geometry
#define RSLC 256                 // row slices, E/RSLC = 6250
#define EPR (N_EDGES / RSLC)
#define NWORDS 12500             // 50000 nodes as packed u8 in u32 (50 KB)
#define DWORDS 25000             // 50000 nodes as packed u16 in u32 (100 KB)
#define DEGSCALE 512.0f

__device__ __forceinline__ float b2f(bf16 v) { return __bfloat162float(v); }
__device__ __forceinline__ float bu2f(unsigned int u) { return __uint_as_float(u << 16); }
__device__ __forceinline__ unsigned short f2bu(float f) {
    unsigned int x = __float_as_uint(f);
    unsigned int r = x + 0x7FFFu + ((x >> 16) & 1u);
    return (unsigned short)(r >> 16);
}
__device__ __forceinline__ unsigned short f2h(float f) {
    _Float16 h = (_Float16)f;
    return *(unsigned short*)&h;
}
// low 16 bits as fp16 -> float (single v_cvt_f32_f16)
union H16 { unsigned short b; _Float16 h; };
__device__ __forceinline__ float h16f(unsigned u) {
    H16 x; x.b = (unsigned short)u;
    return (float)x.h;
}

// ---------------- dtype detection ----------------
__global__ void k_detect(const void* __restrict__ ew, int* __restrict__ flag) {
    int ok = 1;
    for (int i = threadIdx.x; i < 512; i += 64) {
        float v = b2f(((const bf16*)ew)[i]);
        if (!(v >= 0.f && v <= 1.f)) ok = 0;
    }
    unsigned long long m = __ballot(ok);
    if (threadIdx.x == 0) *flag = (m == 0xFFFFFFFFFFFFFFFFull) ? 0 : 1;
}

struct ConvArgs {
    const void* src[14];
    float* dst[14];
    int cum[15];
};

__global__ void k_conv_small(ConvArgs a, const int* __restrict__ flag) {
    int q = blockIdx.x * 256 + threadIdx.x;
    if (q >= a.cum[14]) return;
    int s = 0;
    while (q >= a.cum[s + 1]) ++s;
    int off = q - a.cum[s];
    if (*flag) a.dst[s][off] = ((const float*)a.src[s])[off];
    else       a.dst[s][off] = bu2f(((const unsigned short*)a.src[s])[off]);
}

// pack ep_W1 (f32 [64][128]) into f16 [128][64]: rows 0-63 = au weights (W1[f][0:64]),
// rows 64-127 = av weights (W1[f][64:128]) — B-operand layout for MFMA k_uv.
__global__ void k_w1h(const float* __restrict__ W1, unsigned short* __restrict__ w1h) {
    int i = blockIdx.x * 256 + threadIdx.x;
    if (i >= 8192) return;
    int r = i >> 6, k = i & 63;
    float v = (r < 64) ? W1[r * 128 + k] : W1[(r - 64) * 128 + 64 + k];
    w1h[i] = f2h(v);
}

// ---------------- FUSED row-hist + degree: ONE pass over ei, no global atomics ----------
// r13 rationale: deg2 (128 blocks = half GPU idle) + hist_row were separate full ei passes.
// Fused: 256 blocks x 6250 edges; row hist u8x4 (50 KB) + FULL-NODE u16 fixed-point degree
// table (100 KB) = 150 KB LDS < 160. Unlike r10's broken half-range split, every block
// counts ALL its edges' cols — no coverage partition. Degree stays integer-exact and the
// total integer sum is slice-partition-invariant -> dis is BIT-IDENTICAL to r11/r13.
// Overflow: u16 slot needs >=128 same-node edges in a 6250-edge slice (Poisson 0.125): P~0.
__global__ void __launch_bounds__(1024) k_histdeg2(const int* __restrict__ ei,
                                                   const void* __restrict__ ewr,
                                                   const int* __restrict__ flag,
                                                   unsigned int* __restrict__ pcnt_u32,
                                                   unsigned short* __restrict__ pdeg16) {
    __shared__ unsigned int sm_h[NWORDS];   // 50 KB
    __shared__ unsigned int sm_d[DWORDS];   // 100 KB
    int b = blockIdx.x, t = threadIdx.x;
    for (int i = t; i < NWORDS; i += 1024) sm_h[i] = 0;
    for (int i = t; i < DWORDS; i += 1024) sm_d[i] = 0;
    __syncthreads();
    int f32 = *flag;
    int ebase = b * EPR;
    for (int el = t; el < EPR; el += 1024) {
        int e = ebase + el;
        int r = ei[e];
        atomicAdd(&sm_h[r >> 2], 1u << ((r & 3) * 8));
        int c = ei[N_EDGES + e];
        float w = f32 ? ((const float*)ewr)[e] : bu2f(((const unsigned short*)ewr)[e]);
        unsigned fx = (unsigned)__float2int_rn(w * DEGSCALE);
        atomicAdd(&sm_d[c >> 1], fx << ((c & 1) * 16));
    }
    __syncthreads();
    unsigned int* dsth = pcnt_u32 + (size_t)b * NWORDS;
    for (int i = t; i < NWORDS; i += 1024) dsth[i] = sm_h[i];
    unsigned int* dstd = (unsigned int*)(pdeg16 + (size_t)b * N_NODES);
    for (int i = t; i < DWORDS; i += 1024) dstd[i] = sm_d[i];
}

// per-node: 256-slice u8 prefix -> pref16, total -> cnt, block sums; dis/dis2 from the
// 256 u16 partial slices (integer-exact sum; <= 256*65535 < 2^24, exact in u32).
__global__ void k_merge(const unsigned char* __restrict__ pcnt8,
                        const unsigned short* __restrict__ pdeg16,
                        int* __restrict__ cnt, float* __restrict__ dis,
                        float* __restrict__ dis2,
                        unsigned short* __restrict__ pref16, int* __restrict__ bsum) {
    __shared__ int red[256];
    int t = threadIdx.x;
    int n = blockIdx.x * 256 + t;
    int run = 0;
    if (n < N_NODES) {
#pragma unroll 8
        for (int s = 0; s < RSLC; ++s) {
            pref16[(size_t)s * N_NODES + n] = (unsigned short)run;
            run += pcnt8[(size_t)s * N_NODES + n];
        }
        cnt[n] = run;
        unsigned s = 0;
#pragma unroll 8
        for (int k = 0; k < RSLC; ++k) s += pdeg16[(size_t)k * N_NODES + n];
        float d = (float)s * (1.f / DEGSCALE);
        float di = fminf(rsqrtf(d), 1e6f);   // rsqrt(0)=inf -> 1e6, matches ref clamp
        dis[n] = di;
        dis2[n] = di * di;
    }
    red[t] = run;
    __syncthreads();
    for (int off = 128; off; off >>= 1) {
        if (t < off) red[t] += red[t + off];
        __syncthreads();
    }
    if (t == 0) bsum[blockIdx.x] = red[0];
}

__global__ void k_scan_top(const int* __restrict__ bsum, int* __restrict__ bpre,
                           int* __restrict__ row_ptr) {
    __shared__ int sm[256];
    int t = threadIdx.x;
    int v = (t < 196) ? bsum[t] : 0;
    sm[t] = v;
    __syncthreads();
    int val = v;
    for (int off = 1; off < 256; off <<= 1) {
        int other = (t >= off) ? sm[t - off] : 0;
        __syncthreads();
        val += other;
        sm[t] = val;
        __syncthreads();
    }
    bpre[t] = val - v;
    if (t == 0) row_ptr[N_NODES] = N_EDGES;
}

__global__ void k_scan_fin(const int* __restrict__ cnt, const int* __restrict__ bpre,
                           int* __restrict__ row_ptr) {
    __shared__ int sm[256];
    int t = threadIdx.x;
    int n = blockIdx.x * 256 + t;
    int v = (n < N_NODES) ? cnt[n] : 0;
    sm[t] = v;
    __syncthreads();
    int val = v;
    for (int off = 1; off < 256; off <<= 1) {
        int other = (t >= off) ? sm[t - off] : 0;
        __syncthreads();
        val += other;
        sm[t] = val;
        __syncthreads();
    }
    if (n < N_NODES) row_ptr[n] = bpre[blockIdx.x] + val - v;
}

// placement: per-slice u8 ordinal in LDS; writes pairs4[pos]=(c<<16|w_fp16) scattered (4 B)
// + iperm[e]=pos coalesced. ei/ew reads coalesced. 1024 threads (16 waves/CU at 1 blk/CU).
__global__ void __launch_bounds__(1024) k_placeA(const int* __restrict__ ei,
                                                 const void* __restrict__ ewr,
                                                 const int* __restrict__ flag,
                                                 const int* __restrict__ row_ptr,
                                                 const unsigned short* __restrict__ pref16,
                                                 unsigned int* __restrict__ pairs4,
                                                 int* __restrict__ iperm) {
    __shared__ unsigned int sm[NWORDS];
    int b = blockIdx.x, t = threadIdx.x;
    for (int i = t; i < NWORDS; i += 1024) sm[i] = 0;
    __syncthreads();
    int f32 = *flag;
    int ebase = b * EPR;
    const unsigned short* pr = pref16 + (size_t)b * N_NODES;
    for (int el = t; el < EPR; el += 1024) {
        int e = ebase + el;
        int r = ei[e];
        int c = ei[N_EDGES + e];
        float w = f32 ? ((const float*)ewr)[e] : bu2f(((const unsigned short*)ewr)[e]);
        int sh = (r & 3) * 8;
        unsigned old = atomicAdd(&sm[r >> 2], 1u << sh);
        int ord = (old >> sh) & 0xFF;
        int pos = row_ptr[r] + pr[r] + ord;
        pairs4[pos] = ((unsigned)c << 16) | (unsigned)f2h(w);  // scattered 4 B
        iperm[e] = pos;                                        // coalesced
    }
}

// rc rebuild: wave per node, coalesced read of pairs4 + coalesced write of rc
__global__ void __launch_bounds__(256) k_rc(const int* __restrict__ row_ptr,
                                            const unsigned int* __restrict__ pairs4,
                                            unsigned int* __restrict__ rc) {
    int lane = threadIdx.x & 63;
    int wv = __builtin_amdgcn_readfirstlane((int)(blockIdx.x * 4 + (threadIdx.x >> 6)));
    int s = __builtin_amdgcn_readfirstlane(row_ptr[wv]);
    int e = __builtin_amdgcn_readfirstlane(row_ptr[wv + 1]);
    unsigned rhi = ((unsigned)wv) << 16;
    for (int pos = s + lane; pos < e; pos += 64)
        rc[pos] = (pairs4[pos] >> 16) | rhi;
}

// ---------------- input projection: h (f32, unscaled) + hbf = bf16(dis*h) scaled state ----

__global__ void k_inproj(const void* __restrict__ xr_, const float* __restrict__ W,
                         const float* __restrict__ b, const float* __restrict__ dis,
                         float* __restrict__ h,
                         unsigned short* __restrict__ h_bf, const int* __restrict__ flag) {
    __shared__ float Wt[FIN * HD];
    __shared__ float bs[HD];
    int t = threadIdx.x;
    int f32 = *flag;
    for (int idx = t; idx < FIN * HD; idx += 256) {
        int f = idx >> 3, j = idx & 7;
        Wt[j * 64 + f] = W[idx];
    }
    if (t < 64) bs[t] = b[t];
    __syncthreads();
    int gid = blockIdx.x * 256 + t;
    if (gid < NH) {
        int i = gid >> 6, f = gid & 63;
        const float* xf = (const float*)xr_ + i * FIN;
        const unsigned short* xb = (const unsigned short*)xr_ + i * FIN;
        float acc = bs[f];
#pragma unroll
        for (int j = 0; j < FIN; ++j) {
            float xv = f32 ? xf[j] : bu2f(xb[j]);
            acc += xv * Wt[j * 64 + f];
        }
        h[gid] = acc;
        h_bf[gid] = f2bu(acc * dis[i]);   // scaled state s0 = dis .* h
    }
}

// ---------------- stats + coefficient MLP ----------------

__global__ void k_stats(const float* __restrict__ h, float* __restrict__ stats) {
    __shared__ float ssum[256], ssq[256];
    int t = threadIdx.x;
    float ls = 0.f, lq = 0.f;
    for (int idx = blockIdx.x * 256 + t; idx < NH; idx += 102400) {
        float v = h[idx];
        ls += v; lq += v * v;
    }
    ssum[t] = ls; ssq[t] = lq;
    __syncthreads();
    if (t < 64) {
        float a = ssum[t] + ssum[t + 64] + ssum[t + 128] + ssum[t + 192];
        atomicAdd(&stats[t], a);
        float q = ssq[t] + ssq[t + 64] + ssq[t + 128] + ssq[t + 192];
        for (int off = 32; off; off >>= 1) q += __shfl_down(q, off, 64);
        if (t == 0) atomicAdd(&stats[64], q);
    }
}

__global__ void k_coeffs(const float* __restrict__ stats,
                         const float* __restrict__ W1, const float* __restrict__ b1,
                         const float* __restrict__ W2, const float* __restrict__ b2,
                         int layer, float* __restrict__ coeffs) {
    __shared__ float ci[68];
    __shared__ float hid[32];
    __shared__ float lg[6];
    int t = threadIdx.x;
    float sf = stats[t];
    float tot = sf;
    for (int off = 1; off < 64; off <<= 1) tot += __shfl_xor(tot, off, 64);
    ci[t] = sf / (float)N_NODES;
    if (t == 0) {
        float sumsq = stats[64];
        float mean = tot / (float)NH;
        float var = (sumsq - (float)NH * mean * mean) / (float)(NH - 1);
        ci[64] = mean;
        ci[65] = sqrtf(fmaxf(var, 0.f));
        ci[66] = (float)N_NODES;
        ci[67] = (float)N_EDGES;
    }
    __syncthreads();
    if (t < 32) {
        float a = b1[layer * 32 + t];
        const float* wr = W1 + (layer * 32 + t) * 68;
        for (int j = 0; j < 68; ++j) a += ci[j] * wr[j];
        hid[t] = fmaxf(a, 0.f);
    }
    __syncthreads();
    if (t < 6) {
        float a = b2[layer * 6 + t];
        const float* wr = W2 + (layer * 6 + t) * 32;
        for (int g = 0; g < 32; ++g) a += hid[g] * wr[g];
        lg[t] = a;
    }
    __syncthreads();
    if (t == 0) {
        float mx = lg[0];
        for (int p = 1; p < 6; ++p) mx = fmaxf(mx, lg[p]);
        float s = 0.f, e[6];
        for (int p = 0; p < 6; ++p) { e[p] = expf(lg[p] - mx); s += e[p]; }
        for (int p = 0; p < 6; ++p) coeffs[p] = e[p] / s;
    }
}

// ---------------- SpMM hop: wave per node, scalar pair loads, 16-deep gather unroll -------
// scaled-state algebra: s_{k+1}[r] = dis2[r] * sum_e w_e * s_k[col]
// At the measured per-CU cacheline-touch wall (~13.5 cyc/random 128B touch) — r1/r6/r13
// structural variants all failed to beat it. Keep.

__device__ __forceinline__ float acc_range(const unsigned short* __restrict__ txo,
                                           const unsigned int* __restrict__ pairs4,
                                           int j0, int j1, int lane, float acc) {
    int j = j0;
    for (; j + 15 < j1; j += 16) {
        unsigned p0 = pairs4[j],      p1 = pairs4[j + 1],  p2 = pairs4[j + 2],  p3 = pairs4[j + 3];
        unsigned p4 = pairs4[j + 4],  p5 = pairs4[j + 5],  p6 = pairs4[j + 6],  p7 = pairs4[j + 7];
        unsigned p8 = pairs4[j + 8],  p9 = pairs4[j + 9],  pa = pairs4[j + 10], pb = pairs4[j + 11];
        unsigned pc = pairs4[j + 12], pd = pairs4[j + 13], pe = pairs4[j + 14], pf = pairs4[j + 15];
        float g0 = bu2f(txo[(p0 >> 16) * 64 + lane]);
        float g1 = bu2f(txo[(p1 >> 16) * 64 + lane]);
        float g2 = bu2f(txo[(p2 >> 16) * 64 + lane]);
        float g3 = bu2f(txo[(p3 >> 16) * 64 + lane]);
        float g4 = bu2f(txo[(p4 >> 16) * 64 + lane]);
        float g5 = bu2f(txo[(p5 >> 16) * 64 + lane]);
        float g6 = bu2f(txo[(p6 >> 16) * 64 + lane]);
        float g7 = bu2f(txo[(p7 >> 16) * 64 + lane]);
        float g8 = bu2f(txo[(p8 >> 16) * 64 + lane]);
        float g9 = bu2f(txo[(p9 >> 16) * 64 + lane]);
        float ga = bu2f(txo[(pa >> 16) * 64 + lane]);
        float gb = bu2f(txo[(pb >> 16) * 64 + lane]);
        float gc = bu2f(txo[(pc >> 16) * 64 + lane]);
        float gd = bu2f(txo[(pd >> 16) * 64 + lane]);
        float ge = bu2f(txo[(pe >> 16) * 64 + lane]);
        float gf = bu2f(txo[(pf >> 16) * 64 + lane]);
        acc += h16f(p0) * g0 + h16f(p1) * g1 + h16f(p2) * g2 + h16f(p3) * g3;
        acc += h16f(p4) * g4 + h16f(p5) * g5 + h16f(p6) * g6 + h16f(p7) * g7;
        acc += h16f(p8) * g8 + h16f(p9) * g9 + h16f(pa) * ga + h16f(pb) * gb;
        acc += h16f(pc) * gc + h16f(pd) * gd + h16f(pe) * ge + h16f(pf) * gf;
    }
    for (; j + 7 < j1; j += 8) {
        unsigned p0 = pairs4[j],     p1 = pairs4[j + 1], p2 = pairs4[j + 2], p3 = pairs4[j + 3];
        unsigned p4 = pairs4[j + 4], p5 = pairs4[j + 5], p6 = pairs4[j + 6], p7 = pairs4[j + 7];
        float g0 = bu2f(txo[(p0 >> 16) * 64 + lane]);
        float g1 = bu2f(txo[(p1 >> 16) * 64 + lane]);
        float g2 = bu2f(txo[(p2 >> 16) * 64 + lane]);
        float g3 = bu2f(txo[(p3 >> 16) * 64 + lane]);
        float g4 = bu2f(txo[(p4 >> 16) * 64 + lane]);
        float g5 = bu2f(txo[(p5 >> 16) * 64 + lane]);
        float g6 = bu2f(txo[(p6 >> 16) * 64 + lane]);
        float g7 = bu2f(txo[(p7 >> 16) * 64 + lane]);
        acc += h16f(p0) * g0 + h16f(p1) * g1 + h16f(p2) * g2 + h16f(p3) * g3;
        acc += h16f(p4) * g4 + h16f(p5) * g5 + h16f(p6) * g6 + h16f(p7) * g7;
    }
    for (; j < j1; ++j) {
        unsigned p = pairs4[j];
        acc += h16f(p) * bu2f(txo[(p >> 16) * 64 + lane]);
    }
    return acc;
}

__global__ void __launch_bounds__(256) k_spmm(
    const unsigned short* __restrict__ txo, unsigned short* __restrict__ txn,
    const int* __restrict__ row_ptr, const unsigned int* __restrict__ pairs4,
    const float* __restrict__ dis2) {
    int lane = threadIdx.x & 63;
    int wv = __builtin_amdgcn_readfirstlane((int)(blockIdx.x * 4 + (threadIdx.x >> 6)));
    int s = __builtin_amdgcn_readfirstlane(row_ptr[wv]);
    int e = __builtin_amdgcn_readfirstlane(row_ptr[wv + 1]);
    float acc = acc_range(txo, pairs4, s, e, lane, 0.f);
    float d2 = dis2[wv];
    txn[wv * 64 + lane] = f2bu(acc * d2);
}

// ---------------- fused last hop + polynomial combine + layernorm ----------------
// t1..t4 hold scaled s_k; tx_k = s_k / dis[r]; hop5: tx5 = dis[r] * acc

__global__ void __launch_bounds__(256) k_spmm_ln(
    const unsigned short* __restrict__ txo,
    const int* __restrict__ row_ptr, const unsigned int* __restrict__ pairs4,
    float* __restrict__ h, unsigned short* __restrict__ h_bf,
    const unsigned short* __restrict__ t1, const unsigned short* __restrict__ t2,
    const unsigned short* __restrict__ t3, const unsigned short* __restrict__ t4,
    const float* __restrict__ coeffs, const float* __restrict__ dis,
    const float* __restrict__ sc, const float* __restrict__ bi,
    int layer, int last, void* __restrict__ outv, const int* __restrict__ flag) {
    int lane = threadIdx.x & 63;
    int wv = __builtin_amdgcn_readfirstlane((int)(blockIdx.x * 4 + (threadIdx.x >> 6)));
    int s = __builtin_amdgcn_readfirstlane(row_ptr[wv]);
    int e = __builtin_amdgcn_readfirstlane(row_ptr[wv + 1]);
    float acc = acc_range(txo, pairs4, s, e, lane, 0.f);
    int o = wv * 64 + lane;
    float ds = dis[wv];
    float invd = 1.f / ds;
    float c0 = coeffs[0], c1 = coeffs[1], c2 = coeffs[2],
          c3 = coeffs[3], c4 = coeffs[4], c5 = coeffs[5];
    float v = (1.f + c0) * h[o] +
              invd * (c1 * bu2f(t1[o]) + c2 * bu2f(t2[o]) +
                      c3 * bu2f(t3[o]) + c4 * bu2f(t4[o])) +
              c5 * ds * acc;
    float m = v;
    for (int off = 1; off < 64; off <<= 1) m += __shfl_xor(m, off, 64);
    m *= (1.f / 64.f);
    float d = v - m;
    float q = d * d;
    for (int off = 1; off < 64; off <<= 1) q += __shfl_xor(q, off, 64);
    float var = q * (1.f / 64.f);
    float y = d / sqrtf(var + 1e-5f) * sc[layer * 64 + lane] + bi[layer * 64 + lane];
    h[o] = y;
    h_bf[o] = f2bu(y * ds);   // next layer's scaled state s0
    if (last) {
        if (*flag) ((float*)outv)[N_EDGES + o] = y;
        else       ((unsigned short*)outv)[N_EDGES + o] = f2bu(y);
    }
}

union U4H8 { uint4 u; half8 h; };

// ---------------- edge predictor projection: MFMA GEMM h[50000x64] @ w1h^T -> ub|vb ------
__global__ void __launch_bounds__(256) k_uv(const float* __restrict__ h,
                                            const unsigned short* __restrict__ w1h,
                                            unsigned short* __restrict__ ub,
                                            unsigned short* __restrict__ vb) {
    int t = threadIdx.x;
    int lane = t & 63;
    int m = lane & 15, q = lane >> 4;
    int wv = blockIdx.x * 4 + (t >> 6);
    if (wv >= N_NODES / 16) return;
    int node0 = wv * 16;
    const float* hrow = h + (size_t)(node0 + m) * 64 + q * 8;
    U4H8 a0, a1;
#pragma unroll
    for (int j = 0; j < 8; ++j) a0.h[j] = (_Float16)hrow[j];
#pragma unroll
    for (int j = 0; j < 8; ++j) a1.h[j] = (_Float16)hrow[32 + j];
#pragma unroll
    for (int ct = 0; ct < 8; ++ct) {
        const unsigned short* wrow = w1h + (size_t)(ct * 16 + m) * 64 + q * 8;
        U4H8 b0, b1;
        b0.u = *(const uint4*)wrow;
        b1.u = *(const uint4*)(wrow + 32);
        f32x4 acc = {0.f, 0.f, 0.f, 0.f};
        acc = __builtin_amdgcn_mfma_f32_16x16x32_f16(a0.h, b0.h, acc, 0, 0, 0);
        acc = __builtin_amdgcn_mfma_f32_16x16x32_f16(a1.h, b1.h, acc, 0, 0, 0);
        int feat = ct * 16 + m;
        unsigned short* dst = (feat < 64) ? (ub + feat) : (vb + (feat - 64));
#pragma unroll
        for (int r = 0; r < 4; ++r) {
            int node = node0 + q * 4 + r;
            dst[(size_t)node * 64] = f2h(acc[r]);
        }
    }
}

// packed fp16 relu(u + v + b) via native _Float16 vectors (avoids __hmax2 overload clash)
__device__ __forceinline__ unsigned h2rel(unsigned uu, unsigned vv, half2v b) {
    half2v a = *(half2v*)&uu + *(half2v*)&vv + b;
    a[0] = a[0] > (_Float16)0 ? a[0] : (_Float16)0;
    a[1] = a[1] > (_Float16)0 ? a[1] : (_Float16)0;
    return *(unsigned*)&a;
}

// MFMA f16 edge predictor, 2-tile unrolled. Grid 2048 (8 blk/CU exactly, one residency
// round — r13's 2500 left a 33%-occupancy second round). v-gathers sit at the same
// cacheline-touch wall as spmm.
__global__ void __launch_bounds__(256) k_edgepred(
    const unsigned short* __restrict__ ub, const unsigned short* __restrict__ vb,
    const unsigned int* __restrict__ rc,
    const float* __restrict__ eb1, const float* __restrict__ eW2,
    const float* __restrict__ eb2, const float* __restrict__ eW3,
    const float* __restrict__ eb3, float* __restrict__ tmpP) {
    int t = threadIdx.x;
    int lane = t & 63;
    int m = lane & 15, q = lane >> 4;

    half8 B00, B01, B10, B11;
#pragma unroll
    for (int j = 0; j < 8; ++j) {
        B00[j] = (_Float16)eW2[(m) * 64      + q * 8 + j];
        B01[j] = (_Float16)eW2[(m) * 64 + 32 + q * 8 + j];
        B10[j] = (_Float16)eW2[(m + 16) * 64      + q * 8 + j];
        B11[j] = (_Float16)eW2[(m + 16) * 64 + 32 + q * 8 + j];
    }
    half2v b1p0[4], b1p1[4];
#pragma unroll
    for (int wq = 0; wq < 4; ++wq) {
        b1p0[wq][0] = (_Float16)eb1[q * 8 + 2 * wq];
        b1p0[wq][1] = (_Float16)eb1[q * 8 + 2 * wq + 1];
        b1p1[wq][0] = (_Float16)eb1[32 + q * 8 + 2 * wq];
        b1p1[wq][1] = (_Float16)eb1[32 + q * 8 + 2 * wq + 1];
    }
    float w3a = eW3[m], w3b = eW3[16 + m];
    float b2a = eb2[m], b2b = eb2[16 + m];
    float b3v = eb3[0];

    int gw = blockIdx.x * 4 + (t >> 6);
    const int NW = 2048 * 4;
    for (int tp = gw; tp < N_EDGES / 32; tp += NW) {
        int base0 = (tp * 2) << 4;
        int base1 = base0 + 16;
        unsigned rcv0 = rc[base0 + m];
        unsigned rcv1 = rc[base1 + m];
        const unsigned short* up0 = ub + (rcv0 >> 16) * 64;
        const unsigned short* vp0 = vb + (rcv0 & 0xFFFFu) * 64;
        const unsigned short* up1 = ub + (rcv1 >> 16) * 64;
        const unsigned short* vp1 = vb + (rcv1 & 0xFFFFu) * 64;
        uint4 U00 = *(const uint4*)(up0 + q * 8);
        uint4 U01 = *(const uint4*)(up0 + 32 + q * 8);
        uint4 V00 = *(const uint4*)(vp0 + q * 8);
        uint4 V01 = *(const uint4*)(vp0 + 32 + q * 8);
        uint4 U10 = *(const uint4*)(up1 + q * 8);
        uint4 U11 = *(const uint4*)(up1 + 32 + q * 8);
        uint4 V10 = *(const uint4*)(vp1 + q * 8);
        uint4 V11 = *(const uint4*)(vp1 + 32 + q * 8);

        // ---- tile 0 ----
        U4H8 a0, a1;
        a0.u.x = h2rel(U00.x, V00.x, b1p0[0]);
        a0.u.y = h2rel(U00.y, V00.y, b1p0[1]);
        a0.u.z = h2rel(U00.z, V00.z, b1p0[2]);
        a0.u.w = h2rel(U00.w, V00.w, b1p0[3]);
        a1.u.x = h2rel(U01.x, V01.x, b1p1[0]);
        a1.u.y = h2rel(U01.y, V01.y, b1p1[1]);
        a1.u.z = h2rel(U01.z, V01.z, b1p1[2]);
        a1.u.w = h2rel(U01.w, V01.w, b1p1[3]);
        f32x4 acc0 = {0.f, 0.f, 0.f, 0.f};
        f32x4 acc1 = {0.f, 0.f, 0.f, 0.f};
        acc0 = __builtin_amdgcn_mfma_f32_16x16x32_f16(a0.h, B00, acc0, 0, 0, 0);
        acc0 = __builtin_amdgcn_mfma_f32_16x16x32_f16(a1.h, B01, acc0, 0, 0, 0);
        acc1 = __builtin_amdgcn_mfma_f32_16x16x32_f16(a0.h, B10, acc1, 0, 0, 0);
        acc1 = __builtin_amdgcn_mfma_f32_16x16x32_f16(a1.h, B11, acc1, 0, 0, 0);
        float z0[4];
#pragma unroll
        for (int rr = 0; rr < 4; ++rr) {
            z0[rr] = w3a * fmaxf(acc0[rr] + b2a, 0.f) + w3b * fmaxf(acc1[rr] + b2b, 0.f);
            z0[rr] += __shfl_xor(z0[rr], 1, 64);
            z0[rr] += __shfl_xor(z0[rr], 2, 64);
            z0[rr] += __shfl_xor(z0[rr], 4, 64);
            z0[rr] += __shfl_xor(z0[rr], 8, 64);
        }

        // ---- tile 1 ----
        U4H8 c0, c1;
        c0.u.x = h2rel(U10.x, V10.x, b1p0[0]);
        c0.u.y = h2rel(U10.y, V10.y, b1p0[1]);
        c0.u.z = h2rel(U10.z, V10.z, b1p0[2]);
        c0.u.w = h2rel(U10.w, V10.w, b1p0[3]);
        c1.u.x = h2rel(U11.x, V11.x, b1p1[0]);
        c1.u.y = h2rel(U11.y, V11.y, b1p1[1]);
        c1.u.z = h2rel(U11.z, V11.z, b1p1[2]);
        c1.u.w = h2rel(U11.w, V11.w, b1p1[3]);
        f32x4 acc2 = {0.f, 0.f, 0.f, 0.f};
        f32x4 acc3 = {0.f, 0.f, 0.f, 0.f};
        acc2 = __builtin_amdgcn_mfma_f32_16x16x32_f16(c0.h, B00, acc2, 0, 0, 0);
        acc2 = __builtin_amdgcn_mfma_f32_16x16x32_f16(c1.h, B01, acc2, 0, 0, 0);
        acc3 = __builtin_amdgcn_mfma_f32_16x16x32_f16(c0.h, B10, acc3, 0, 0, 0);
        acc3 = __builtin_amdgcn_mfma_f32_16x16x32_f16(c1.h, B11, acc3, 0, 0, 0);
        float z1[4];
#pragma unroll
        for (int rr = 0; rr < 4; ++rr) {
            z1[rr] = w3a * fmaxf(acc2[rr] + b2a, 0.f) + w3b * fmaxf(acc3[rr] + b2b, 0.f);
            z1[rr] += __shfl_xor(z1[rr], 1, 64);
            z1[rr] += __shfl_xor(z1[rr], 2, 64);
            z1[rr] += __shfl_xor(z1[rr], 4, 64);
            z1[rr] += __shfl_xor(z1[rr], 8, 64);
        }

        if (m == 0) {
#pragma unroll
            for (int rr = 0; rr < 4; ++rr) {
                float p0 = 1.f / (1.f + __expf(-(z0[rr] + b3v)));
                float p1 = 1.f / (1.f + __expf(-(z1[rr] + b3v)));
                tmpP[base0 + (q << 2) + rr] = p0;
                tmpP[base1 + (q << 2) + rr] = p1;
            }
        }
    }
}

// final: out[e] = tmpP[iperm[e]] (coalesced read+write; tmpP gather is L2-resident)
__global__ void k_out(const int* __restrict__ iperm, const float* __restrict__ tmpP,
                      void* __restrict__ outv, const int* __restrict__ flag) {
    int e = blockIdx.x * 256 + threadIdx.x;
    if (e >= N_EDGES) return;
    float p = tmpP[iperm[e]];
    if (*flag) ((float*)outv)[e] = p;
    else       ((unsigned short*)outv)[e] = f2bu(p);
}

// ---------------- launch ----------------

extern "C" void kernel_launch(void* const* d_in, const int* in_sizes, int n_in,
                              void* d_out, int out_size, void* d_ws, size_t ws_size,
                              hipStream_t stream) {
    (void)in_sizes; (void)n_in; (void)out_size; (void)ws_size;
    const void* x_r   = d_in[0];
    const int*  ei    = (const int*)d_in[1];
    const void* ew_r  = d_in[2];

    // layout NOTE: iperm moved up so [h|hbf|iperm] = 25.6 MB hosts pdeg16 (256 u16 slices)
    char* w = (char*)d_ws;
    float* h            = (float*)w;          w += (size_t)NH * 4;       // 12.8 MB
    unsigned short* hbf = (unsigned short*)w; w += (size_t)NH * 2;       // 6.4
    int* iperm          = (int*)w;            w += (size_t)N_EDGES * 4;  // 6.4
    char* txr           = w;                  w += (size_t)NH * 8;       // 25.6 (4 bufs)
    unsigned int* pairs4 = (unsigned int*)w;  w += (size_t)N_EDGES * 4;  // 6.4
    unsigned int* rc    = (unsigned int*)w;   w += (size_t)N_EDGES * 4;  // 6.4 (adjacent!)
    int* row_ptr        = (int*)w;            w += 200192;
    int* cnt            = (int*)w;            w += 200192;
    float* dis          = (float*)w;          w += 200192;
    float* dis2         = (float*)w;          w += 200192;
    float* cWin = (float*)w; w += 2048;
    float* cbin = (float*)w; w += 256;
    float* ccW1 = (float*)w; w += 26112;
    float* ccb1 = (float*)w; w += 384;
    float* ccW2 = (float*)w; w += 2304;
    float* ccb2 = (float*)w; w += 128;
    float* clns = (float*)w; w += 768;
    float* clnb = (float*)w; w += 768;
    float* ceW1 = (float*)w; w += 32768;
    float* ceb1 = (float*)w; w += 256;
    float* ceW2 = (float*)w; w += 8192;
    float* ceb2 = (float*)w; w += 128;
    float* ceW3 = (float*)w; w += 128;
    float* ceb3 = (float*)w; w += 128;
    unsigned short* w1h = (unsigned short*)w; w += 16384;   // f16 [128][64] packed ep_W1
    int* bsum = (int*)w; w += 1024;
    int* bpre = (int*)w; w += 1024;
    char* zero_base = w;
    float* stats = (float*)w; w += 1024;
    size_t zero_bytes = (size_t)(w - zero_base);
    float* coeffs = (float*)w; w += 128;
    int*   flag   = (int*)w;   w += 128;

    // setup-phase overlays (lifetimes disjoint with hosts):
    //  pcnt8  (12.8 MB) -> [pairs4|rc] region   [histdeg2 -> merge; dead before placeA/k_rc]
    //  pdeg16 (25.6 MB) -> [h|hbf|iperm] region [histdeg2 -> merge; iperm written by placeA
    //                                            AFTER merge; h/hbf written by inproj later]
    //  pref16 (25.6 MB) -> txr                  [merge -> placeA]
    //  tmpP   (6.4 MB)  -> pairs4 region        [edgepred -> k_out; pairs4 dead]
    unsigned int* pcnt_u32 = (unsigned int*)pairs4;
    unsigned char* pcnt8   = (unsigned char*)pairs4;
    unsigned short* pref16 = (unsigned short*)txr;
    unsigned short* pdeg16 = (unsigned short*)h;
    float* tmpP            = (float*)pairs4;

    unsigned short* tx[4];
    for (int k = 0; k < 4; ++k) tx[k] = (unsigned short*)txr + (size_t)k * NH;
    unsigned short* ub = tx[0];   // k_uv runs after last spmm_ln: tx dead
    unsigned short* vb = tx[1];

    (void)hipMemsetAsync(zero_base, 0, zero_bytes, stream);

    k_detect<<<1, 64, 0, stream>>>(ew_r, flag);

    ConvArgs ca;
    const void* srcs[14] = {d_in[3], d_in[4], d_in[5], d_in[6], d_in[7], d_in[8], d_in[9],
                            d_in[10], d_in[11], d_in[12], d_in[13], d_in[14], d_in[15], d_in[16]};
    float* dsts[14] = {cWin, cbin, ccW1, ccb1, ccW2, ccb2, clns,
                       clnb, ceW1, ceb1, ceW2, ceb2, ceW3, ceb3};
    int sizes[14] = {512, 64, 6528, 96, 576, 18, 192, 192, 8192, 64, 2048, 32, 32, 1};
    int c = 0;
    for (int i = 0; i < 14; ++i) { ca.src[i] = srcs[i]; ca.dst[i] = dsts[i]; ca.cum[i] = c; c += sizes[i]; }
    ca.cum[14] = c;
    k_conv_small<<<(c + 255) / 256, 256, 0, stream>>>(ca, flag);
    k_w1h<<<32, 256, 0, stream>>>(ceW1, w1h);

    k_histdeg2<<<RSLC, 1024, 0, stream>>>(ei, ew_r, flag, pcnt_u32, pdeg16);
    k_merge<<<196, 256, 0, stream>>>(pcnt8, pdeg16, cnt, dis, dis2, pref16, bsum);
    k_scan_top<<<1, 256, 0, stream>>>(bsum, bpre, row_ptr);
    k_scan_fin<<<196, 256, 0, stream>>>(cnt, bpre, row_ptr);
    k_placeA<<<RSLC, 1024, 0, stream>>>(ei, ew_r, flag, row_ptr, pref16, pairs4, iperm);
    k_rc<<<12500, 256, 0, stream>>>(row_ptr, pairs4, rc);
    k_inproj<<<12500, 256, 0, stream>>>(x_r, cWin, cbin, dis, h, hbf, flag);

    for (int l = 0; l < NLAYERS; ++l) {
        k_stats<<<400, 256, 0, stream>>>(h, stats + l * 80);
        k_coeffs<<<1, 64, 0, stream>>>(stats + l * 80, ccW1, ccb1, ccW2, ccb2, l,
                                       coeffs + l * 8);
        const unsigned short* src = hbf;
        for (int k = 0; k < 4; ++k) {
            k_spmm<<<12500, 256, 0, stream>>>(src, tx[k], row_ptr, pairs4, dis2);
            src = tx[k];
        }
        k_spmm_ln<<<12500, 256, 0, stream>>>(tx[3], row_ptr, pairs4, h, hbf,
                                             tx[0], tx[1], tx[2], tx[3],
                                             coeffs + l * 8, dis, clns, clnb, l,
                                             (l == NLAYERS - 1) ? 1 : 0, d_out, flag);
    }

    k_uv<<<782, 256, 0, stream>>>(h, w1h, ub, vb);
    k_edgepred<<<2048, 256, 0, stream>>>(ub, vb, rc, ceb1, ceW2, ceb2, ceW3, ceb3, tmpP);
    k_out<<<6250, 256, 0, stream>>>(iperm, tmpP, d_out, flag);
}